// Round 3
// baseline (329.751 us; speedup 1.0000x reference)
//
#include <hip/hip_runtime.h>
#include <math.h>

// Problem constants
#define BATCH 8
#define CH    256
#define HDIM  56
#define WDIM  56
#define HW    (HDIM*WDIM)          // 3136
#define MTOT  (BATCH*HW)           // 25088
#define GRP   8
#define GC    32
#define NP    9                    // K*K
#define NOFF  (GRP*NP*2)           // 144
#define NMSK  (GRP*NP)             // 72
#define NTOT  (NOFF+NMSK)          // 216
#define POSB  4                    // positions per sample block

typedef float f32x4 __attribute__((ext_vector_type(4)));
typedef short s16x8 __attribute__((ext_vector_type(8)));

// split a,b into packed bf16 hi (truncation) and bf16 lo (exact remainder, truncated)
__device__ inline void split2(float a, float b, unsigned int& hp, unsigned int& lp)
{
    const unsigned int ua = __float_as_uint(a), ub = __float_as_uint(b);
    hp = (ub & 0xffff0000u) | (ua >> 16);
    const float ha = __uint_as_float(ua & 0xffff0000u);
    const float hb = __uint_as_float(ub & 0xffff0000u);
    const unsigned int la = __float_as_uint(a - ha), lb = __float_as_uint(b - hb);
    lp = (lb & 0xffff0000u) | (la >> 16);
}

// ---------------------------------------------------------------------------
// Transpose + split x (NCHW) -> xt_hi/xt_lo [m][k] bf16. 64x64 LDS tiles.
// ---------------------------------------------------------------------------
__global__ __launch_bounds__(256)
void xt_split_kernel(const float* __restrict__ x,
                     unsigned short* __restrict__ hi,
                     unsigned short* __restrict__ lo)
{
    __shared__ float lds[64][68];
    const int hw0 = blockIdx.x * 64;       // 49 tiles (3136/64)
    const int k0  = blockIdx.y * 64;       // 4 tiles
    const int b   = blockIdx.z;            // 8
    const int t = threadIdx.x;
    #pragma unroll
    for (int p = 0; p < 4; ++p) {
        const int kr = (t >> 4) + p * 16;
        const int hc = (t & 15) * 4;
        *(float4*)&lds[kr][hc] =
            *(const float4*)(x + ((size_t)b * CH + k0 + kr) * HW + hw0 + hc);
    }
    __syncthreads();
    const int ml = t >> 2;             // m-row 0..63
    const int kc = (t & 3) * 16;       // k base 0,16,32,48
    unsigned int hbuf[8], lbuf[8];
    #pragma unroll
    for (int j = 0; j < 16; j += 2)
        split2(lds[kc + j][ml], lds[kc + j + 1][ml], hbuf[j >> 1], lbuf[j >> 1]);
    const size_t row = (size_t)(b * HW + hw0 + ml) * CH + k0 + kc;
    *(uint4*)&hi[row]     = *(uint4*)&hbuf[0];
    *(uint4*)&hi[row + 8] = *(uint4*)&hbuf[4];
    *(uint4*)&lo[row]     = *(uint4*)&lbuf[0];
    *(uint4*)&lo[row + 8] = *(uint4*)&lbuf[4];
}

// ---------------------------------------------------------------------------
// GEMM in via bf16 MFMA: v = x^T @ w_in + b_in (NHWC out). Barrier-free.
// ---------------------------------------------------------------------------
__global__ __launch_bounds__(256)
void gemm_in_mfma(const unsigned short* __restrict__ xhi, // [m][k]
                  const unsigned short* __restrict__ xlo,
                  const unsigned short* __restrict__ whi, // [n][k]
                  const unsigned short* __restrict__ wlo,
                  const float* __restrict__ bias,
                  float* __restrict__ v)                  // [MTOT,256]
{
    const int m0 = blockIdx.x * 256;
    const int n0 = blockIdx.y * 64;
    const int t = threadIdx.x;
    const int lane = t & 63, wv = t >> 6;
    const int mblk = m0 + wv * 64;
    const int fm = lane & 15;
    const int q  = lane >> 4;

    f32x4 acc[4][4];              // [nt][mt]
    const f32x4 zero = {0.0f, 0.0f, 0.0f, 0.0f};
    #pragma unroll
    for (int i = 0; i < 4; ++i)
        #pragma unroll
        for (int j = 0; j < 4; ++j) acc[i][j] = zero;

    const unsigned short *xrh[4], *xrl[4], *wrh[4], *wrl[4];
    #pragma unroll
    for (int mt = 0; mt < 4; ++mt) {
        xrh[mt] = xhi + (size_t)(mblk + mt*16 + fm) * CH + q * 8;
        xrl[mt] = xlo + (size_t)(mblk + mt*16 + fm) * CH + q * 8;
    }
    #pragma unroll
    for (int nt = 0; nt < 4; ++nt) {
        wrh[nt] = whi + (size_t)(n0 + nt*16 + fm) * CH + q * 8;
        wrl[nt] = wlo + (size_t)(n0 + nt*16 + fm) * CH + q * 8;
    }

    for (int k0 = 0; k0 < CH; k0 += 32) {
        s16x8 wh[4], wl[4], ah[4], al[4];
        #pragma unroll
        for (int nt = 0; nt < 4; ++nt) {
            wh[nt] = *(const s16x8*)(wrh[nt] + k0);
            wl[nt] = *(const s16x8*)(wrl[nt] + k0);
        }
        #pragma unroll
        for (int mt = 0; mt < 4; ++mt) {
            ah[mt] = *(const s16x8*)(xrh[mt] + k0);
            al[mt] = *(const s16x8*)(xrl[mt] + k0);
        }
        #pragma unroll
        for (int nt = 0; nt < 4; ++nt)
            #pragma unroll
            for (int mt = 0; mt < 4; ++mt) {
                acc[nt][mt] = __builtin_amdgcn_mfma_f32_16x16x32_bf16(wh[nt], ah[mt], acc[nt][mt], 0, 0, 0);
                acc[nt][mt] = __builtin_amdgcn_mfma_f32_16x16x32_bf16(wh[nt], al[mt], acc[nt][mt], 0, 0, 0);
                acc[nt][mt] = __builtin_amdgcn_mfma_f32_16x16x32_bf16(wl[nt], ah[mt], acc[nt][mt], 0, 0, 0);
            }
    }

    #pragma unroll
    for (int nt = 0; nt < 4; ++nt) {
        const float4 b4 = *(const float4*)&bias[n0 + nt*16 + q*4];
        #pragma unroll
        for (int mt = 0; mt < 4; ++mt) {
            f32x4 o = acc[nt][mt];
            o[0] += b4.x; o[1] += b4.y; o[2] += b4.z; o[3] += b4.w;
            *(f32x4*)&v[(size_t)(mblk + mt*16 + fm) * CH + n0 + nt*16 + q*4] = o;
        }
    }
}

// ---------------------------------------------------------------------------
// OLD fallback: fused depthwise 3x3 + bias + LayerNorm(C) + exact GELU -> f.
// ---------------------------------------------------------------------------
__global__ __launch_bounds__(256)
void dw_ln_gelu_kernel(const float* __restrict__ x,
                       const float* __restrict__ dw_w,
                       const float* __restrict__ dw_b,
                       const float* __restrict__ ln_g,
                       const float* __restrict__ ln_b,
                       float* __restrict__ f)
{
    __shared__ float tile[WDIM][CH + 1];
    __shared__ float red1[WDIM][4], red2[WDIM][4];
    __shared__ float meanA[WDIM], rstdA[WDIM];

    const int h = blockIdx.x;
    const int b = blockIdx.y;
    const int t = threadIdx.x;
    const int lane = t & 63;
    const int wv   = t >> 6;

    for (int cg = 0; cg < CH / 4; ++cg) {
        const int c = cg * 4 + wv;
        const float* xp = x + ((size_t)b * CH + c) * HW;
        float rowv[3];
        #pragma unroll
        for (int r = 0; r < 3; ++r) {
            const int hh = h + r - 1;
            rowv[r] = (lane < WDIM && hh >= 0 && hh < HDIM) ? xp[hh * WDIM + lane] : 0.0f;
        }
        const float* wp = dw_w + c * 9;
        float acc = dw_b[c];
        #pragma unroll
        for (int r = 0; r < 3; ++r) {
            float L = __shfl_up(rowv[r], 1);
            float R = __shfl_down(rowv[r], 1);
            if (lane == 0) L = 0.0f;
            acc += L * wp[r * 3 + 0] + rowv[r] * wp[r * 3 + 1] + R * wp[r * 3 + 2];
        }
        if (lane < WDIM)
            tile[lane][c] = acc;
    }
    __syncthreads();

    if (t < 224) {
        const int p = t >> 2, q = t & 3;
        float s1 = 0.0f, s2 = 0.0f;
        #pragma unroll 8
        for (int i = 0; i < 64; ++i) {
            const float v = tile[p][q * 64 + i];
            s1 += v; s2 += v * v;
        }
        red1[p][q] = s1; red2[p][q] = s2;
    }
    __syncthreads();
    if (t < WDIM) {
        const float s1 = red1[t][0] + red1[t][1] + red1[t][2] + red1[t][3];
        const float s2 = red2[t][0] + red2[t][1] + red2[t][2] + red2[t][3];
        const float m = s1 * (1.0f / 256.0f);
        const float var = s2 * (1.0f / 256.0f) - m * m;
        meanA[t] = m;
        rstdA[t] = rsqrtf(var + 1e-5f);
    }
    __syncthreads();

    const float gam = ln_g[t], bet = ln_b[t];
    const size_t n0 = (size_t)(b * HDIM + h) * WDIM;
    for (int p = 0; p < WDIM; ++p) {
        const float xn = (tile[p][t] - meanA[p]) * rstdA[p] * gam + bet;
        const float g = 0.5f * xn * (1.0f + erff(xn * 0.70710678118654752f));
        f[(n0 + p) * CH + t] = g;
    }
}

// ---------------------------------------------------------------------------
// Per-position-wave depthwise 3x3 + bias + LN + GELU from NHWC bf16 hi/lo xt,
// output stored PRE-SPLIT as bf16 hi/lo (bit-identical to what the GEMM's
// in-loop split2 would produce). One wave per position, no LDS hot path.
// XCD swizzle: each XCD owns one batch image (xt slice 3.2MB fits 4MB L2).
// ---------------------------------------------------------------------------
__global__ __launch_bounds__(256)
void dw_ln_gelu_nhwc_split(const unsigned short* __restrict__ xhi,
                           const unsigned short* __restrict__ xlo,
                           const float* __restrict__ dw_w,   // [256][9]
                           const float* __restrict__ dw_b,
                           const float* __restrict__ ln_g,
                           const float* __restrict__ ln_b,
                           unsigned short* __restrict__ fh,  // [MTOT][256]
                           unsigned short* __restrict__ fl)  // [MTOT][256]
{
    __shared__ float wt[NP][CH];                       // transposed dw weights
    __shared__ float lbias[CH], lgam[CH], lbet[CH];

    const int t = threadIdx.x;
    {
        const float* wp = dw_w + t * NP;
        #pragma unroll
        for (int p = 0; p < NP; ++p) wt[p][t] = wp[p];
        lbias[t] = dw_b[t]; lgam[t] = ln_g[t]; lbet[t] = ln_b[t];
    }
    __syncthreads();

    const int nblk = MTOT / POSB;          // 6272
    const int per  = nblk / 8;             // 784
    const int bid  = blockIdx.x;
    const int sw   = (bid & 7) * per + (bid >> 3);
    const int q    = t >> 6, lane = t & 63;
    const int n    = sw * POSB + q;
    const int b    = n / HW;
    const int hw   = n % HW;
    const int h    = hw / WDIM, w = hw % WDIM;
    const int c4   = lane * 4;
    const size_t base = (size_t)b * HW * CH + c4;

    float ax = 0.0f, ay = 0.0f, az = 0.0f, aw = 0.0f;
    #pragma unroll
    for (int p = 0; p < NP; ++p) {
        const int hh = h + p / 3 - 1;
        const int ww = w + p % 3 - 1;
        if ((unsigned)hh >= (unsigned)HDIM || (unsigned)ww >= (unsigned)WDIM)
            continue;                       // wave-uniform branch (h,w per-wave)
        const size_t idx = base + (size_t)(hh * WDIM + ww) * CH;
        const ushort4 uh = *(const ushort4*)(xhi + idx);
        const ushort4 ul = *(const ushort4*)(xlo + idx);
        const float4 wv = *(const float4*)&wt[p][c4];
        ax = fmaf(__uint_as_float((unsigned)uh.x << 16), wv.x,
             fmaf(__uint_as_float((unsigned)ul.x << 16), wv.x, ax));
        ay = fmaf(__uint_as_float((unsigned)uh.y << 16), wv.y,
             fmaf(__uint_as_float((unsigned)ul.y << 16), wv.y, ay));
        az = fmaf(__uint_as_float((unsigned)uh.z << 16), wv.z,
             fmaf(__uint_as_float((unsigned)ul.z << 16), wv.z, az));
        aw = fmaf(__uint_as_float((unsigned)uh.w << 16), wv.w,
             fmaf(__uint_as_float((unsigned)ul.w << 16), wv.w, aw));
    }
    {
        const float4 b4 = *(const float4*)&lbias[c4];
        ax += b4.x; ay += b4.y; az += b4.z; aw += b4.w;
    }

    // LayerNorm over the wave's 256 channel values: in-wave butterfly.
    float s1 = ax + ay + az + aw;
    float s2 = ax*ax + ay*ay + az*az + aw*aw;
    #pragma unroll
    for (int off = 32; off > 0; off >>= 1) {
        s1 += __shfl_xor(s1, off);
        s2 += __shfl_xor(s2, off);
    }
    const float mean = s1 * (1.0f / 256.0f);
    const float rstd = rsqrtf(s2 * (1.0f / 256.0f) - mean * mean + 1e-5f);

    const float4 g4 = *(const float4*)&lgam[c4];
    const float4 e4 = *(const float4*)&lbet[c4];
    const float x0 = (ax - mean) * rstd * g4.x + e4.x;
    const float x1 = (ay - mean) * rstd * g4.y + e4.y;
    const float x2 = (az - mean) * rstd * g4.z + e4.z;
    const float x3 = (aw - mean) * rstd * g4.w + e4.w;
    const float o0 = 0.5f * x0 * (1.0f + erff(x0 * 0.70710678118654752f));
    const float o1 = 0.5f * x1 * (1.0f + erff(x1 * 0.70710678118654752f));
    const float o2 = 0.5f * x2 * (1.0f + erff(x2 * 0.70710678118654752f));
    const float o3 = 0.5f * x3 * (1.0f + erff(x3 * 0.70710678118654752f));

    unsigned int hp0, lp0, hp1, lp1;
    split2(o0, o1, hp0, lp0);
    split2(o2, o3, hp1, lp1);
    *(uint2*)&fh[(size_t)n * CH + c4] = make_uint2(hp0, hp1);
    *(uint2*)&fl[(size_t)n * CH + c4] = make_uint2(lp0, lp1);
}

// ---------------------------------------------------------------------------
// Offset+mask GEMM from pre-split bf16 A. 16m x 64n per wave -> 6272 waves
// (4x round-2's parallelism), no in-loop split2. 1-D grid 1568 = 8 XCDs x
// (49 m-tiles x 4 n-tiles): each XCD reads exactly one batch image's fh/fl
// slice (3.2 MB -> fits its private 4 MB L2).
// ---------------------------------------------------------------------------
__global__ __launch_bounds__(256)
void gemm_offmask_bf16(const unsigned short* __restrict__ fh, // [MTOT][256]
                       const unsigned short* __restrict__ fl,
                       const unsigned short* __restrict__ whi, // [256][256] bf16
                       const unsigned short* __restrict__ wlo,
                       const float* __restrict__ b_off,
                       const float* __restrict__ b_mask,
                       float* __restrict__ offb,               // [MTOT,144]
                       float* __restrict__ mskb)               // [MTOT,72]
{
    const int bid = blockIdx.x;            // 0..1567
    const int xcd = bid & 7;
    const int idx = bid >> 3;              // 0..195
    const int mt_img = idx >> 2;           // 0..48 (m-tile within image)
    const int nt  = idx & 3;               // n-tile 0..3
    const int m0  = (xcd * 49 + mt_img) * 64;
    const int n0  = nt * 64;

    const int t = threadIdx.x;
    const int wv = t >> 6, lane = t & 63;
    const int fm = lane & 15, q = lane >> 4;
    const int mrow = m0 + wv * 16 + fm;

    f32x4 acc[4];
    const f32x4 zero = {0.0f, 0.0f, 0.0f, 0.0f};
    #pragma unroll
    for (int i = 0; i < 4; ++i) acc[i] = zero;

    const unsigned short* arh = fh + (size_t)mrow * CH + q * 8;
    const unsigned short* arl = fl + (size_t)mrow * CH + q * 8;
    const unsigned short *wrh[4], *wrl[4];
    #pragma unroll
    for (int sub = 0; sub < 4; ++sub) {
        wrh[sub] = whi + (size_t)(n0 + sub*16 + fm) * CH + q * 8;
        wrl[sub] = wlo + (size_t)(n0 + sub*16 + fm) * CH + q * 8;
    }

    for (int k0 = 0; k0 < CH; k0 += 32) {
        const s16x8 ah = *(const s16x8*)(arh + k0);
        const s16x8 al = *(const s16x8*)(arl + k0);
        #pragma unroll
        for (int sub = 0; sub < 4; ++sub) {
            const s16x8 wh = *(const s16x8*)(wrh[sub] + k0);
            const s16x8 wl = *(const s16x8*)(wrl[sub] + k0);
            acc[sub] = __builtin_amdgcn_mfma_f32_16x16x32_bf16(wh, ah, acc[sub], 0, 0, 0);
            acc[sub] = __builtin_amdgcn_mfma_f32_16x16x32_bf16(wh, al, acc[sub], 0, 0, 0);
            acc[sub] = __builtin_amdgcn_mfma_f32_16x16x32_bf16(wl, ah, acc[sub], 0, 0, 0);
        }
    }

    #pragma unroll
    for (int sub = 0; sub < 4; ++sub) {
        #pragma unroll
        for (int r = 0; r < 4; ++r) {
            const int n = n0 + sub*16 + q*4 + r;
            if (n >= NTOT) continue;
            const float bs = (n < NOFF) ? b_off[n] : b_mask[n - NOFF];
            const float val = acc[sub][r] + bs;
            if (n < NOFF) offb[(size_t)mrow * NOFF + n] = val;
            else          mskb[(size_t)mrow * NMSK + (n - NOFF)] = val;
        }
    }
}

// ---------------------------------------------------------------------------
// Transpose + hi/lo bf16 split of a [256k][256n] fp32 weight -> [n][k] bf16.
// ---------------------------------------------------------------------------
__global__ __launch_bounds__(256)
void wt_split_kernel(const float* __restrict__ w,
                     unsigned short* __restrict__ hi,
                     unsigned short* __restrict__ lo)
{
    __shared__ float lds[64][68];
    const int kt = blockIdx.x * 64, nt = blockIdx.y * 64;
    const int t = threadIdx.x;
    #pragma unroll
    for (int p = 0; p < 4; ++p) {
        const int kr = (t >> 4) + p * 16, nc = (t & 15) * 4;
        *(float4*)&lds[kr][nc] = *(const float4*)(w + (size_t)(kt + kr) * CH + nt + nc);
    }
    __syncthreads();
    const int nl = t >> 2, kc = (t & 3) * 16;
    #pragma unroll
    for (int j = 0; j < 16; j += 2) {
        const float f0 = lds[kc + j][nl], f1 = lds[kc + j + 1][nl];
        unsigned int hp, lp;
        split2(f0, f1, hp, lp);
        *(unsigned int*)&hi[(size_t)(nt + nl) * CH + kt + kc + j] = hp;
        *(unsigned int*)&lo[(size_t)(nt + nl) * CH + kt + kc + j] = lp;
    }
}

// ---------------------------------------------------------------------------
// Transpose + split of [w_off | w_mask] -> wt2_hi/lo [256 n_pad][256 k] bf16.
// ---------------------------------------------------------------------------
__global__ __launch_bounds__(256)
void wt2_split_kernel(const float* __restrict__ w_off,   // [256][144]
                      const float* __restrict__ w_mask,  // [256][72]
                      unsigned short* __restrict__ hi,
                      unsigned short* __restrict__ lo)
{
    const int n = threadIdx.x;
    const int k0 = blockIdx.x * 16;
    #pragma unroll
    for (int j = 0; j < 16; j += 2) {
        const int k = k0 + j;
        float f0 = 0.0f, f1 = 0.0f;
        if (n < NOFF) {
            f0 = w_off[(size_t)k * NOFF + n];
            f1 = w_off[(size_t)(k + 1) * NOFF + n];
        } else if (n < NTOT) {
            f0 = w_mask[(size_t)k * NMSK + (n - NOFF)];
            f1 = w_mask[(size_t)(k + 1) * NMSK + (n - NOFF)];
        }
        unsigned int hp, lp;
        split2(f0, f1, hp, lp);
        *(unsigned int*)&hi[(size_t)n * CH + k] = hp;
        *(unsigned int*)&lo[(size_t)n * CH + k] = lp;
    }
}

// ---------------------------------------------------------------------------
// Fallback: offset+mask GEMM via bf16 MFMA (reads f32 f from global).
// ---------------------------------------------------------------------------
__global__ __launch_bounds__(256)
void gemm_offmask_mfma(const float* __restrict__ A,            // f [MTOT,256]
                       const unsigned short* __restrict__ whi, // [256][256] bf16
                       const unsigned short* __restrict__ wlo,
                       const float* __restrict__ b_off,
                       const float* __restrict__ b_mask,
                       float* __restrict__ offb,               // [MTOT,144]
                       float* __restrict__ mskb)               // [MTOT,72]
{
    const int m0 = blockIdx.x * 256;
    const int n0 = blockIdx.y * 64;
    const int t = threadIdx.x;
    const int lane = t & 63, wv = t >> 6;
    const int mblk = m0 + wv * 64;
    const int fm = lane & 15;
    const int q  = lane >> 4;

    f32x4 acc[4][4];
    const f32x4 zero = {0.0f, 0.0f, 0.0f, 0.0f};
    #pragma unroll
    for (int i = 0; i < 4; ++i)
        #pragma unroll
        for (int j = 0; j < 4; ++j) acc[i][j] = zero;

    const float* arow[4];
    const unsigned short* wrh[4];
    const unsigned short* wrl[4];
    #pragma unroll
    for (int mt = 0; mt < 4; ++mt)
        arow[mt] = A + (size_t)(mblk + mt*16 + fm) * CH + q * 8;
    #pragma unroll
    for (int nt = 0; nt < 4; ++nt) {
        wrh[nt] = whi + (size_t)(n0 + nt*16 + fm) * CH + q * 8;
        wrl[nt] = wlo + (size_t)(n0 + nt*16 + fm) * CH + q * 8;
    }

    for (int k0 = 0; k0 < CH; k0 += 32) {
        s16x8 wh[4], wl[4], sh[4], sl[4];
        #pragma unroll
        for (int nt = 0; nt < 4; ++nt) {
            wh[nt] = *(const s16x8*)(wrh[nt] + k0);
            wl[nt] = *(const s16x8*)(wrl[nt] + k0);
        }
        #pragma unroll
        for (int mt = 0; mt < 4; ++mt) {
            const f32x4 r0 = *(const f32x4*)(arow[mt] + k0);
            const f32x4 r1 = *(const f32x4*)(arow[mt] + k0 + 4);
            union { s16x8 v; unsigned int u[4]; } ph, pl;
            split2(r0[0], r0[1], ph.u[0], pl.u[0]);
            split2(r0[2], r0[3], ph.u[1], pl.u[1]);
            split2(r1[0], r1[1], ph.u[2], pl.u[2]);
            split2(r1[2], r1[3], ph.u[3], pl.u[3]);
            sh[mt] = ph.v; sl[mt] = pl.v;
        }
        #pragma unroll
        for (int nt = 0; nt < 4; ++nt)
            #pragma unroll
            for (int mt = 0; mt < 4; ++mt) {
                acc[nt][mt] = __builtin_amdgcn_mfma_f32_16x16x32_bf16(wh[nt], sh[mt], acc[nt][mt], 0, 0, 0);
                acc[nt][mt] = __builtin_amdgcn_mfma_f32_16x16x32_bf16(wh[nt], sl[mt], acc[nt][mt], 0, 0, 0);
                acc[nt][mt] = __builtin_amdgcn_mfma_f32_16x16x32_bf16(wl[nt], sh[mt], acc[nt][mt], 0, 0, 0);
            }
    }

    #pragma unroll
    for (int nt = 0; nt < 4; ++nt) {
        #pragma unroll
        for (int r = 0; r < 4; ++r) {
            const int n = n0 + nt*16 + q*4 + r;
            if (n >= NTOT) continue;
            const float bs = (n < NOFF) ? b_off[n] : b_mask[n - NOFF];
            #pragma unroll
            for (int mt = 0; mt < 4; ++mt) {
                const int m = mblk + mt*16 + fm;
                const float val = acc[nt][mt][r] + bs;
                if (n < NOFF) offb[(size_t)m * NOFF + n] = val;
                else          mskb[(size_t)m * NMSK + (n - NOFF)] = val;
            }
        }
    }
}

// ---------------------------------------------------------------------------
// Deformable sampling. XCD-aware swizzle (bid%8 -> XCD) so each XCD covers one
// batch image; its v slice (3.2 MB) fits the 4 MB per-XCD L2.
// ---------------------------------------------------------------------------
__global__ __launch_bounds__(256)
void sample_kernel(const float* __restrict__ v,
                   const float* __restrict__ offb,
                   const float* __restrict__ mskb,
                   float* __restrict__ s)
{
    __shared__ alignas(16) float loff[POSB][NOFF];
    __shared__ alignas(16) float lmsk[POSB][NMSK];
    __shared__ alignas(16) float wtab[POSB][GRP*NP][4];
    __shared__ alignas(16) int   itab[POSB][GRP*NP][4];

    const int nblk = MTOT / POSB;            // 6272
    const int per  = nblk / 8;               // 784
    const int bid  = blockIdx.x;
    const int sw   = (bid % 8) * per + (bid / 8);
    const int n0 = sw * POSB;
    const int t = threadIdx.x;

    if (t < POSB * (NOFF/4)) {
        const int q = t / (NOFF/4), r = t % (NOFF/4);
        *(float4*)&loff[q][r*4] = *(const float4*)&offb[(size_t)(n0+q)*NOFF + r*4];
    } else if (t < POSB * (NOFF/4) + POSB * (NMSK/4)) {
        const int u = t - POSB * (NOFF/4);
        const int q = u / (NMSK/4), r = u % (NMSK/4);
        *(float4*)&lmsk[q][r*4] = *(const float4*)&mskb[(size_t)(n0+q)*NMSK + r*4];
    }
    __syncthreads();

    if (t < POSB * GRP) {
        const int q = t >> 3, g = t & 7;
        float* mm = &lmsk[q][g * NP];
        float mx = -1e30f;
        #pragma unroll
        for (int p = 0; p < NP; ++p) mx = fmaxf(mx, mm[p]);
        float sum = 0.0f;
        #pragma unroll
        for (int p = 0; p < NP; ++p) { const float e = __expf(mm[p] - mx); mm[p] = e; sum += e; }
        const float inv = 1.0f / sum;
        #pragma unroll
        for (int p = 0; p < NP; ++p) mm[p] *= inv;
    }
    __syncthreads();

    for (int u = t; u < POSB * GRP * NP; u += 256) {
        const int q = u / (GRP*NP), j = u % (GRP*NP);
        const int g = j / NP, p = j % NP;
        const int n = n0 + q;
        const int hw = n % HW;
        const int h = hw / WDIM, w = hw % WDIM;
        const float ox = loff[q][g*18 + p*2 + 0];
        const float oy = loff[q][g*18 + p*2 + 1];
        const float m  = lmsk[q][g*NP + p];
        const float px = (float)(w + p/3) + ox;
        const float py = (float)(h + p%3) + oy;
        const float fx = floorf(px), fy = floorf(py);
        const float wx = px - fx, wy = py - fy;
        const int x0 = (int)fx, y0 = (int)fy;
        const int x1 = x0 + 1, y1 = y0 + 1;
        const float vx0 = (x0 >= 1 && x0 < 57) ? 1.0f : 0.0f;
        const float vx1 = (x1 >= 1 && x1 < 57) ? 1.0f : 0.0f;
        const float vy0 = (y0 >= 1 && y0 < 57) ? 1.0f : 0.0f;
        const float vy1 = (y1 >= 1 && y1 < 57) ? 1.0f : 0.0f;
        const int x0c = min(max(x0, 1), 56), x1c = min(max(x1, 1), 56);
        const int y0c = min(max(y0, 1), 56), y1c = min(max(y1, 1), 56);
        wtab[q][j][0] = m * (1.0f-wx) * (1.0f-wy) * vx0 * vy0;
        wtab[q][j][1] = m * wx        * (1.0f-wy) * vx1 * vy0;
        wtab[q][j][2] = m * (1.0f-wx) * wy        * vx0 * vy1;
        wtab[q][j][3] = m * wx        * wy        * vx1 * vy1;
        itab[q][j][0] = ((y0c-1)*WDIM + (x0c-1)) * CH;
        itab[q][j][1] = ((y0c-1)*WDIM + (x1c-1)) * CH;
        itab[q][j][2] = ((y1c-1)*WDIM + (x0c-1)) * CH;
        itab[q][j][3] = ((y1c-1)*WDIM + (x1c-1)) * CH;
    }
    __syncthreads();

    const int q = t >> 6, lane = t & 63;
    const int n = n0 + q;
    const int b = n / HW;
    const int g = lane >> 3;
    const float* vb = v + (size_t)b*HW*CH + lane*4;
    float4 acc = {0.0f, 0.0f, 0.0f, 0.0f};
    #pragma unroll
    for (int p = 0; p < NP; ++p) {
        const int j = g*NP + p;
        const float4 wv = *(const float4*)&wtab[q][j][0];
        const int4  iv = *(const int4*)&itab[q][j][0];
        const float4 c0 = *(const float4*)(vb + iv.x);
        const float4 c1 = *(const float4*)(vb + iv.y);
        const float4 c2 = *(const float4*)(vb + iv.z);
        const float4 c3 = *(const float4*)(vb + iv.w);
        acc.x += wv.x*c0.x + wv.y*c1.x + wv.z*c2.x + wv.w*c3.x;
        acc.y += wv.x*c0.y + wv.y*c1.y + wv.z*c2.y + wv.w*c3.y;
        acc.z += wv.x*c0.z + wv.y*c1.z + wv.z*c2.z + wv.w*c3.z;
        acc.w += wv.x*c0.w + wv.y*c1.w + wv.z*c2.w + wv.w*c3.w;
    }
    *(float4*)&s[(size_t)n*CH + lane*4] = acc;
}

// ---------------------------------------------------------------------------
// GEMM out via bf16 MFMA: y = SiLU(BN(s @ w_out + b_out)) NCHW.
// ---------------------------------------------------------------------------
__global__ __launch_bounds__(256)
void gemm_out_mfma(const float* __restrict__ A,            // s [MTOT,256]
                   const unsigned short* __restrict__ whi, // [256 n][256 k] bf16
                   const unsigned short* __restrict__ wlo,
                   const float* __restrict__ bias,
                   const float* __restrict__ bn_g,
                   const float* __restrict__ bn_b,
                   const float* __restrict__ bn_mean,
                   const float* __restrict__ bn_var,
                   float* __restrict__ y)                  // [B,256,3136]
{
    const int m0 = blockIdx.x * 256;
    const int n0 = blockIdx.y * 64;
    const int t = threadIdx.x;
    const int lane = t & 63, wv = t >> 6;
    const int mblk = m0 + wv * 64;
    const int fm = lane & 15;
    const int q  = lane >> 4;

    f32x4 acc[4][4];
    const f32x4 zero = {0.0f, 0.0f, 0.0f, 0.0f};
    #pragma unroll
    for (int i = 0; i < 4; ++i)
        #pragma unroll
        for (int j = 0; j < 4; ++j) acc[i][j] = zero;

    const float* arow[4];
    const unsigned short* wrh[4];
    const unsigned short* wrl[4];
    #pragma unroll
    for (int mt = 0; mt < 4; ++mt)
        arow[mt] = A + (size_t)(mblk + mt*16 + fm) * CH + q * 8;
    #pragma unroll
    for (int nt = 0; nt < 4; ++nt) {
        wrh[nt] = whi + (size_t)(n0 + nt*16 + fm) * CH + q * 8;
        wrl[nt] = wlo + (size_t)(n0 + nt*16 + fm) * CH + q * 8;
    }

    for (int k0 = 0; k0 < CH; k0 += 32) {
        s16x8 wh[4], wl[4], sh[4], sl[4];
        #pragma unroll
        for (int nt = 0; nt < 4; ++nt) {
            wh[nt] = *(const s16x8*)(wrh[nt] + k0);
            wl[nt] = *(const s16x8*)(wrl[nt] + k0);
        }
        #pragma unroll
        for (int mt = 0; mt < 4; ++mt) {
            const f32x4 r0 = *(const f32x4*)(arow[mt] + k0);
            const f32x4 r1 = *(const f32x4*)(arow[mt] + k0 + 4);
            union { s16x8 v; unsigned int u[4]; } ph, pl;
            split2(r0[0], r0[1], ph.u[0], pl.u[0]);
            split2(r0[2], r0[3], ph.u[1], pl.u[1]);
            split2(r1[0], r1[1], ph.u[2], pl.u[2]);
            split2(r1[2], r1[3], ph.u[3], pl.u[3]);
            sh[mt] = ph.v; sl[mt] = pl.v;
        }
        #pragma unroll
        for (int nt = 0; nt < 4; ++nt)
            #pragma unroll
            for (int mt = 0; mt < 4; ++mt) {
                acc[nt][mt] = __builtin_amdgcn_mfma_f32_16x16x32_bf16(wh[nt], sh[mt], acc[nt][mt], 0, 0, 0);
                acc[nt][mt] = __builtin_amdgcn_mfma_f32_16x16x32_bf16(wh[nt], sl[mt], acc[nt][mt], 0, 0, 0);
                acc[nt][mt] = __builtin_amdgcn_mfma_f32_16x16x32_bf16(wl[nt], sh[mt], acc[nt][mt], 0, 0, 0);
            }
    }

    #pragma unroll
    for (int nt = 0; nt < 4; ++nt) {
        #pragma unroll
        for (int r = 0; r < 4; ++r) {
            const int n = n0 + nt*16 + q*4 + r;
            const float sc = bn_g[n] * rsqrtf(bn_var[n] + 1e-5f);
            const float sb = bn_b[n] - bn_mean[n] * sc;
            const float bs = bias[n];
            #pragma unroll
            for (int mt = 0; mt < 4; ++mt) {
                const int mm = mblk + mt*16;
                const size_t base = (size_t)(mm / HW) * CH * HW + (mm % HW);
                float val = (acc[nt][mt][r] + bs) * sc + sb;
                y[base + (size_t)n * HW + fm] = val / (1.0f + expf(-val));
            }
        }
    }
}

extern "C" void kernel_launch(void* const* d_in, const int* in_sizes, int n_in,
                              void* d_out, int out_size, void* d_ws, size_t ws_size,
                              hipStream_t stream) {
    const float* x      = (const float*)d_in[0];
    const float* w_in   = (const float*)d_in[1];
    const float* b_in   = (const float*)d_in[2];
    const float* dw_w   = (const float*)d_in[3];
    const float* dw_b   = (const float*)d_in[4];
    const float* ln_g   = (const float*)d_in[5];
    const float* ln_b   = (const float*)d_in[6];
    const float* w_off  = (const float*)d_in[7];
    const float* b_off  = (const float*)d_in[8];
    const float* w_mask = (const float*)d_in[9];
    const float* b_mask = (const float*)d_in[10];
    const float* w_out  = (const float*)d_in[11];
    const float* b_out  = (const float*)d_in[12];
    const float* bn_g   = (const float*)d_in[13];
    const float* bn_b   = (const float*)d_in[14];
    const float* bn_mean= (const float*)d_in[15];
    const float* bn_var = (const float*)d_in[16];
    float* out = (float*)d_out;

    const size_t SZ = (size_t)MTOT * CH;                 // elements
    // Layout: v | xt_hi | xt_lo | fh | fl | offb | mskb | 6x weight splits
    // (fh+fl occupy exactly the bytes of one SZ f32 array)
    const size_t need_new =
        (3 * SZ + (size_t)MTOT * NOFF + (size_t)MTOT * NMSK) * sizeof(float)
        + 6 * (size_t)CH * CH * sizeof(unsigned short);

    if (ws_size >= need_new) {
        // -------- main path --------
        float* ws = (float*)d_ws;
        float* v    = ws;                                          // SZ f32
        unsigned short* xt_hi = (unsigned short*)(v + SZ);         // SZ us
        unsigned short* xt_lo = xt_hi + SZ;                        // SZ us
        unsigned short* fh    = xt_lo + SZ;                        // SZ us
        unsigned short* fl    = fh + SZ;                           // SZ us
        float* offb = (float*)(fl + SZ);                           // MTOT*NOFF
        float* mskb = offb + (size_t)MTOT * NOFF;                  // MTOT*NMSK
        unsigned short* wt_hi  = (unsigned short*)(mskb + (size_t)MTOT * NMSK);
        unsigned short* wt_lo  = wt_hi + CH * CH;
        unsigned short* wt2_hi = wt_lo + CH * CH;
        unsigned short* wt2_lo = wt2_hi + CH * CH;
        unsigned short* wt3_hi = wt2_lo + CH * CH;
        unsigned short* wt3_lo = wt3_hi + CH * CH;
        // s overlays xt region (xt consumed by gemm_in + dw before sample).
        float* s = (float*)xt_hi;

        wt_split_kernel<<<dim3(4, 4), dim3(256), 0, stream>>>(w_out, wt_hi, wt_lo);
        wt_split_kernel<<<dim3(4, 4), dim3(256), 0, stream>>>(w_in, wt3_hi, wt3_lo);
        wt2_split_kernel<<<dim3(16), dim3(256), 0, stream>>>(w_off, w_mask, wt2_hi, wt2_lo);
        xt_split_kernel<<<dim3(HW/64, CH/64, BATCH), dim3(256), 0, stream>>>(x, xt_hi, xt_lo);
        gemm_in_mfma<<<dim3(MTOT/256, CH/64), dim3(256), 0, stream>>>(
            xt_hi, xt_lo, wt3_hi, wt3_lo, b_in, v);
        dw_ln_gelu_nhwc_split<<<dim3(MTOT/POSB), dim3(256), 0, stream>>>(
            xt_hi, xt_lo, dw_w, dw_b, ln_g, ln_b, fh, fl);
        gemm_offmask_bf16<<<dim3((MTOT/64) * 4), dim3(256), 0, stream>>>(
            fh, fl, wt2_hi, wt2_lo, b_off, b_mask, offb, mskb);
        sample_kernel<<<dim3(MTOT/POSB), dim3(256), 0, stream>>>(v, offb, mskb, s);
        gemm_out_mfma<<<dim3(MTOT/256, CH/64), dim3(256), 0, stream>>>(
            s, wt_hi, wt_lo, b_out, bn_g, bn_b, bn_mean, bn_var, out);
    } else {
        // -------- fallback: previous verified path (xt overlays f) --------
        float* ws   = (float*)d_ws;
        float* v    = ws;                                   // SZ f32
        float* f    = v + SZ;                               // SZ f32
        float* offb = f + SZ;                               // MTOT*NOFF
        float* mskb = offb + (size_t)MTOT * NOFF;           // MTOT*NMSK
        float* s    = f;                                    // reuse f buffer
        unsigned short* wt_hi  = (unsigned short*)(mskb + (size_t)MTOT * NMSK);
        unsigned short* wt_lo  = wt_hi + CH * CH;
        unsigned short* wt2_hi = wt_lo + CH * CH;
        unsigned short* wt2_lo = wt2_hi + CH * CH;
        unsigned short* wt3_hi = wt2_lo + CH * CH;
        unsigned short* wt3_lo = wt3_hi + CH * CH;
        unsigned short* xt_hi = (unsigned short*)f;
        unsigned short* xt_lo = xt_hi + SZ;

        wt_split_kernel<<<dim3(4, 4), dim3(256), 0, stream>>>(w_out, wt_hi, wt_lo);
        wt_split_kernel<<<dim3(4, 4), dim3(256), 0, stream>>>(w_in, wt3_hi, wt3_lo);
        wt2_split_kernel<<<dim3(16), dim3(256), 0, stream>>>(w_off, w_mask, wt2_hi, wt2_lo);
        xt_split_kernel<<<dim3(HW/64, CH/64, BATCH), dim3(256), 0, stream>>>(x, xt_hi, xt_lo);
        gemm_in_mfma<<<dim3(MTOT/256, CH/64), dim3(256), 0, stream>>>(
            xt_hi, xt_lo, wt3_hi, wt3_lo, b_in, v);
        dw_ln_gelu_kernel<<<dim3(HDIM, BATCH), dim3(256), 0, stream>>>(x, dw_w, dw_b, ln_g, ln_b, f);
        gemm_offmask_mfma<<<dim3(MTOT/256, 4), dim3(256), 0, stream>>>(
            f, wt2_hi, wt2_lo, b_off, b_mask, offb, mskb);
        sample_kernel<<<dim3(MTOT/POSB), dim3(256), 0, stream>>>(v, offb, mskb, s);
        gemm_out_mfma<<<dim3(MTOT/256, CH/64), dim3(256), 0, stream>>>(
            s, wt_hi, wt_lo, b_out, bn_g, bn_b, bn_mean, bn_var, out);
    }
}

// Round 4
// 294.761 us; speedup vs baseline: 1.1187x; 1.1187x over previous
//
#include <hip/hip_runtime.h>
#include <math.h>

// Problem constants
#define BATCH 8
#define CH    256
#define HDIM  56
#define WDIM  56
#define HW    (HDIM*WDIM)          // 3136
#define MTOT  (BATCH*HW)           // 25088
#define GRP   8
#define GC    32
#define NP    9                    // K*K
#define NOFF  (GRP*NP*2)           // 144
#define NMSK  (GRP*NP)             // 72
#define NTOT  (NOFF+NMSK)          // 216
#define POSB  4                    // positions per sample block

typedef float f32x4 __attribute__((ext_vector_type(4)));
typedef short s16x8 __attribute__((ext_vector_type(8)));

// split a,b into packed bf16 hi (truncation) and bf16 lo (exact remainder, truncated)
__device__ inline void split2(float a, float b, unsigned int& hp, unsigned int& lp)
{
    const unsigned int ua = __float_as_uint(a), ub = __float_as_uint(b);
    hp = (ub & 0xffff0000u) | (ua >> 16);
    const float ha = __uint_as_float(ua & 0xffff0000u);
    const float hb = __uint_as_float(ub & 0xffff0000u);
    const unsigned int la = __float_as_uint(a - ha), lb = __float_as_uint(b - hb);
    lp = (lb & 0xffff0000u) | (la >> 16);
}

// ---------------------------------------------------------------------------
// Transpose + split x (NCHW) -> xt_hi/xt_lo [m][k] bf16. 64x64 LDS tiles.
// ---------------------------------------------------------------------------
__global__ __launch_bounds__(256)
void xt_split_kernel(const float* __restrict__ x,
                     unsigned short* __restrict__ hi,
                     unsigned short* __restrict__ lo)
{
    __shared__ float lds[64][68];
    const int hw0 = blockIdx.x * 64;       // 49 tiles (3136/64)
    const int k0  = blockIdx.y * 64;       // 4 tiles
    const int b   = blockIdx.z;            // 8
    const int t = threadIdx.x;
    #pragma unroll
    for (int p = 0; p < 4; ++p) {
        const int kr = (t >> 4) + p * 16;
        const int hc = (t & 15) * 4;
        *(float4*)&lds[kr][hc] =
            *(const float4*)(x + ((size_t)b * CH + k0 + kr) * HW + hw0 + hc);
    }
    __syncthreads();
    const int ml = t >> 2;             // m-row 0..63
    const int kc = (t & 3) * 16;       // k base 0,16,32,48
    unsigned int hbuf[8], lbuf[8];
    #pragma unroll
    for (int j = 0; j < 16; j += 2)
        split2(lds[kc + j][ml], lds[kc + j + 1][ml], hbuf[j >> 1], lbuf[j >> 1]);
    const size_t row = (size_t)(b * HW + hw0 + ml) * CH + k0 + kc;
    *(uint4*)&hi[row]     = *(uint4*)&hbuf[0];
    *(uint4*)&hi[row + 8] = *(uint4*)&hbuf[4];
    *(uint4*)&lo[row]     = *(uint4*)&lbuf[0];
    *(uint4*)&lo[row + 8] = *(uint4*)&lbuf[4];
}

// ---------------------------------------------------------------------------
// GEMM via bf16 MFMA: out = A @ W^T + bias (256-wide rows). Barrier-free.
// Used for BOTH the input projection (v) and the offset/mask projection (omb):
// identical structure is the control experiment — only pointers differ.
// ---------------------------------------------------------------------------
__global__ __launch_bounds__(256)
void gemm_in_mfma(const unsigned short* __restrict__ xhi, // [m][k]
                  const unsigned short* __restrict__ xlo,
                  const unsigned short* __restrict__ whi, // [n][k]
                  const unsigned short* __restrict__ wlo,
                  const float* __restrict__ bias,
                  float* __restrict__ v)                  // [MTOT,256]
{
    const int m0 = blockIdx.x * 256;
    const int n0 = blockIdx.y * 64;
    const int t = threadIdx.x;
    const int lane = t & 63, wv = t >> 6;
    const int mblk = m0 + wv * 64;
    const int fm = lane & 15;
    const int q  = lane >> 4;

    f32x4 acc[4][4];              // [nt][mt]
    const f32x4 zero = {0.0f, 0.0f, 0.0f, 0.0f};
    #pragma unroll
    for (int i = 0; i < 4; ++i)
        #pragma unroll
        for (int j = 0; j < 4; ++j) acc[i][j] = zero;

    const unsigned short *xrh[4], *xrl[4], *wrh[4], *wrl[4];
    #pragma unroll
    for (int mt = 0; mt < 4; ++mt) {
        xrh[mt] = xhi + (size_t)(mblk + mt*16 + fm) * CH + q * 8;
        xrl[mt] = xlo + (size_t)(mblk + mt*16 + fm) * CH + q * 8;
    }
    #pragma unroll
    for (int nt = 0; nt < 4; ++nt) {
        wrh[nt] = whi + (size_t)(n0 + nt*16 + fm) * CH + q * 8;
        wrl[nt] = wlo + (size_t)(n0 + nt*16 + fm) * CH + q * 8;
    }

    for (int k0 = 0; k0 < CH; k0 += 32) {
        s16x8 wh[4], wl[4], ah[4], al[4];
        #pragma unroll
        for (int nt = 0; nt < 4; ++nt) {
            wh[nt] = *(const s16x8*)(wrh[nt] + k0);
            wl[nt] = *(const s16x8*)(wrl[nt] + k0);
        }
        #pragma unroll
        for (int mt = 0; mt < 4; ++mt) {
            ah[mt] = *(const s16x8*)(xrh[mt] + k0);
            al[mt] = *(const s16x8*)(xrl[mt] + k0);
        }
        #pragma unroll
        for (int nt = 0; nt < 4; ++nt)
            #pragma unroll
            for (int mt = 0; mt < 4; ++mt) {
                acc[nt][mt] = __builtin_amdgcn_mfma_f32_16x16x32_bf16(wh[nt], ah[mt], acc[nt][mt], 0, 0, 0);
                acc[nt][mt] = __builtin_amdgcn_mfma_f32_16x16x32_bf16(wh[nt], al[mt], acc[nt][mt], 0, 0, 0);
                acc[nt][mt] = __builtin_amdgcn_mfma_f32_16x16x32_bf16(wl[nt], ah[mt], acc[nt][mt], 0, 0, 0);
            }
    }

    #pragma unroll
    for (int nt = 0; nt < 4; ++nt) {
        const float4 b4 = *(const float4*)&bias[n0 + nt*16 + q*4];
        #pragma unroll
        for (int mt = 0; mt < 4; ++mt) {
            f32x4 o = acc[nt][mt];
            o[0] += b4.x; o[1] += b4.y; o[2] += b4.z; o[3] += b4.w;
            *(f32x4*)&v[(size_t)(mblk + mt*16 + fm) * CH + n0 + nt*16 + q*4] = o;
        }
    }
}

// ---------------------------------------------------------------------------
// OLD fallback: fused depthwise 3x3 + bias + LayerNorm(C) + exact GELU -> f.
// ---------------------------------------------------------------------------
__global__ __launch_bounds__(256)
void dw_ln_gelu_kernel(const float* __restrict__ x,
                       const float* __restrict__ dw_w,
                       const float* __restrict__ dw_b,
                       const float* __restrict__ ln_g,
                       const float* __restrict__ ln_b,
                       float* __restrict__ f)
{
    __shared__ float tile[WDIM][CH + 1];
    __shared__ float red1[WDIM][4], red2[WDIM][4];
    __shared__ float meanA[WDIM], rstdA[WDIM];

    const int h = blockIdx.x;
    const int b = blockIdx.y;
    const int t = threadIdx.x;
    const int lane = t & 63;
    const int wv   = t >> 6;

    for (int cg = 0; cg < CH / 4; ++cg) {
        const int c = cg * 4 + wv;
        const float* xp = x + ((size_t)b * CH + c) * HW;
        float rowv[3];
        #pragma unroll
        for (int r = 0; r < 3; ++r) {
            const int hh = h + r - 1;
            rowv[r] = (lane < WDIM && hh >= 0 && hh < HDIM) ? xp[hh * WDIM + lane] : 0.0f;
        }
        const float* wp = dw_w + c * 9;
        float acc = dw_b[c];
        #pragma unroll
        for (int r = 0; r < 3; ++r) {
            float L = __shfl_up(rowv[r], 1);
            float R = __shfl_down(rowv[r], 1);
            if (lane == 0) L = 0.0f;
            acc += L * wp[r * 3 + 0] + rowv[r] * wp[r * 3 + 1] + R * wp[r * 3 + 2];
        }
        if (lane < WDIM)
            tile[lane][c] = acc;
    }
    __syncthreads();

    if (t < 224) {
        const int p = t >> 2, q = t & 3;
        float s1 = 0.0f, s2 = 0.0f;
        #pragma unroll 8
        for (int i = 0; i < 64; ++i) {
            const float v = tile[p][q * 64 + i];
            s1 += v; s2 += v * v;
        }
        red1[p][q] = s1; red2[p][q] = s2;
    }
    __syncthreads();
    if (t < WDIM) {
        const float s1 = red1[t][0] + red1[t][1] + red1[t][2] + red1[t][3];
        const float s2 = red2[t][0] + red2[t][1] + red2[t][2] + red2[t][3];
        const float m = s1 * (1.0f / 256.0f);
        const float var = s2 * (1.0f / 256.0f) - m * m;
        meanA[t] = m;
        rstdA[t] = rsqrtf(var + 1e-5f);
    }
    __syncthreads();

    const float gam = ln_g[t], bet = ln_b[t];
    const size_t n0 = (size_t)(b * HDIM + h) * WDIM;
    for (int p = 0; p < WDIM; ++p) {
        const float xn = (tile[p][t] - meanA[p]) * rstdA[p] * gam + bet;
        const float g = 0.5f * xn * (1.0f + erff(xn * 0.70710678118654752f));
        f[(n0 + p) * CH + t] = g;
    }
}

// ---------------------------------------------------------------------------
// Per-position-wave depthwise 3x3 + bias + LN + GELU from NHWC bf16 hi/lo xt,
// output stored PRE-SPLIT as bf16 hi/lo (bit-identical to what the GEMM's
// in-loop split2 would produce). One wave per position, no LDS hot path.
// ---------------------------------------------------------------------------
__global__ __launch_bounds__(256)
void dw_ln_gelu_nhwc_split(const unsigned short* __restrict__ xhi,
                           const unsigned short* __restrict__ xlo,
                           const float* __restrict__ dw_w,   // [256][9]
                           const float* __restrict__ dw_b,
                           const float* __restrict__ ln_g,
                           const float* __restrict__ ln_b,
                           unsigned short* __restrict__ fh,  // [MTOT][256]
                           unsigned short* __restrict__ fl)  // [MTOT][256]
{
    __shared__ float wt[NP][CH];                       // transposed dw weights
    __shared__ float lbias[CH], lgam[CH], lbet[CH];

    const int t = threadIdx.x;
    {
        const float* wp = dw_w + t * NP;
        #pragma unroll
        for (int p = 0; p < NP; ++p) wt[p][t] = wp[p];
        lbias[t] = dw_b[t]; lgam[t] = ln_g[t]; lbet[t] = ln_b[t];
    }
    __syncthreads();

    const int nblk = MTOT / POSB;          // 6272
    const int per  = nblk / 8;             // 784
    const int bid  = blockIdx.x;
    const int sw   = (bid & 7) * per + (bid >> 3);
    const int q    = t >> 6, lane = t & 63;
    const int n    = sw * POSB + q;
    const int b    = n / HW;
    const int hw   = n % HW;
    const int h    = hw / WDIM, w = hw % WDIM;
    const int c4   = lane * 4;
    const size_t base = (size_t)b * HW * CH + c4;

    float ax = 0.0f, ay = 0.0f, az = 0.0f, aw = 0.0f;
    #pragma unroll
    for (int p = 0; p < NP; ++p) {
        const int hh = h + p / 3 - 1;
        const int ww = w + p % 3 - 1;
        if ((unsigned)hh >= (unsigned)HDIM || (unsigned)ww >= (unsigned)WDIM)
            continue;                       // wave-uniform branch (h,w per-wave)
        const size_t idx = base + (size_t)(hh * WDIM + ww) * CH;
        const ushort4 uh = *(const ushort4*)(xhi + idx);
        const ushort4 ul = *(const ushort4*)(xlo + idx);
        const float4 wv = *(const float4*)&wt[p][c4];
        ax = fmaf(__uint_as_float((unsigned)uh.x << 16), wv.x,
             fmaf(__uint_as_float((unsigned)ul.x << 16), wv.x, ax));
        ay = fmaf(__uint_as_float((unsigned)uh.y << 16), wv.y,
             fmaf(__uint_as_float((unsigned)ul.y << 16), wv.y, ay));
        az = fmaf(__uint_as_float((unsigned)uh.z << 16), wv.z,
             fmaf(__uint_as_float((unsigned)ul.z << 16), wv.z, az));
        aw = fmaf(__uint_as_float((unsigned)uh.w << 16), wv.w,
             fmaf(__uint_as_float((unsigned)ul.w << 16), wv.w, aw));
    }
    {
        const float4 b4 = *(const float4*)&lbias[c4];
        ax += b4.x; ay += b4.y; az += b4.z; aw += b4.w;
    }

    // LayerNorm over the wave's 256 channel values: in-wave butterfly.
    float s1 = ax + ay + az + aw;
    float s2 = ax*ax + ay*ay + az*az + aw*aw;
    #pragma unroll
    for (int off = 32; off > 0; off >>= 1) {
        s1 += __shfl_xor(s1, off);
        s2 += __shfl_xor(s2, off);
    }
    const float mean = s1 * (1.0f / 256.0f);
    const float rstd = rsqrtf(s2 * (1.0f / 256.0f) - mean * mean + 1e-5f);

    const float4 g4 = *(const float4*)&lgam[c4];
    const float4 e4 = *(const float4*)&lbet[c4];
    const float x0 = (ax - mean) * rstd * g4.x + e4.x;
    const float x1 = (ay - mean) * rstd * g4.y + e4.y;
    const float x2 = (az - mean) * rstd * g4.z + e4.z;
    const float x3 = (aw - mean) * rstd * g4.w + e4.w;
    const float o0 = 0.5f * x0 * (1.0f + erff(x0 * 0.70710678118654752f));
    const float o1 = 0.5f * x1 * (1.0f + erff(x1 * 0.70710678118654752f));
    const float o2 = 0.5f * x2 * (1.0f + erff(x2 * 0.70710678118654752f));
    const float o3 = 0.5f * x3 * (1.0f + erff(x3 * 0.70710678118654752f));

    unsigned int hp0, lp0, hp1, lp1;
    split2(o0, o1, hp0, lp0);
    split2(o2, o3, hp1, lp1);
    *(uint2*)&fh[(size_t)n * CH + c4] = make_uint2(hp0, hp1);
    *(uint2*)&fl[(size_t)n * CH + c4] = make_uint2(lp0, lp1);
}

// ---------------------------------------------------------------------------
// Transpose + hi/lo bf16 split of a [256k][256n] fp32 weight -> [n][k] bf16.
// ---------------------------------------------------------------------------
__global__ __launch_bounds__(256)
void wt_split_kernel(const float* __restrict__ w,
                     unsigned short* __restrict__ hi,
                     unsigned short* __restrict__ lo)
{
    __shared__ float lds[64][68];
    const int kt = blockIdx.x * 64, nt = blockIdx.y * 64;
    const int t = threadIdx.x;
    #pragma unroll
    for (int p = 0; p < 4; ++p) {
        const int kr = (t >> 4) + p * 16, nc = (t & 15) * 4;
        *(float4*)&lds[kr][nc] = *(const float4*)(w + (size_t)(kt + kr) * CH + nt + nc);
    }
    __syncthreads();
    const int nl = t >> 2, kc = (t & 3) * 16;
    #pragma unroll
    for (int j = 0; j < 16; j += 2) {
        const float f0 = lds[kc + j][nl], f1 = lds[kc + j + 1][nl];
        unsigned int hp, lp;
        split2(f0, f1, hp, lp);
        *(unsigned int*)&hi[(size_t)(nt + nl) * CH + kt + kc + j] = hp;
        *(unsigned int*)&lo[(size_t)(nt + nl) * CH + kt + kc + j] = lp;
    }
}

// ---------------------------------------------------------------------------
// Transpose + split of [w_off | w_mask] -> wt2_hi/lo [256 n_pad][256 k] bf16.
// Also builds bcat[256] = [b_off | b_mask | 0] (block 0 only).
// ---------------------------------------------------------------------------
__global__ __launch_bounds__(256)
void wt2_split_kernel(const float* __restrict__ w_off,   // [256][144]
                      const float* __restrict__ w_mask,  // [256][72]
                      const float* __restrict__ b_off,
                      const float* __restrict__ b_mask,
                      unsigned short* __restrict__ hi,
                      unsigned short* __restrict__ lo,
                      float* __restrict__ bcat)          // [256]
{
    const int n = threadIdx.x;
    if (blockIdx.x == 0) {
        bcat[n] = (n < NOFF) ? b_off[n] : ((n < NTOT) ? b_mask[n - NOFF] : 0.0f);
    }
    const int k0 = blockIdx.x * 16;
    #pragma unroll
    for (int j = 0; j < 16; j += 2) {
        const int k = k0 + j;
        float f0 = 0.0f, f1 = 0.0f;
        if (n < NOFF) {
            f0 = w_off[(size_t)k * NOFF + n];
            f1 = w_off[(size_t)(k + 1) * NOFF + n];
        } else if (n < NTOT) {
            f0 = w_mask[(size_t)k * NMSK + (n - NOFF)];
            f1 = w_mask[(size_t)(k + 1) * NMSK + (n - NOFF)];
        }
        unsigned int hp, lp;
        split2(f0, f1, hp, lp);
        *(unsigned int*)&hi[(size_t)n * CH + k] = hp;
        *(unsigned int*)&lo[(size_t)n * CH + k] = lp;
    }
}

// ---------------------------------------------------------------------------
// Fallback: offset+mask GEMM via bf16 MFMA (reads f32 f, scattered epilogue).
// ---------------------------------------------------------------------------
__global__ __launch_bounds__(256)
void gemm_offmask_mfma(const float* __restrict__ A,            // f [MTOT,256]
                       const unsigned short* __restrict__ whi, // [256][256] bf16
                       const unsigned short* __restrict__ wlo,
                       const float* __restrict__ b_off,
                       const float* __restrict__ b_mask,
                       float* __restrict__ offb,               // [MTOT,144]
                       float* __restrict__ mskb)               // [MTOT,72]
{
    const int m0 = blockIdx.x * 256;
    const int n0 = blockIdx.y * 64;
    const int t = threadIdx.x;
    const int lane = t & 63, wv = t >> 6;
    const int mblk = m0 + wv * 64;
    const int fm = lane & 15;
    const int q  = lane >> 4;

    f32x4 acc[4][4];
    const f32x4 zero = {0.0f, 0.0f, 0.0f, 0.0f};
    #pragma unroll
    for (int i = 0; i < 4; ++i)
        #pragma unroll
        for (int j = 0; j < 4; ++j) acc[i][j] = zero;

    const float* arow[4];
    const unsigned short* wrh[4];
    const unsigned short* wrl[4];
    #pragma unroll
    for (int mt = 0; mt < 4; ++mt)
        arow[mt] = A + (size_t)(mblk + mt*16 + fm) * CH + q * 8;
    #pragma unroll
    for (int nt = 0; nt < 4; ++nt) {
        wrh[nt] = whi + (size_t)(n0 + nt*16 + fm) * CH + q * 8;
        wrl[nt] = wlo + (size_t)(n0 + nt*16 + fm) * CH + q * 8;
    }

    for (int k0 = 0; k0 < CH; k0 += 32) {
        s16x8 wh[4], wl[4], sh[4], sl[4];
        #pragma unroll
        for (int nt = 0; nt < 4; ++nt) {
            wh[nt] = *(const s16x8*)(wrh[nt] + k0);
            wl[nt] = *(const s16x8*)(wrl[nt] + k0);
        }
        #pragma unroll
        for (int mt = 0; mt < 4; ++mt) {
            const f32x4 r0 = *(const f32x4*)(arow[mt] + k0);
            const f32x4 r1 = *(const f32x4*)(arow[mt] + k0 + 4);
            union { s16x8 v; unsigned int u[4]; } ph, pl;
            split2(r0[0], r0[1], ph.u[0], pl.u[0]);
            split2(r0[2], r0[3], ph.u[1], pl.u[1]);
            split2(r1[0], r1[1], ph.u[2], pl.u[2]);
            split2(r1[2], r1[3], ph.u[3], pl.u[3]);
            sh[mt] = ph.v; sl[mt] = pl.v;
        }
        #pragma unroll
        for (int nt = 0; nt < 4; ++nt)
            #pragma unroll
            for (int mt = 0; mt < 4; ++mt) {
                acc[nt][mt] = __builtin_amdgcn_mfma_f32_16x16x32_bf16(wh[nt], sh[mt], acc[nt][mt], 0, 0, 0);
                acc[nt][mt] = __builtin_amdgcn_mfma_f32_16x16x32_bf16(wh[nt], sl[mt], acc[nt][mt], 0, 0, 0);
                acc[nt][mt] = __builtin_amdgcn_mfma_f32_16x16x32_bf16(wl[nt], sh[mt], acc[nt][mt], 0, 0, 0);
            }
    }

    #pragma unroll
    for (int nt = 0; nt < 4; ++nt) {
        #pragma unroll
        for (int r = 0; r < 4; ++r) {
            const int n = n0 + nt*16 + q*4 + r;
            if (n >= NTOT) continue;
            const float bs = (n < NOFF) ? b_off[n] : b_mask[n - NOFF];
            #pragma unroll
            for (int mt = 0; mt < 4; ++mt) {
                const int m = mblk + mt*16 + fm;
                const float val = acc[nt][mt][r] + bs;
                if (n < NOFF) offb[(size_t)m * NOFF + n] = val;
                else          mskb[(size_t)m * NMSK + (n - NOFF)] = val;
            }
        }
    }
}

// ---------------------------------------------------------------------------
// Deformable sampling reading the padded omb [MTOT][256] rows
// (cols 0..143 offsets, 144..215 mask logits). XCD-aware swizzle.
// ---------------------------------------------------------------------------
__global__ __launch_bounds__(256)
void sample_kernel_omb(const float* __restrict__ v,
                       const float* __restrict__ omb,
                       float* __restrict__ s)
{
    __shared__ alignas(16) float loff[POSB][NOFF];
    __shared__ alignas(16) float lmsk[POSB][NMSK];
    __shared__ alignas(16) float wtab[POSB][GRP*NP][4];
    __shared__ alignas(16) int   itab[POSB][GRP*NP][4];

    const int nblk = MTOT / POSB;            // 6272
    const int per  = nblk / 8;               // 784
    const int bid  = blockIdx.x;
    const int sw   = (bid % 8) * per + (bid / 8);
    const int n0 = sw * POSB;
    const int t = threadIdx.x;

    if (t < POSB * (NOFF/4)) {
        const int q = t / (NOFF/4), r = t % (NOFF/4);
        *(float4*)&loff[q][r*4] = *(const float4*)&omb[(size_t)(n0+q)*CH + r*4];
    } else if (t < POSB * (NOFF/4) + POSB * (NMSK/4)) {
        const int u = t - POSB * (NOFF/4);
        const int q = u / (NMSK/4), r = u % (NMSK/4);
        *(float4*)&lmsk[q][r*4] = *(const float4*)&omb[(size_t)(n0+q)*CH + NOFF + r*4];
    }
    __syncthreads();

    if (t < POSB * GRP) {
        const int q = t >> 3, g = t & 7;
        float* mm = &lmsk[q][g * NP];
        float mx = -1e30f;
        #pragma unroll
        for (int p = 0; p < NP; ++p) mx = fmaxf(mx, mm[p]);
        float sum = 0.0f;
        #pragma unroll
        for (int p = 0; p < NP; ++p) { const float e = __expf(mm[p] - mx); mm[p] = e; sum += e; }
        const float inv = 1.0f / sum;
        #pragma unroll
        for (int p = 0; p < NP; ++p) mm[p] *= inv;
    }
    __syncthreads();

    for (int u = t; u < POSB * GRP * NP; u += 256) {
        const int q = u / (GRP*NP), j = u % (GRP*NP);
        const int g = j / NP, p = j % NP;
        const int n = n0 + q;
        const int hw = n % HW;
        const int h = hw / WDIM, w = hw % WDIM;
        const float ox = loff[q][g*18 + p*2 + 0];
        const float oy = loff[q][g*18 + p*2 + 1];
        const float m  = lmsk[q][g*NP + p];
        const float px = (float)(w + p/3) + ox;
        const float py = (float)(h + p%3) + oy;
        const float fx = floorf(px), fy = floorf(py);
        const float wx = px - fx, wy = py - fy;
        const int x0 = (int)fx, y0 = (int)fy;
        const int x1 = x0 + 1, y1 = y0 + 1;
        const float vx0 = (x0 >= 1 && x0 < 57) ? 1.0f : 0.0f;
        const float vx1 = (x1 >= 1 && x1 < 57) ? 1.0f : 0.0f;
        const float vy0 = (y0 >= 1 && y0 < 57) ? 1.0f : 0.0f;
        const float vy1 = (y1 >= 1 && y1 < 57) ? 1.0f : 0.0f;
        const int x0c = min(max(x0, 1), 56), x1c = min(max(x1, 1), 56);
        const int y0c = min(max(y0, 1), 56), y1c = min(max(y1, 1), 56);
        wtab[q][j][0] = m * (1.0f-wx) * (1.0f-wy) * vx0 * vy0;
        wtab[q][j][1] = m * wx        * (1.0f-wy) * vx1 * vy0;
        wtab[q][j][2] = m * (1.0f-wx) * wy        * vx0 * vy1;
        wtab[q][j][3] = m * wx        * wy        * vx1 * vy1;
        itab[q][j][0] = ((y0c-1)*WDIM + (x0c-1)) * CH;
        itab[q][j][1] = ((y0c-1)*WDIM + (x1c-1)) * CH;
        itab[q][j][2] = ((y1c-1)*WDIM + (x0c-1)) * CH;
        itab[q][j][3] = ((y1c-1)*WDIM + (x1c-1)) * CH;
    }
    __syncthreads();

    const int q = t >> 6, lane = t & 63;
    const int n = n0 + q;
    const int b = n / HW;
    const int g = lane >> 3;
    const float* vb = v + (size_t)b*HW*CH + lane*4;
    float4 acc = {0.0f, 0.0f, 0.0f, 0.0f};
    #pragma unroll
    for (int p = 0; p < NP; ++p) {
        const int j = g*NP + p;
        const float4 wv = *(const float4*)&wtab[q][j][0];
        const int4  iv = *(const int4*)&itab[q][j][0];
        const float4 c0 = *(const float4*)(vb + iv.x);
        const float4 c1 = *(const float4*)(vb + iv.y);
        const float4 c2 = *(const float4*)(vb + iv.z);
        const float4 c3 = *(const float4*)(vb + iv.w);
        acc.x += wv.x*c0.x + wv.y*c1.x + wv.z*c2.x + wv.w*c3.x;
        acc.y += wv.x*c0.y + wv.y*c1.y + wv.z*c2.y + wv.w*c3.y;
        acc.z += wv.x*c0.z + wv.y*c1.z + wv.z*c2.z + wv.w*c3.z;
        acc.w += wv.x*c0.w + wv.y*c1.w + wv.z*c2.w + wv.w*c3.w;
    }
    *(float4*)&s[(size_t)n*CH + lane*4] = acc;
}

// ---------------------------------------------------------------------------
// Fallback sampling reading separate offb/mskb arrays.
// ---------------------------------------------------------------------------
__global__ __launch_bounds__(256)
void sample_kernel(const float* __restrict__ v,
                   const float* __restrict__ offb,
                   const float* __restrict__ mskb,
                   float* __restrict__ s)
{
    __shared__ alignas(16) float loff[POSB][NOFF];
    __shared__ alignas(16) float lmsk[POSB][NMSK];
    __shared__ alignas(16) float wtab[POSB][GRP*NP][4];
    __shared__ alignas(16) int   itab[POSB][GRP*NP][4];

    const int nblk = MTOT / POSB;            // 6272
    const int per  = nblk / 8;               // 784
    const int bid  = blockIdx.x;
    const int sw   = (bid % 8) * per + (bid / 8);
    const int n0 = sw * POSB;
    const int t = threadIdx.x;

    if (t < POSB * (NOFF/4)) {
        const int q = t / (NOFF/4), r = t % (NOFF/4);
        *(float4*)&loff[q][r*4] = *(const float4*)&offb[(size_t)(n0+q)*NOFF + r*4];
    } else if (t < POSB * (NOFF/4) + POSB * (NMSK/4)) {
        const int u = t - POSB * (NOFF/4);
        const int q = u / (NMSK/4), r = u % (NMSK/4);
        *(float4*)&lmsk[q][r*4] = *(const float4*)&mskb[(size_t)(n0+q)*NMSK + r*4];
    }
    __syncthreads();

    if (t < POSB * GRP) {
        const int q = t >> 3, g = t & 7;
        float* mm = &lmsk[q][g * NP];
        float mx = -1e30f;
        #pragma unroll
        for (int p = 0; p < NP; ++p) mx = fmaxf(mx, mm[p]);
        float sum = 0.0f;
        #pragma unroll
        for (int p = 0; p < NP; ++p) { const float e = __expf(mm[p] - mx); mm[p] = e; sum += e; }
        const float inv = 1.0f / sum;
        #pragma unroll
        for (int p = 0; p < NP; ++p) mm[p] *= inv;
    }
    __syncthreads();

    for (int u = t; u < POSB * GRP * NP; u += 256) {
        const int q = u / (GRP*NP), j = u % (GRP*NP);
        const int g = j / NP, p = j % NP;
        const int n = n0 + q;
        const int hw = n % HW;
        const int h = hw / WDIM, w = hw % WDIM;
        const float ox = loff[q][g*18 + p*2 + 0];
        const float oy = loff[q][g*18 + p*2 + 1];
        const float m  = lmsk[q][g*NP + p];
        const float px = (float)(w + p/3) + ox;
        const float py = (float)(h + p%3) + oy;
        const float fx = floorf(px), fy = floorf(py);
        const float wx = px - fx, wy = py - fy;
        const int x0 = (int)fx, y0 = (int)fy;
        const int x1 = x0 + 1, y1 = y0 + 1;
        const float vx0 = (x0 >= 1 && x0 < 57) ? 1.0f : 0.0f;
        const float vx1 = (x1 >= 1 && x1 < 57) ? 1.0f : 0.0f;
        const float vy0 = (y0 >= 1 && y0 < 57) ? 1.0f : 0.0f;
        const float vy1 = (y1 >= 1 && y1 < 57) ? 1.0f : 0.0f;
        const int x0c = min(max(x0, 1), 56), x1c = min(max(x1, 1), 56);
        const int y0c = min(max(y0, 1), 56), y1c = min(max(y1, 1), 56);
        wtab[q][j][0] = m * (1.0f-wx) * (1.0f-wy) * vx0 * vy0;
        wtab[q][j][1] = m * wx        * (1.0f-wy) * vx1 * vy0;
        wtab[q][j][2] = m * (1.0f-wx) * wy        * vx0 * vy1;
        wtab[q][j][3] = m * wx        * wy        * vx1 * vy1;
        itab[q][j][0] = ((y0c-1)*WDIM + (x0c-1)) * CH;
        itab[q][j][1] = ((y0c-1)*WDIM + (x1c-1)) * CH;
        itab[q][j][2] = ((y1c-1)*WDIM + (x0c-1)) * CH;
        itab[q][j][3] = ((y1c-1)*WDIM + (x1c-1)) * CH;
    }
    __syncthreads();

    const int q = t >> 6, lane = t & 63;
    const int n = n0 + q;
    const int b = n / HW;
    const int g = lane >> 3;
    const float* vb = v + (size_t)b*HW*CH + lane*4;
    float4 acc = {0.0f, 0.0f, 0.0f, 0.0f};
    #pragma unroll
    for (int p = 0; p < NP; ++p) {
        const int j = g*NP + p;
        const float4 wv = *(const float4*)&wtab[q][j][0];
        const int4  iv = *(const int4*)&itab[q][j][0];
        const float4 c0 = *(const float4*)(vb + iv.x);
        const float4 c1 = *(const float4*)(vb + iv.y);
        const float4 c2 = *(const float4*)(vb + iv.z);
        const float4 c3 = *(const float4*)(vb + iv.w);
        acc.x += wv.x*c0.x + wv.y*c1.x + wv.z*c2.x + wv.w*c3.x;
        acc.y += wv.x*c0.y + wv.y*c1.y + wv.z*c2.y + wv.w*c3.y;
        acc.z += wv.x*c0.z + wv.y*c1.z + wv.z*c2.z + wv.w*c3.z;
        acc.w += wv.x*c0.w + wv.y*c1.w + wv.z*c2.w + wv.w*c3.w;
    }
    *(float4*)&s[(size_t)n*CH + lane*4] = acc;
}

// ---------------------------------------------------------------------------
// GEMM out via bf16 MFMA: y = SiLU(BN(s @ w_out + b_out)) NCHW.
// ---------------------------------------------------------------------------
__global__ __launch_bounds__(256)
void gemm_out_mfma(const float* __restrict__ A,            // s [MTOT,256]
                   const unsigned short* __restrict__ whi, // [256 n][256 k] bf16
                   const unsigned short* __restrict__ wlo,
                   const float* __restrict__ bias,
                   const float* __restrict__ bn_g,
                   const float* __restrict__ bn_b,
                   const float* __restrict__ bn_mean,
                   const float* __restrict__ bn_var,
                   float* __restrict__ y)                  // [B,256,3136]
{
    const int m0 = blockIdx.x * 256;
    const int n0 = blockIdx.y * 64;
    const int t = threadIdx.x;
    const int lane = t & 63, wv = t >> 6;
    const int mblk = m0 + wv * 64;
    const int fm = lane & 15;
    const int q  = lane >> 4;

    f32x4 acc[4][4];
    const f32x4 zero = {0.0f, 0.0f, 0.0f, 0.0f};
    #pragma unroll
    for (int i = 0; i < 4; ++i)
        #pragma unroll
        for (int j = 0; j < 4; ++j) acc[i][j] = zero;

    const float* arow[4];
    const unsigned short* wrh[4];
    const unsigned short* wrl[4];
    #pragma unroll
    for (int mt = 0; mt < 4; ++mt)
        arow[mt] = A + (size_t)(mblk + mt*16 + fm) * CH + q * 8;
    #pragma unroll
    for (int nt = 0; nt < 4; ++nt) {
        wrh[nt] = whi + (size_t)(n0 + nt*16 + fm) * CH + q * 8;
        wrl[nt] = wlo + (size_t)(n0 + nt*16 + fm) * CH + q * 8;
    }

    for (int k0 = 0; k0 < CH; k0 += 32) {
        s16x8 wh[4], wl[4], sh[4], sl[4];
        #pragma unroll
        for (int nt = 0; nt < 4; ++nt) {
            wh[nt] = *(const s16x8*)(wrh[nt] + k0);
            wl[nt] = *(const s16x8*)(wrl[nt] + k0);
        }
        #pragma unroll
        for (int mt = 0; mt < 4; ++mt) {
            const f32x4 r0 = *(const f32x4*)(arow[mt] + k0);
            const f32x4 r1 = *(const f32x4*)(arow[mt] + k0 + 4);
            union { s16x8 v; unsigned int u[4]; } ph, pl;
            split2(r0[0], r0[1], ph.u[0], pl.u[0]);
            split2(r0[2], r0[3], ph.u[1], pl.u[1]);
            split2(r1[0], r1[1], ph.u[2], pl.u[2]);
            split2(r1[2], r1[3], ph.u[3], pl.u[3]);
            sh[mt] = ph.v; sl[mt] = pl.v;
        }
        #pragma unroll
        for (int nt = 0; nt < 4; ++nt)
            #pragma unroll
            for (int mt = 0; mt < 4; ++mt) {
                acc[nt][mt] = __builtin_amdgcn_mfma_f32_16x16x32_bf16(wh[nt], sh[mt], acc[nt][mt], 0, 0, 0);
                acc[nt][mt] = __builtin_amdgcn_mfma_f32_16x16x32_bf16(wh[nt], sl[mt], acc[nt][mt], 0, 0, 0);
                acc[nt][mt] = __builtin_amdgcn_mfma_f32_16x16x32_bf16(wl[nt], sh[mt], acc[nt][mt], 0, 0, 0);
            }
    }

    #pragma unroll
    for (int nt = 0; nt < 4; ++nt) {
        #pragma unroll
        for (int r = 0; r < 4; ++r) {
            const int n = n0 + nt*16 + q*4 + r;
            const float sc = bn_g[n] * rsqrtf(bn_var[n] + 1e-5f);
            const float sb = bn_b[n] - bn_mean[n] * sc;
            const float bs = bias[n];
            #pragma unroll
            for (int mt = 0; mt < 4; ++mt) {
                const int mm = mblk + mt*16;
                const size_t base = (size_t)(mm / HW) * CH * HW + (mm % HW);
                float val = (acc[nt][mt][r] + bs) * sc + sb;
                y[base + (size_t)n * HW + fm] = val / (1.0f + expf(-val));
            }
        }
    }
}

extern "C" void kernel_launch(void* const* d_in, const int* in_sizes, int n_in,
                              void* d_out, int out_size, void* d_ws, size_t ws_size,
                              hipStream_t stream) {
    const float* x      = (const float*)d_in[0];
    const float* w_in   = (const float*)d_in[1];
    const float* b_in   = (const float*)d_in[2];
    const float* dw_w   = (const float*)d_in[3];
    const float* dw_b   = (const float*)d_in[4];
    const float* ln_g   = (const float*)d_in[5];
    const float* ln_b   = (const float*)d_in[6];
    const float* w_off  = (const float*)d_in[7];
    const float* b_off  = (const float*)d_in[8];
    const float* w_mask = (const float*)d_in[9];
    const float* b_mask = (const float*)d_in[10];
    const float* w_out  = (const float*)d_in[11];
    const float* b_out  = (const float*)d_in[12];
    const float* bn_g   = (const float*)d_in[13];
    const float* bn_b   = (const float*)d_in[14];
    const float* bn_mean= (const float*)d_in[15];
    const float* bn_var = (const float*)d_in[16];
    float* out = (float*)d_out;

    const size_t SZ = (size_t)MTOT * CH;                 // elements
    // Layout: v | xt_hi,xt_lo | fh,fl | omb | weights | bcat
    const size_t need_new =
        4 * SZ * sizeof(float)
        + 6 * (size_t)CH * CH * sizeof(unsigned short)
        + CH * sizeof(float);

    if (ws_size >= need_new) {
        // -------- main path --------
        float* ws = (float*)d_ws;
        float* v    = ws;                                          // SZ f32
        unsigned short* xt_hi = (unsigned short*)(v + SZ);         // SZ us
        unsigned short* xt_lo = xt_hi + SZ;                        // SZ us
        unsigned short* fh    = xt_lo + SZ;                        // SZ us
        unsigned short* fl    = fh + SZ;                           // SZ us
        float* omb  = (float*)(fl + SZ);                           // SZ f32
        unsigned short* wt_hi  = (unsigned short*)(omb + SZ);
        unsigned short* wt_lo  = wt_hi + CH * CH;
        unsigned short* wt2_hi = wt_lo + CH * CH;
        unsigned short* wt2_lo = wt2_hi + CH * CH;
        unsigned short* wt3_hi = wt2_lo + CH * CH;
        unsigned short* wt3_lo = wt3_hi + CH * CH;
        float* bcat = (float*)(wt3_lo + CH * CH);                  // 256 f32
        // s overlays xt region (xt consumed by gemm_in + dw before sample).
        float* s = (float*)xt_hi;

        wt_split_kernel<<<dim3(4, 4), dim3(256), 0, stream>>>(w_out, wt_hi, wt_lo);
        wt_split_kernel<<<dim3(4, 4), dim3(256), 0, stream>>>(w_in, wt3_hi, wt3_lo);
        wt2_split_kernel<<<dim3(16), dim3(256), 0, stream>>>(
            w_off, w_mask, b_off, b_mask, wt2_hi, wt2_lo, bcat);
        xt_split_kernel<<<dim3(HW/64, CH/64, BATCH), dim3(256), 0, stream>>>(x, xt_hi, xt_lo);
        gemm_in_mfma<<<dim3(MTOT/256, CH/64), dim3(256), 0, stream>>>(
            xt_hi, xt_lo, wt3_hi, wt3_lo, b_in, v);
        dw_ln_gelu_nhwc_split<<<dim3(MTOT/POSB), dim3(256), 0, stream>>>(
            xt_hi, xt_lo, dw_w, dw_b, ln_g, ln_b, fh, fl);
        // offmask projection: IDENTICAL kernel to gemm_in (control experiment),
        // writing the 256-padded omb with coalesced f32x4 stores.
        gemm_in_mfma<<<dim3(MTOT/256, CH/64), dim3(256), 0, stream>>>(
            fh, fl, wt2_hi, wt2_lo, bcat, omb);
        sample_kernel_omb<<<dim3(MTOT/POSB), dim3(256), 0, stream>>>(v, omb, s);
        gemm_out_mfma<<<dim3(MTOT/256, CH/64), dim3(256), 0, stream>>>(
            s, wt_hi, wt_lo, b_out, bn_g, bn_b, bn_mean, bn_var, out);
    } else {
        // -------- fallback: round-1 verified path (xt overlays f) --------
        float* ws   = (float*)d_ws;
        float* v    = ws;                                   // SZ f32
        float* f    = v + SZ;                               // SZ f32
        float* offb = f + SZ;                               // MTOT*NOFF
        float* mskb = offb + (size_t)MTOT * NOFF;           // MTOT*NMSK
        float* s    = f;                                    // reuse f buffer
        unsigned short* wt_hi  = (unsigned short*)(mskb + (size_t)MTOT * NMSK);
        unsigned short* wt_lo  = wt_hi + CH * CH;
        unsigned short* wt2_hi = wt_lo + CH * CH;
        unsigned short* wt2_lo = wt2_hi + CH * CH;
        unsigned short* wt3_hi = wt2_lo + CH * CH;
        unsigned short* wt3_lo = wt3_hi + CH * CH;
        float* bcat = (float*)(wt3_lo + CH * CH);           // 256 f32 (unused)
        unsigned short* xt_hi = (unsigned short*)f;
        unsigned short* xt_lo = xt_hi + SZ;

        wt_split_kernel<<<dim3(4, 4), dim3(256), 0, stream>>>(w_out, wt_hi, wt_lo);
        wt_split_kernel<<<dim3(4, 4), dim3(256), 0, stream>>>(w_in, wt3_hi, wt3_lo);
        wt2_split_kernel<<<dim3(16), dim3(256), 0, stream>>>(
            w_off, w_mask, b_off, b_mask, wt2_hi, wt2_lo, bcat);
        xt_split_kernel<<<dim3(HW/64, CH/64, BATCH), dim3(256), 0, stream>>>(x, xt_hi, xt_lo);
        gemm_in_mfma<<<dim3(MTOT/256, CH/64), dim3(256), 0, stream>>>(
            xt_hi, xt_lo, wt3_hi, wt3_lo, b_in, v);
        dw_ln_gelu_kernel<<<dim3(HDIM, BATCH), dim3(256), 0, stream>>>(x, dw_w, dw_b, ln_g, ln_b, f);
        gemm_offmask_mfma<<<dim3(MTOT/256, 4), dim3(256), 0, stream>>>(
            f, wt2_hi, wt2_lo, b_off, b_mask, offb, mskb);
        sample_kernel<<<dim3(MTOT/POSB), dim3(256), 0, stream>>>(v, offb, mskb, s);
        gemm_out_mfma<<<dim3(MTOT/256, CH/64), dim3(256), 0, stream>>>(
            s, wt_hi, wt_lo, b_out, bn_g, bn_b, bn_mean, bn_var, out);
    }
}

// Round 5
// 292.122 us; speedup vs baseline: 1.1288x; 1.0090x over previous
//
#include <hip/hip_runtime.h>
#include <math.h>

// Problem constants
#define BATCH 8
#define CH    256
#define HDIM  56
#define WDIM  56
#define HW    (HDIM*WDIM)          // 3136
#define MTOT  (BATCH*HW)           // 25088
#define GRP   8
#define GC    32
#define NP    9                    // K*K
#define NOFF  (GRP*NP*2)           // 144
#define NMSK  (GRP*NP)             // 72
#define NTOT  (NOFF+NMSK)          // 216
#define POSB  4                    // positions per sample block

typedef float f32x4 __attribute__((ext_vector_type(4)));
typedef short s16x8 __attribute__((ext_vector_type(8)));

// split a,b into packed bf16 hi (truncation) and bf16 lo (exact remainder, truncated)
__device__ inline void split2(float a, float b, unsigned int& hp, unsigned int& lp)
{
    const unsigned int ua = __float_as_uint(a), ub = __float_as_uint(b);
    hp = (ub & 0xffff0000u) | (ua >> 16);
    const float ha = __uint_as_float(ua & 0xffff0000u);
    const float hb = __uint_as_float(ub & 0xffff0000u);
    const unsigned int la = __float_as_uint(a - ha), lb = __float_as_uint(b - hb);
    lp = (lb & 0xffff0000u) | (la >> 16);
}

// ---------------------------------------------------------------------------
// Transpose + split x (NCHW) -> xt_hi/xt_lo [m][k] bf16. 64x64 LDS tiles.
// ---------------------------------------------------------------------------
__global__ __launch_bounds__(256)
void xt_split_kernel(const float* __restrict__ x,
                     unsigned short* __restrict__ hi,
                     unsigned short* __restrict__ lo)
{
    __shared__ float lds[64][68];
    const int hw0 = blockIdx.x * 64;       // 49 tiles (3136/64)
    const int k0  = blockIdx.y * 64;       // 4 tiles
    const int b   = blockIdx.z;            // 8
    const int t = threadIdx.x;
    #pragma unroll
    for (int p = 0; p < 4; ++p) {
        const int kr = (t >> 4) + p * 16;
        const int hc = (t & 15) * 4;
        *(float4*)&lds[kr][hc] =
            *(const float4*)(x + ((size_t)b * CH + k0 + kr) * HW + hw0 + hc);
    }
    __syncthreads();
    const int ml = t >> 2;             // m-row 0..63
    const int kc = (t & 3) * 16;       // k base 0,16,32,48
    unsigned int hbuf[8], lbuf[8];
    #pragma unroll
    for (int j = 0; j < 16; j += 2)
        split2(lds[kc + j][ml], lds[kc + j + 1][ml], hbuf[j >> 1], lbuf[j >> 1]);
    const size_t row = (size_t)(b * HW + hw0 + ml) * CH + k0 + kc;
    *(uint4*)&hi[row]     = *(uint4*)&hbuf[0];
    *(uint4*)&hi[row + 8] = *(uint4*)&hbuf[4];
    *(uint4*)&lo[row]     = *(uint4*)&lbuf[0];
    *(uint4*)&lo[row + 8] = *(uint4*)&lbuf[4];
}

// ---------------------------------------------------------------------------
// GEMM via bf16 MFMA: out = A @ W^T + bias (256-wide rows). Barrier-free.
// Used for the input projection (v) AND the offset/mask projection (omb).
// ---------------------------------------------------------------------------
__global__ __launch_bounds__(256)
void gemm_in_mfma(const unsigned short* __restrict__ xhi, // [m][k]
                  const unsigned short* __restrict__ xlo,
                  const unsigned short* __restrict__ whi, // [n][k]
                  const unsigned short* __restrict__ wlo,
                  const float* __restrict__ bias,
                  float* __restrict__ v)                  // [MTOT,256]
{
    const int m0 = blockIdx.x * 256;
    const int n0 = blockIdx.y * 64;
    const int t = threadIdx.x;
    const int lane = t & 63, wv = t >> 6;
    const int mblk = m0 + wv * 64;
    const int fm = lane & 15;
    const int q  = lane >> 4;

    f32x4 acc[4][4];              // [nt][mt]
    const f32x4 zero = {0.0f, 0.0f, 0.0f, 0.0f};
    #pragma unroll
    for (int i = 0; i < 4; ++i)
        #pragma unroll
        for (int j = 0; j < 4; ++j) acc[i][j] = zero;

    const unsigned short *xrh[4], *xrl[4], *wrh[4], *wrl[4];
    #pragma unroll
    for (int mt = 0; mt < 4; ++mt) {
        xrh[mt] = xhi + (size_t)(mblk + mt*16 + fm) * CH + q * 8;
        xrl[mt] = xlo + (size_t)(mblk + mt*16 + fm) * CH + q * 8;
    }
    #pragma unroll
    for (int nt = 0; nt < 4; ++nt) {
        wrh[nt] = whi + (size_t)(n0 + nt*16 + fm) * CH + q * 8;
        wrl[nt] = wlo + (size_t)(n0 + nt*16 + fm) * CH + q * 8;
    }

    for (int k0 = 0; k0 < CH; k0 += 32) {
        s16x8 wh[4], wl[4], ah[4], al[4];
        #pragma unroll
        for (int nt = 0; nt < 4; ++nt) {
            wh[nt] = *(const s16x8*)(wrh[nt] + k0);
            wl[nt] = *(const s16x8*)(wrl[nt] + k0);
        }
        #pragma unroll
        for (int mt = 0; mt < 4; ++mt) {
            ah[mt] = *(const s16x8*)(xrh[mt] + k0);
            al[mt] = *(const s16x8*)(xrl[mt] + k0);
        }
        #pragma unroll
        for (int nt = 0; nt < 4; ++nt)
            #pragma unroll
            for (int mt = 0; mt < 4; ++mt) {
                acc[nt][mt] = __builtin_amdgcn_mfma_f32_16x16x32_bf16(wh[nt], ah[mt], acc[nt][mt], 0, 0, 0);
                acc[nt][mt] = __builtin_amdgcn_mfma_f32_16x16x32_bf16(wh[nt], al[mt], acc[nt][mt], 0, 0, 0);
                acc[nt][mt] = __builtin_amdgcn_mfma_f32_16x16x32_bf16(wl[nt], ah[mt], acc[nt][mt], 0, 0, 0);
            }
    }

    #pragma unroll
    for (int nt = 0; nt < 4; ++nt) {
        const float4 b4 = *(const float4*)&bias[n0 + nt*16 + q*4];
        #pragma unroll
        for (int mt = 0; mt < 4; ++mt) {
            f32x4 o = acc[nt][mt];
            o[0] += b4.x; o[1] += b4.y; o[2] += b4.z; o[3] += b4.w;
            *(f32x4*)&v[(size_t)(mblk + mt*16 + fm) * CH + n0 + nt*16 + q*4] = o;
        }
    }
}

// ---------------------------------------------------------------------------
// OLD fallback: fused depthwise 3x3 + bias + LayerNorm(C) + exact GELU -> f.
// ---------------------------------------------------------------------------
__global__ __launch_bounds__(256)
void dw_ln_gelu_kernel(const float* __restrict__ x,
                       const float* __restrict__ dw_w,
                       const float* __restrict__ dw_b,
                       const float* __restrict__ ln_g,
                       const float* __restrict__ ln_b,
                       float* __restrict__ f)
{
    __shared__ float tile[WDIM][CH + 1];
    __shared__ float red1[WDIM][4], red2[WDIM][4];
    __shared__ float meanA[WDIM], rstdA[WDIM];

    const int h = blockIdx.x;
    const int b = blockIdx.y;
    const int t = threadIdx.x;
    const int lane = t & 63;
    const int wv   = t >> 6;

    for (int cg = 0; cg < CH / 4; ++cg) {
        const int c = cg * 4 + wv;
        const float* xp = x + ((size_t)b * CH + c) * HW;
        float rowv[3];
        #pragma unroll
        for (int r = 0; r < 3; ++r) {
            const int hh = h + r - 1;
            rowv[r] = (lane < WDIM && hh >= 0 && hh < HDIM) ? xp[hh * WDIM + lane] : 0.0f;
        }
        const float* wp = dw_w + c * 9;
        float acc = dw_b[c];
        #pragma unroll
        for (int r = 0; r < 3; ++r) {
            float L = __shfl_up(rowv[r], 1);
            float R = __shfl_down(rowv[r], 1);
            if (lane == 0) L = 0.0f;
            acc += L * wp[r * 3 + 0] + rowv[r] * wp[r * 3 + 1] + R * wp[r * 3 + 2];
        }
        if (lane < WDIM)
            tile[lane][c] = acc;
    }
    __syncthreads();

    if (t < 224) {
        const int p = t >> 2, q = t & 3;
        float s1 = 0.0f, s2 = 0.0f;
        #pragma unroll 8
        for (int i = 0; i < 64; ++i) {
            const float v = tile[p][q * 64 + i];
            s1 += v; s2 += v * v;
        }
        red1[p][q] = s1; red2[p][q] = s2;
    }
    __syncthreads();
    if (t < WDIM) {
        const float s1 = red1[t][0] + red1[t][1] + red1[t][2] + red1[t][3];
        const float s2 = red2[t][0] + red2[t][1] + red2[t][2] + red2[t][3];
        const float m = s1 * (1.0f / 256.0f);
        const float var = s2 * (1.0f / 256.0f) - m * m;
        meanA[t] = m;
        rstdA[t] = rsqrtf(var + 1e-5f);
    }
    __syncthreads();

    const float gam = ln_g[t], bet = ln_b[t];
    const size_t n0 = (size_t)(b * HDIM + h) * WDIM;
    for (int p = 0; p < WDIM; ++p) {
        const float xn = (tile[p][t] - meanA[p]) * rstdA[p] * gam + bet;
        const float g = 0.5f * xn * (1.0f + erff(xn * 0.70710678118654752f));
        f[(n0 + p) * CH + t] = g;
    }
}

// ---------------------------------------------------------------------------
// Per-position-wave depthwise 3x3 + bias + LN + GELU from NHWC bf16 hi/lo xt,
// output stored PRE-SPLIT as bf16 hi/lo. One wave per position.
// ---------------------------------------------------------------------------
__global__ __launch_bounds__(256)
void dw_ln_gelu_nhwc_split(const unsigned short* __restrict__ xhi,
                           const unsigned short* __restrict__ xlo,
                           const float* __restrict__ dw_w,   // [256][9]
                           const float* __restrict__ dw_b,
                           const float* __restrict__ ln_g,
                           const float* __restrict__ ln_b,
                           unsigned short* __restrict__ fh,  // [MTOT][256]
                           unsigned short* __restrict__ fl)  // [MTOT][256]
{
    __shared__ float wt[NP][CH];                       // transposed dw weights
    __shared__ float lbias[CH], lgam[CH], lbet[CH];

    const int t = threadIdx.x;
    {
        const float* wp = dw_w + t * NP;
        #pragma unroll
        for (int p = 0; p < NP; ++p) wt[p][t] = wp[p];
        lbias[t] = dw_b[t]; lgam[t] = ln_g[t]; lbet[t] = ln_b[t];
    }
    __syncthreads();

    const int nblk = MTOT / POSB;          // 6272
    const int per  = nblk / 8;             // 784
    const int bid  = blockIdx.x;
    const int sw   = (bid & 7) * per + (bid >> 3);
    const int q    = t >> 6, lane = t & 63;
    const int n    = sw * POSB + q;
    const int b    = n / HW;
    const int hw   = n % HW;
    const int h    = hw / WDIM, w = hw % WDIM;
    const int c4   = lane * 4;
    const size_t base = (size_t)b * HW * CH + c4;

    float ax = 0.0f, ay = 0.0f, az = 0.0f, aw = 0.0f;
    #pragma unroll
    for (int p = 0; p < NP; ++p) {
        const int hh = h + p / 3 - 1;
        const int ww = w + p % 3 - 1;
        if ((unsigned)hh >= (unsigned)HDIM || (unsigned)ww >= (unsigned)WDIM)
            continue;                       // wave-uniform branch (h,w per-wave)
        const size_t idx = base + (size_t)(hh * WDIM + ww) * CH;
        const ushort4 uh = *(const ushort4*)(xhi + idx);
        const ushort4 ul = *(const ushort4*)(xlo + idx);
        const float4 wv = *(const float4*)&wt[p][c4];
        ax = fmaf(__uint_as_float((unsigned)uh.x << 16), wv.x,
             fmaf(__uint_as_float((unsigned)ul.x << 16), wv.x, ax));
        ay = fmaf(__uint_as_float((unsigned)uh.y << 16), wv.y,
             fmaf(__uint_as_float((unsigned)ul.y << 16), wv.y, ay));
        az = fmaf(__uint_as_float((unsigned)uh.z << 16), wv.z,
             fmaf(__uint_as_float((unsigned)ul.z << 16), wv.z, az));
        aw = fmaf(__uint_as_float((unsigned)uh.w << 16), wv.w,
             fmaf(__uint_as_float((unsigned)ul.w << 16), wv.w, aw));
    }
    {
        const float4 b4 = *(const float4*)&lbias[c4];
        ax += b4.x; ay += b4.y; az += b4.z; aw += b4.w;
    }

    // LayerNorm over the wave's 256 channel values: in-wave butterfly.
    float s1 = ax + ay + az + aw;
    float s2 = ax*ax + ay*ay + az*az + aw*aw;
    #pragma unroll
    for (int off = 32; off > 0; off >>= 1) {
        s1 += __shfl_xor(s1, off);
        s2 += __shfl_xor(s2, off);
    }
    const float mean = s1 * (1.0f / 256.0f);
    const float rstd = rsqrtf(s2 * (1.0f / 256.0f) - mean * mean + 1e-5f);

    const float4 g4 = *(const float4*)&lgam[c4];
    const float4 e4 = *(const float4*)&lbet[c4];
    const float x0 = (ax - mean) * rstd * g4.x + e4.x;
    const float x1 = (ay - mean) * rstd * g4.y + e4.y;
    const float x2 = (az - mean) * rstd * g4.z + e4.z;
    const float x3 = (aw - mean) * rstd * g4.w + e4.w;
    const float o0 = 0.5f * x0 * (1.0f + erff(x0 * 0.70710678118654752f));
    const float o1 = 0.5f * x1 * (1.0f + erff(x1 * 0.70710678118654752f));
    const float o2 = 0.5f * x2 * (1.0f + erff(x2 * 0.70710678118654752f));
    const float o3 = 0.5f * x3 * (1.0f + erff(x3 * 0.70710678118654752f));

    unsigned int hp0, lp0, hp1, lp1;
    split2(o0, o1, hp0, lp0);
    split2(o2, o3, hp1, lp1);
    *(uint2*)&fh[(size_t)n * CH + c4] = make_uint2(hp0, hp1);
    *(uint2*)&fl[(size_t)n * CH + c4] = make_uint2(lp0, lp1);
}

// ---------------------------------------------------------------------------
// Transpose + hi/lo bf16 split of a [256k][256n] fp32 weight -> [n][k] bf16.
// ---------------------------------------------------------------------------
__global__ __launch_bounds__(256)
void wt_split_kernel(const float* __restrict__ w,
                     unsigned short* __restrict__ hi,
                     unsigned short* __restrict__ lo)
{
    __shared__ float lds[64][68];
    const int kt = blockIdx.x * 64, nt = blockIdx.y * 64;
    const int t = threadIdx.x;
    #pragma unroll
    for (int p = 0; p < 4; ++p) {
        const int kr = (t >> 4) + p * 16, nc = (t & 15) * 4;
        *(float4*)&lds[kr][nc] = *(const float4*)(w + (size_t)(kt + kr) * CH + nt + nc);
    }
    __syncthreads();
    const int nl = t >> 2, kc = (t & 3) * 16;
    #pragma unroll
    for (int j = 0; j < 16; j += 2) {
        const float f0 = lds[kc + j][nl], f1 = lds[kc + j + 1][nl];
        unsigned int hp, lp;
        split2(f0, f1, hp, lp);
        *(unsigned int*)&hi[(size_t)(nt + nl) * CH + kt + kc + j] = hp;
        *(unsigned int*)&lo[(size_t)(nt + nl) * CH + kt + kc + j] = lp;
    }
}

// ---------------------------------------------------------------------------
// Transpose + split of [w_off | w_mask] -> wt2_hi/lo [256 n_pad][256 k] bf16.
// Also builds bcat[256] = [b_off | b_mask | 0] (block 0 only).
// ---------------------------------------------------------------------------
__global__ __launch_bounds__(256)
void wt2_split_kernel(const float* __restrict__ w_off,   // [256][144]
                      const float* __restrict__ w_mask,  // [256][72]
                      const float* __restrict__ b_off,
                      const float* __restrict__ b_mask,
                      unsigned short* __restrict__ hi,
                      unsigned short* __restrict__ lo,
                      float* __restrict__ bcat)          // [256]
{
    const int n = threadIdx.x;
    if (blockIdx.x == 0) {
        bcat[n] = (n < NOFF) ? b_off[n] : ((n < NTOT) ? b_mask[n - NOFF] : 0.0f);
    }
    const int k0 = blockIdx.x * 16;
    #pragma unroll
    for (int j = 0; j < 16; j += 2) {
        const int k = k0 + j;
        float f0 = 0.0f, f1 = 0.0f;
        if (n < NOFF) {
            f0 = w_off[(size_t)k * NOFF + n];
            f1 = w_off[(size_t)(k + 1) * NOFF + n];
        } else if (n < NTOT) {
            f0 = w_mask[(size_t)k * NMSK + (n - NOFF)];
            f1 = w_mask[(size_t)(k + 1) * NMSK + (n - NOFF)];
        }
        unsigned int hp, lp;
        split2(f0, f1, hp, lp);
        *(unsigned int*)&hi[(size_t)n * CH + k] = hp;
        *(unsigned int*)&lo[(size_t)n * CH + k] = lp;
    }
}

// ---------------------------------------------------------------------------
// Fallback: offset+mask GEMM via bf16 MFMA (reads f32 f, scattered epilogue).
// ---------------------------------------------------------------------------
__global__ __launch_bounds__(256)
void gemm_offmask_mfma(const float* __restrict__ A,            // f [MTOT,256]
                       const unsigned short* __restrict__ whi, // [256][256] bf16
                       const unsigned short* __restrict__ wlo,
                       const float* __restrict__ b_off,
                       const float* __restrict__ b_mask,
                       float* __restrict__ offb,               // [MTOT,144]
                       float* __restrict__ mskb)               // [MTOT,72]
{
    const int m0 = blockIdx.x * 256;
    const int n0 = blockIdx.y * 64;
    const int t = threadIdx.x;
    const int lane = t & 63, wv = t >> 6;
    const int mblk = m0 + wv * 64;
    const int fm = lane & 15;
    const int q  = lane >> 4;

    f32x4 acc[4][4];
    const f32x4 zero = {0.0f, 0.0f, 0.0f, 0.0f};
    #pragma unroll
    for (int i = 0; i < 4; ++i)
        #pragma unroll
        for (int j = 0; j < 4; ++j) acc[i][j] = zero;

    const float* arow[4];
    const unsigned short* wrh[4];
    const unsigned short* wrl[4];
    #pragma unroll
    for (int mt = 0; mt < 4; ++mt)
        arow[mt] = A + (size_t)(mblk + mt*16 + fm) * CH + q * 8;
    #pragma unroll
    for (int nt = 0; nt < 4; ++nt) {
        wrh[nt] = whi + (size_t)(n0 + nt*16 + fm) * CH + q * 8;
        wrl[nt] = wlo + (size_t)(n0 + nt*16 + fm) * CH + q * 8;
    }

    for (int k0 = 0; k0 < CH; k0 += 32) {
        s16x8 wh[4], wl[4], sh[4], sl[4];
        #pragma unroll
        for (int nt = 0; nt < 4; ++nt) {
            wh[nt] = *(const s16x8*)(wrh[nt] + k0);
            wl[nt] = *(const s16x8*)(wrl[nt] + k0);
        }
        #pragma unroll
        for (int mt = 0; mt < 4; ++mt) {
            const f32x4 r0 = *(const f32x4*)(arow[mt] + k0);
            const f32x4 r1 = *(const f32x4*)(arow[mt] + k0 + 4);
            union { s16x8 v; unsigned int u[4]; } ph, pl;
            split2(r0[0], r0[1], ph.u[0], pl.u[0]);
            split2(r0[2], r0[3], ph.u[1], pl.u[1]);
            split2(r1[0], r1[1], ph.u[2], pl.u[2]);
            split2(r1[2], r1[3], ph.u[3], pl.u[3]);
            sh[mt] = ph.v; sl[mt] = pl.v;
        }
        #pragma unroll
        for (int nt = 0; nt < 4; ++nt)
            #pragma unroll
            for (int mt = 0; mt < 4; ++mt) {
                acc[nt][mt] = __builtin_amdgcn_mfma_f32_16x16x32_bf16(wh[nt], sh[mt], acc[nt][mt], 0, 0, 0);
                acc[nt][mt] = __builtin_amdgcn_mfma_f32_16x16x32_bf16(wh[nt], sl[mt], acc[nt][mt], 0, 0, 0);
                acc[nt][mt] = __builtin_amdgcn_mfma_f32_16x16x32_bf16(wl[nt], sh[mt], acc[nt][mt], 0, 0, 0);
            }
    }

    #pragma unroll
    for (int nt = 0; nt < 4; ++nt) {
        #pragma unroll
        for (int r = 0; r < 4; ++r) {
            const int n = n0 + nt*16 + q*4 + r;
            if (n >= NTOT) continue;
            const float bs = (n < NOFF) ? b_off[n] : b_mask[n - NOFF];
            #pragma unroll
            for (int mt = 0; mt < 4; ++mt) {
                const int m = mblk + mt*16 + fm;
                const float val = acc[nt][mt][r] + bs;
                if (n < NOFF) offb[(size_t)m * NOFF + n] = val;
                else          mskb[(size_t)m * NMSK + (n - NOFF)] = val;
            }
        }
    }
}

// ---------------------------------------------------------------------------
// Deformable sampling reading the padded omb [MTOT][256] rows
// (cols 0..143 offsets, 144..215 mask logits). Output s PRE-SPLIT bf16 hi/lo
// (bit-identical to the values gemm_out's in-loop split2 would produce).
// ---------------------------------------------------------------------------
__global__ __launch_bounds__(256)
void sample_kernel_omb_split(const float* __restrict__ v,
                             const float* __restrict__ omb,
                             unsigned short* __restrict__ sh,  // [MTOT][256]
                             unsigned short* __restrict__ sl)  // [MTOT][256]
{
    __shared__ alignas(16) float loff[POSB][NOFF];
    __shared__ alignas(16) float lmsk[POSB][NMSK];
    __shared__ alignas(16) float wtab[POSB][GRP*NP][4];
    __shared__ alignas(16) int   itab[POSB][GRP*NP][4];

    const int nblk = MTOT / POSB;            // 6272
    const int per  = nblk / 8;               // 784
    const int bid  = blockIdx.x;
    const int sw   = (bid % 8) * per + (bid / 8);
    const int n0 = sw * POSB;
    const int t = threadIdx.x;

    if (t < POSB * (NOFF/4)) {
        const int q = t / (NOFF/4), r = t % (NOFF/4);
        *(float4*)&loff[q][r*4] = *(const float4*)&omb[(size_t)(n0+q)*CH + r*4];
    } else if (t < POSB * (NOFF/4) + POSB * (NMSK/4)) {
        const int u = t - POSB * (NOFF/4);
        const int q = u / (NMSK/4), r = u % (NMSK/4);
        *(float4*)&lmsk[q][r*4] = *(const float4*)&omb[(size_t)(n0+q)*CH + NOFF + r*4];
    }
    __syncthreads();

    if (t < POSB * GRP) {
        const int q = t >> 3, g = t & 7;
        float* mm = &lmsk[q][g * NP];
        float mx = -1e30f;
        #pragma unroll
        for (int p = 0; p < NP; ++p) mx = fmaxf(mx, mm[p]);
        float sum = 0.0f;
        #pragma unroll
        for (int p = 0; p < NP; ++p) { const float e = __expf(mm[p] - mx); mm[p] = e; sum += e; }
        const float inv = 1.0f / sum;
        #pragma unroll
        for (int p = 0; p < NP; ++p) mm[p] *= inv;
    }
    __syncthreads();

    for (int u = t; u < POSB * GRP * NP; u += 256) {
        const int q = u / (GRP*NP), j = u % (GRP*NP);
        const int g = j / NP, p = j % NP;
        const int n = n0 + q;
        const int hw = n % HW;
        const int h = hw / WDIM, w = hw % WDIM;
        const float ox = loff[q][g*18 + p*2 + 0];
        const float oy = loff[q][g*18 + p*2 + 1];
        const float m  = lmsk[q][g*NP + p];
        const float px = (float)(w + p/3) + ox;
        const float py = (float)(h + p%3) + oy;
        const float fx = floorf(px), fy = floorf(py);
        const float wx = px - fx, wy = py - fy;
        const int x0 = (int)fx, y0 = (int)fy;
        const int x1 = x0 + 1, y1 = y0 + 1;
        const float vx0 = (x0 >= 1 && x0 < 57) ? 1.0f : 0.0f;
        const float vx1 = (x1 >= 1 && x1 < 57) ? 1.0f : 0.0f;
        const float vy0 = (y0 >= 1 && y0 < 57) ? 1.0f : 0.0f;
        const float vy1 = (y1 >= 1 && y1 < 57) ? 1.0f : 0.0f;
        const int x0c = min(max(x0, 1), 56), x1c = min(max(x1, 1), 56);
        const int y0c = min(max(y0, 1), 56), y1c = min(max(y1, 1), 56);
        wtab[q][j][0] = m * (1.0f-wx) * (1.0f-wy) * vx0 * vy0;
        wtab[q][j][1] = m * wx        * (1.0f-wy) * vx1 * vy0;
        wtab[q][j][2] = m * (1.0f-wx) * wy        * vx0 * vy1;
        wtab[q][j][3] = m * wx        * wy        * vx1 * vy1;
        itab[q][j][0] = ((y0c-1)*WDIM + (x0c-1)) * CH;
        itab[q][j][1] = ((y0c-1)*WDIM + (x1c-1)) * CH;
        itab[q][j][2] = ((y1c-1)*WDIM + (x0c-1)) * CH;
        itab[q][j][3] = ((y1c-1)*WDIM + (x1c-1)) * CH;
    }
    __syncthreads();

    const int q = t >> 6, lane = t & 63;
    const int n = n0 + q;
    const int b = n / HW;
    const int g = lane >> 3;
    const float* vb = v + (size_t)b*HW*CH + lane*4;
    float4 acc = {0.0f, 0.0f, 0.0f, 0.0f};
    #pragma unroll
    for (int p = 0; p < NP; ++p) {
        const int j = g*NP + p;
        const float4 wv = *(const float4*)&wtab[q][j][0];
        const int4  iv = *(const int4*)&itab[q][j][0];
        const float4 c0 = *(const float4*)(vb + iv.x);
        const float4 c1 = *(const float4*)(vb + iv.y);
        const float4 c2 = *(const float4*)(vb + iv.z);
        const float4 c3 = *(const float4*)(vb + iv.w);
        acc.x += wv.x*c0.x + wv.y*c1.x + wv.z*c2.x + wv.w*c3.x;
        acc.y += wv.x*c0.y + wv.y*c1.y + wv.z*c2.y + wv.w*c3.y;
        acc.z += wv.x*c0.z + wv.y*c1.z + wv.z*c2.z + wv.w*c3.z;
        acc.w += wv.x*c0.w + wv.y*c1.w + wv.z*c2.w + wv.w*c3.w;
    }
    unsigned int hp0, lp0, hp1, lp1;
    split2(acc.x, acc.y, hp0, lp0);
    split2(acc.z, acc.w, hp1, lp1);
    *(uint2*)&sh[(size_t)n*CH + lane*4] = make_uint2(hp0, hp1);
    *(uint2*)&sl[(size_t)n*CH + lane*4] = make_uint2(lp0, lp1);
}

// ---------------------------------------------------------------------------
// Fallback sampling reading separate offb/mskb arrays, f32 s out.
// ---------------------------------------------------------------------------
__global__ __launch_bounds__(256)
void sample_kernel(const float* __restrict__ v,
                   const float* __restrict__ offb,
                   const float* __restrict__ mskb,
                   float* __restrict__ s)
{
    __shared__ alignas(16) float loff[POSB][NOFF];
    __shared__ alignas(16) float lmsk[POSB][NMSK];
    __shared__ alignas(16) float wtab[POSB][GRP*NP][4];
    __shared__ alignas(16) int   itab[POSB][GRP*NP][4];

    const int nblk = MTOT / POSB;            // 6272
    const int per  = nblk / 8;               // 784
    const int bid  = blockIdx.x;
    const int sw   = (bid % 8) * per + (bid / 8);
    const int n0 = sw * POSB;
    const int t = threadIdx.x;

    if (t < POSB * (NOFF/4)) {
        const int q = t / (NOFF/4), r = t % (NOFF/4);
        *(float4*)&loff[q][r*4] = *(const float4*)&offb[(size_t)(n0+q)*NOFF + r*4];
    } else if (t < POSB * (NOFF/4) + POSB * (NMSK/4)) {
        const int u = t - POSB * (NOFF/4);
        const int q = u / (NMSK/4), r = u % (NMSK/4);
        *(float4*)&lmsk[q][r*4] = *(const float4*)&mskb[(size_t)(n0+q)*NMSK + r*4];
    }
    __syncthreads();

    if (t < POSB * GRP) {
        const int q = t >> 3, g = t & 7;
        float* mm = &lmsk[q][g * NP];
        float mx = -1e30f;
        #pragma unroll
        for (int p = 0; p < NP; ++p) mx = fmaxf(mx, mm[p]);
        float sum = 0.0f;
        #pragma unroll
        for (int p = 0; p < NP; ++p) { const float e = __expf(mm[p] - mx); mm[p] = e; sum += e; }
        const float inv = 1.0f / sum;
        #pragma unroll
        for (int p = 0; p < NP; ++p) mm[p] *= inv;
    }
    __syncthreads();

    for (int u = t; u < POSB * GRP * NP; u += 256) {
        const int q = u / (GRP*NP), j = u % (GRP*NP);
        const int g = j / NP, p = j % NP;
        const int n = n0 + q;
        const int hw = n % HW;
        const int h = hw / WDIM, w = hw % WDIM;
        const float ox = loff[q][g*18 + p*2 + 0];
        const float oy = loff[q][g*18 + p*2 + 1];
        const float m  = lmsk[q][g*NP + p];
        const float px = (float)(w + p/3) + ox;
        const float py = (float)(h + p%3) + oy;
        const float fx = floorf(px), fy = floorf(py);
        const float wx = px - fx, wy = py - fy;
        const int x0 = (int)fx, y0 = (int)fy;
        const int x1 = x0 + 1, y1 = y0 + 1;
        const float vx0 = (x0 >= 1 && x0 < 57) ? 1.0f : 0.0f;
        const float vx1 = (x1 >= 1 && x1 < 57) ? 1.0f : 0.0f;
        const float vy0 = (y0 >= 1 && y0 < 57) ? 1.0f : 0.0f;
        const float vy1 = (y1 >= 1 && y1 < 57) ? 1.0f : 0.0f;
        const int x0c = min(max(x0, 1), 56), x1c = min(max(x1, 1), 56);
        const int y0c = min(max(y0, 1), 56), y1c = min(max(y1, 1), 56);
        wtab[q][j][0] = m * (1.0f-wx) * (1.0f-wy) * vx0 * vy0;
        wtab[q][j][1] = m * wx        * (1.0f-wy) * vx1 * vy0;
        wtab[q][j][2] = m * (1.0f-wx) * wy        * vx0 * vy1;
        wtab[q][j][3] = m * wx        * wy        * vx1 * vy1;
        itab[q][j][0] = ((y0c-1)*WDIM + (x0c-1)) * CH;
        itab[q][j][1] = ((y0c-1)*WDIM + (x1c-1)) * CH;
        itab[q][j][2] = ((y1c-1)*WDIM + (x0c-1)) * CH;
        itab[q][j][3] = ((y1c-1)*WDIM + (x1c-1)) * CH;
    }
    __syncthreads();

    const int q = t >> 6, lane = t & 63;
    const int n = n0 + q;
    const int b = n / HW;
    const int g = lane >> 3;
    const float* vb = v + (size_t)b*HW*CH + lane*4;
    float4 acc = {0.0f, 0.0f, 0.0f, 0.0f};
    #pragma unroll
    for (int p = 0; p < NP; ++p) {
        const int j = g*NP + p;
        const float4 wv = *(const float4*)&wtab[q][j][0];
        const int4  iv = *(const int4*)&itab[q][j][0];
        const float4 c0 = *(const float4*)(vb + iv.x);
        const float4 c1 = *(const float4*)(vb + iv.y);
        const float4 c2 = *(const float4*)(vb + iv.z);
        const float4 c3 = *(const float4*)(vb + iv.w);
        acc.x += wv.x*c0.x + wv.y*c1.x + wv.z*c2.x + wv.w*c3.x;
        acc.y += wv.x*c0.y + wv.y*c1.y + wv.z*c2.y + wv.w*c3.y;
        acc.z += wv.x*c0.z + wv.y*c1.z + wv.z*c2.z + wv.w*c3.z;
        acc.w += wv.x*c0.w + wv.y*c1.w + wv.z*c2.w + wv.w*c3.w;
    }
    *(float4*)&s[(size_t)n*CH + lane*4] = acc;
}

// ---------------------------------------------------------------------------
// GEMM out from PRE-SPLIT bf16 A: y = SiLU(BN(s @ w_out + b_out)) NCHW.
// Load structure identical to gemm_in_mfma (the proven-fast variant);
// only the epilogue differs (BN+SiLU, NCHW scatter in 64B runs).
// ---------------------------------------------------------------------------
__global__ __launch_bounds__(256)
void gemm_out_bf16(const unsigned short* __restrict__ shp, // [m][k] bf16 hi
                   const unsigned short* __restrict__ slp, // [m][k] bf16 lo
                   const unsigned short* __restrict__ whi, // [256 n][256 k]
                   const unsigned short* __restrict__ wlo,
                   const float* __restrict__ bias,
                   const float* __restrict__ bn_g,
                   const float* __restrict__ bn_b,
                   const float* __restrict__ bn_mean,
                   const float* __restrict__ bn_var,
                   float* __restrict__ y)                  // [B,256,3136]
{
    const int m0 = blockIdx.x * 256;
    const int n0 = blockIdx.y * 64;
    const int t = threadIdx.x;
    const int lane = t & 63, wv = t >> 6;
    const int mblk = m0 + wv * 64;
    const int fm = lane & 15;
    const int q  = lane >> 4;

    f32x4 acc[4][4];
    const f32x4 zero = {0.0f, 0.0f, 0.0f, 0.0f};
    #pragma unroll
    for (int i = 0; i < 4; ++i)
        #pragma unroll
        for (int j = 0; j < 4; ++j) acc[i][j] = zero;

    const unsigned short *xrh[4], *xrl[4], *wrh[4], *wrl[4];
    #pragma unroll
    for (int mt = 0; mt < 4; ++mt) {
        xrh[mt] = shp + (size_t)(mblk + mt*16 + fm) * CH + q * 8;
        xrl[mt] = slp + (size_t)(mblk + mt*16 + fm) * CH + q * 8;
    }
    #pragma unroll
    for (int nt = 0; nt < 4; ++nt) {
        wrh[nt] = whi + (size_t)(n0 + nt*16 + fm) * CH + q * 8;
        wrl[nt] = wlo + (size_t)(n0 + nt*16 + fm) * CH + q * 8;
    }

    for (int k0 = 0; k0 < CH; k0 += 32) {
        s16x8 wh[4], wl[4], ah[4], al[4];
        #pragma unroll
        for (int nt = 0; nt < 4; ++nt) {
            wh[nt] = *(const s16x8*)(wrh[nt] + k0);
            wl[nt] = *(const s16x8*)(wrl[nt] + k0);
        }
        #pragma unroll
        for (int mt = 0; mt < 4; ++mt) {
            ah[mt] = *(const s16x8*)(xrh[mt] + k0);
            al[mt] = *(const s16x8*)(xrl[mt] + k0);
        }
        #pragma unroll
        for (int nt = 0; nt < 4; ++nt)
            #pragma unroll
            for (int mt = 0; mt < 4; ++mt) {
                acc[nt][mt] = __builtin_amdgcn_mfma_f32_16x16x32_bf16(wh[nt], ah[mt], acc[nt][mt], 0, 0, 0);
                acc[nt][mt] = __builtin_amdgcn_mfma_f32_16x16x32_bf16(wh[nt], al[mt], acc[nt][mt], 0, 0, 0);
                acc[nt][mt] = __builtin_amdgcn_mfma_f32_16x16x32_bf16(wl[nt], ah[mt], acc[nt][mt], 0, 0, 0);
            }
    }

    #pragma unroll
    for (int nt = 0; nt < 4; ++nt) {
        #pragma unroll
        for (int r = 0; r < 4; ++r) {
            const int n = n0 + nt*16 + q*4 + r;
            const float sc = bn_g[n] * rsqrtf(bn_var[n] + 1e-5f);
            const float sb = bn_b[n] - bn_mean[n] * sc;
            const float bs = bias[n];
            #pragma unroll
            for (int mt = 0; mt < 4; ++mt) {
                const int mm = mblk + mt*16;
                const size_t base = (size_t)(mm / HW) * CH * HW + (mm % HW);
                float val = (acc[nt][mt][r] + bs) * sc + sb;
                y[base + (size_t)n * HW + fm] = val / (1.0f + expf(-val));
            }
        }
    }
}

// ---------------------------------------------------------------------------
// Fallback GEMM out (f32 A, in-loop split2).
// ---------------------------------------------------------------------------
__global__ __launch_bounds__(256)
void gemm_out_mfma(const float* __restrict__ A,            // s [MTOT,256]
                   const unsigned short* __restrict__ whi, // [256 n][256 k] bf16
                   const unsigned short* __restrict__ wlo,
                   const float* __restrict__ bias,
                   const float* __restrict__ bn_g,
                   const float* __restrict__ bn_b,
                   const float* __restrict__ bn_mean,
                   const float* __restrict__ bn_var,
                   float* __restrict__ y)                  // [B,256,3136]
{
    const int m0 = blockIdx.x * 256;
    const int n0 = blockIdx.y * 64;
    const int t = threadIdx.x;
    const int lane = t & 63, wv = t >> 6;
    const int mblk = m0 + wv * 64;
    const int fm = lane & 15;
    const int q  = lane >> 4;

    f32x4 acc[4][4];
    const f32x4 zero = {0.0f, 0.0f, 0.0f, 0.0f};
    #pragma unroll
    for (int i = 0; i < 4; ++i)
        #pragma unroll
        for (int j = 0; j < 4; ++j) acc[i][j] = zero;

    const float* arow[4];
    const unsigned short* wrh[4];
    const unsigned short* wrl[4];
    #pragma unroll
    for (int mt = 0; mt < 4; ++mt)
        arow[mt] = A + (size_t)(mblk + mt*16 + fm) * CH + q * 8;
    #pragma unroll
    for (int nt = 0; nt < 4; ++nt) {
        wrh[nt] = whi + (size_t)(n0 + nt*16 + fm) * CH + q * 8;
        wrl[nt] = wlo + (size_t)(n0 + nt*16 + fm) * CH + q * 8;
    }

    for (int k0 = 0; k0 < CH; k0 += 32) {
        s16x8 wh[4], wl[4], sh[4], sl[4];
        #pragma unroll
        for (int nt = 0; nt < 4; ++nt) {
            wh[nt] = *(const s16x8*)(wrh[nt] + k0);
            wl[nt] = *(const s16x8*)(wrl[nt] + k0);
        }
        #pragma unroll
        for (int mt = 0; mt < 4; ++mt) {
            const f32x4 r0 = *(const f32x4*)(arow[mt] + k0);
            const f32x4 r1 = *(const f32x4*)(arow[mt] + k0 + 4);
            union { s16x8 v; unsigned int u[4]; } ph, pl;
            split2(r0[0], r0[1], ph.u[0], pl.u[0]);
            split2(r0[2], r0[3], ph.u[1], pl.u[1]);
            split2(r1[0], r1[1], ph.u[2], pl.u[2]);
            split2(r1[2], r1[3], ph.u[3], pl.u[3]);
            sh[mt] = ph.v; sl[mt] = pl.v;
        }
        #pragma unroll
        for (int nt = 0; nt < 4; ++nt)
            #pragma unroll
            for (int mt = 0; mt < 4; ++mt) {
                acc[nt][mt] = __builtin_amdgcn_mfma_f32_16x16x32_bf16(wh[nt], sh[mt], acc[nt][mt], 0, 0, 0);
                acc[nt][mt] = __builtin_amdgcn_mfma_f32_16x16x32_bf16(wh[nt], sl[mt], acc[nt][mt], 0, 0, 0);
                acc[nt][mt] = __builtin_amdgcn_mfma_f32_16x16x32_bf16(wl[nt], sh[mt], acc[nt][mt], 0, 0, 0);
            }
    }

    #pragma unroll
    for (int nt = 0; nt < 4; ++nt) {
        #pragma unroll
        for (int r = 0; r < 4; ++r) {
            const int n = n0 + nt*16 + q*4 + r;
            const float sc = bn_g[n] * rsqrtf(bn_var[n] + 1e-5f);
            const float sb = bn_b[n] - bn_mean[n] * sc;
            const float bs = bias[n];
            #pragma unroll
            for (int mt = 0; mt < 4; ++mt) {
                const int mm = mblk + mt*16;
                const size_t base = (size_t)(mm / HW) * CH * HW + (mm % HW);
                float val = (acc[nt][mt][r] + bs) * sc + sb;
                y[base + (size_t)n * HW + fm] = val / (1.0f + expf(-val));
            }
        }
    }
}

extern "C" void kernel_launch(void* const* d_in, const int* in_sizes, int n_in,
                              void* d_out, int out_size, void* d_ws, size_t ws_size,
                              hipStream_t stream) {
    const float* x      = (const float*)d_in[0];
    const float* w_in   = (const float*)d_in[1];
    const float* b_in   = (const float*)d_in[2];
    const float* dw_w   = (const float*)d_in[3];
    const float* dw_b   = (const float*)d_in[4];
    const float* ln_g   = (const float*)d_in[5];
    const float* ln_b   = (const float*)d_in[6];
    const float* w_off  = (const float*)d_in[7];
    const float* b_off  = (const float*)d_in[8];
    const float* w_mask = (const float*)d_in[9];
    const float* b_mask = (const float*)d_in[10];
    const float* w_out  = (const float*)d_in[11];
    const float* b_out  = (const float*)d_in[12];
    const float* bn_g   = (const float*)d_in[13];
    const float* bn_b   = (const float*)d_in[14];
    const float* bn_mean= (const float*)d_in[15];
    const float* bn_var = (const float*)d_in[16];
    float* out = (float*)d_out;

    const size_t SZ = (size_t)MTOT * CH;                 // elements
    // Layout: v | xt_hi,xt_lo | fh,fl | omb | weights | bcat
    const size_t need_new =
        4 * SZ * sizeof(float)
        + 6 * (size_t)CH * CH * sizeof(unsigned short)
        + CH * sizeof(float);

    if (ws_size >= need_new) {
        // -------- main path --------
        float* ws = (float*)d_ws;
        float* v    = ws;                                          // SZ f32
        unsigned short* xt_hi = (unsigned short*)(v + SZ);         // SZ us
        unsigned short* xt_lo = xt_hi + SZ;                        // SZ us
        unsigned short* fh    = xt_lo + SZ;                        // SZ us
        unsigned short* fl    = fh + SZ;                           // SZ us
        float* omb  = (float*)(fl + SZ);                           // SZ f32
        unsigned short* wt_hi  = (unsigned short*)(omb + SZ);
        unsigned short* wt_lo  = wt_hi + CH * CH;
        unsigned short* wt2_hi = wt_lo + CH * CH;
        unsigned short* wt2_lo = wt2_hi + CH * CH;
        unsigned short* wt3_hi = wt2_lo + CH * CH;
        unsigned short* wt3_lo = wt3_hi + CH * CH;
        float* bcat = (float*)(wt3_lo + CH * CH);                  // 256 f32
        // sh/sl overlay xt region (xt consumed by gemm_in + dw before sample).
        unsigned short* sh = xt_hi;
        unsigned short* sl = xt_lo;

        wt_split_kernel<<<dim3(4, 4), dim3(256), 0, stream>>>(w_out, wt_hi, wt_lo);
        wt_split_kernel<<<dim3(4, 4), dim3(256), 0, stream>>>(w_in, wt3_hi, wt3_lo);
        wt2_split_kernel<<<dim3(16), dim3(256), 0, stream>>>(
            w_off, w_mask, b_off, b_mask, wt2_hi, wt2_lo, bcat);
        xt_split_kernel<<<dim3(HW/64, CH/64, BATCH), dim3(256), 0, stream>>>(x, xt_hi, xt_lo);
        gemm_in_mfma<<<dim3(MTOT/256, CH/64), dim3(256), 0, stream>>>(
            xt_hi, xt_lo, wt3_hi, wt3_lo, b_in, v);
        dw_ln_gelu_nhwc_split<<<dim3(MTOT/POSB), dim3(256), 0, stream>>>(
            xt_hi, xt_lo, dw_w, dw_b, ln_g, ln_b, fh, fl);
        gemm_in_mfma<<<dim3(MTOT/256, CH/64), dim3(256), 0, stream>>>(
            fh, fl, wt2_hi, wt2_lo, bcat, omb);
        sample_kernel_omb_split<<<dim3(MTOT/POSB), dim3(256), 0, stream>>>(v, omb, sh, sl);
        gemm_out_bf16<<<dim3(MTOT/256, CH/64), dim3(256), 0, stream>>>(
            sh, sl, wt_hi, wt_lo, b_out, bn_g, bn_b, bn_mean, bn_var, out);
    } else {
        // -------- fallback: round-1 verified path (xt overlays f) --------
        float* ws   = (float*)d_ws;
        float* v    = ws;                                   // SZ f32
        float* f    = v + SZ;                               // SZ f32
        float* offb = f + SZ;                               // MTOT*NOFF
        float* mskb = offb + (size_t)MTOT * NOFF;           // MTOT*NMSK
        float* s    = f;                                    // reuse f buffer
        unsigned short* wt_hi  = (unsigned short*)(mskb + (size_t)MTOT * NMSK);
        unsigned short* wt_lo  = wt_hi + CH * CH;
        unsigned short* wt2_hi = wt_lo + CH * CH;
        unsigned short* wt2_lo = wt2_hi + CH * CH;
        unsigned short* wt3_hi = wt2_lo + CH * CH;
        unsigned short* wt3_lo = wt3_hi + CH * CH;
        float* bcat = (float*)(wt3_lo + CH * CH);           // 256 f32 (unused)
        unsigned short* xt_hi = (unsigned short*)f;
        unsigned short* xt_lo = xt_hi + SZ;

        wt_split_kernel<<<dim3(4, 4), dim3(256), 0, stream>>>(w_out, wt_hi, wt_lo);
        wt_split_kernel<<<dim3(4, 4), dim3(256), 0, stream>>>(w_in, wt3_hi, wt3_lo);
        wt2_split_kernel<<<dim3(16), dim3(256), 0, stream>>>(
            w_off, w_mask, b_off, b_mask, wt2_hi, wt2_lo, bcat);
        xt_split_kernel<<<dim3(HW/64, CH/64, BATCH), dim3(256), 0, stream>>>(x, xt_hi, xt_lo);
        gemm_in_mfma<<<dim3(MTOT/256, CH/64), dim3(256), 0, stream>>>(
            xt_hi, xt_lo, wt3_hi, wt3_lo, b_in, v);
        dw_ln_gelu_kernel<<<dim3(HDIM, BATCH), dim3(256), 0, stream>>>(x, dw_w, dw_b, ln_g, ln_b, f);
        gemm_offmask_mfma<<<dim3(MTOT/256, 4), dim3(256), 0, stream>>>(
            f, wt2_hi, wt2_lo, b_off, b_mask, offb, mskb);
        sample_kernel<<<dim3(MTOT/POSB), dim3(256), 0, stream>>>(v, offb, mskb, s);
        gemm_out_mfma<<<dim3(MTOT/256, CH/64), dim3(256), 0, stream>>>(
            s, wt_hi, wt_lo, b_out, bn_g, bn_b, bn_mean, bn_var, out);
    }
}

// Round 6
// 289.548 us; speedup vs baseline: 1.1388x; 1.0089x over previous
//
#include <hip/hip_runtime.h>
#include <math.h>

// Problem constants
#define BATCH 8
#define CH    256
#define HDIM  56
#define WDIM  56
#define HW    (HDIM*WDIM)          // 3136
#define MTOT  (BATCH*HW)           // 25088
#define GRP   8
#define GC    32
#define NP    9                    // K*K
#define NOFF  (GRP*NP*2)           // 144
#define NMSK  (GRP*NP)             // 72
#define NTOT  (NOFF+NMSK)          // 216
#define POSB  4                    // positions per sample block

typedef float f32x4 __attribute__((ext_vector_type(4)));
typedef short s16x8 __attribute__((ext_vector_type(8)));

// split a,b into packed bf16 hi (truncation) and bf16 lo (exact remainder, truncated)
__device__ inline void split2(float a, float b, unsigned int& hp, unsigned int& lp)
{
    const unsigned int ua = __float_as_uint(a), ub = __float_as_uint(b);
    hp = (ub & 0xffff0000u) | (ua >> 16);
    const float ha = __uint_as_float(ua & 0xffff0000u);
    const float hb = __uint_as_float(ub & 0xffff0000u);
    const unsigned int la = __float_as_uint(a - ha), lb = __float_as_uint(b - hb);
    lp = (lb & 0xffff0000u) | (la >> 16);
}

// ---------------------------------------------------------------------------
// Transpose + split x (NCHW) -> xt_hi/xt_lo [m][k] bf16. 64x64 LDS tiles.
// ---------------------------------------------------------------------------
__global__ __launch_bounds__(256)
void xt_split_kernel(const float* __restrict__ x,
                     unsigned short* __restrict__ hi,
                     unsigned short* __restrict__ lo)
{
    __shared__ float lds[64][68];
    const int hw0 = blockIdx.x * 64;       // 49 tiles (3136/64)
    const int k0  = blockIdx.y * 64;       // 4 tiles
    const int b   = blockIdx.z;            // 8
    const int t = threadIdx.x;
    #pragma unroll
    for (int p = 0; p < 4; ++p) {
        const int kr = (t >> 4) + p * 16;
        const int hc = (t & 15) * 4;
        *(float4*)&lds[kr][hc] =
            *(const float4*)(x + ((size_t)b * CH + k0 + kr) * HW + hw0 + hc);
    }
    __syncthreads();
    const int ml = t >> 2;             // m-row 0..63
    const int kc = (t & 3) * 16;       // k base 0,16,32,48
    unsigned int hbuf[8], lbuf[8];
    #pragma unroll
    for (int j = 0; j < 16; j += 2)
        split2(lds[kc + j][ml], lds[kc + j + 1][ml], hbuf[j >> 1], lbuf[j >> 1]);
    const size_t row = (size_t)(b * HW + hw0 + ml) * CH + k0 + kc;
    *(uint4*)&hi[row]     = *(uint4*)&hbuf[0];
    *(uint4*)&hi[row + 8] = *(uint4*)&hbuf[4];
    *(uint4*)&lo[row]     = *(uint4*)&lbuf[0];
    *(uint4*)&lo[row + 8] = *(uint4*)&lbuf[4];
}

// ---------------------------------------------------------------------------
// NEW GEMM skeleton: one block per 64-row m-tile (grid 392), 4 waves = 4
// n-panels of 64. All 4 waves read the SAME A rows -> A is fetched from HBM
// once per block (L1 broadcast), not once per XCD-scattered n-block (round-5
// FETCH showed 2.3x A over-fetch). Explicit register double-buffer on the
// fully-unrolled 8-step k-loop doubles outstanding loads (latency-bound fix).
// Bit-identical math: same k order, same 3-MFMA hi/lo sequence.
// ---------------------------------------------------------------------------
__global__ __launch_bounds__(256)
void gemm64_f32(const unsigned short* __restrict__ ahi, // [m][k] bf16 hi
                const unsigned short* __restrict__ alo, // [m][k] bf16 lo
                const unsigned short* __restrict__ whi, // [n][k] bf16 hi
                const unsigned short* __restrict__ wlo, // [n][k] bf16 lo
                const float* __restrict__ bias,
                float* __restrict__ out)                // [MTOT][256] f32
{
    const int bid = blockIdx.x;                       // 392 = 8 * 49
    const int sw  = (bid & 7) * (MTOT / 64 / 8) + (bid >> 3);
    const int m0  = sw * 64;
    const int t = threadIdx.x;
    const int lane = t & 63, wv = t >> 6;
    const int n0 = wv * 64;
    const int fm = lane & 15, q = lane >> 4;

    f32x4 acc[4][4];              // [nt][mt]
    const f32x4 zero = {0.0f, 0.0f, 0.0f, 0.0f};
    #pragma unroll
    for (int i = 0; i < 4; ++i)
        #pragma unroll
        for (int j = 0; j < 4; ++j) acc[i][j] = zero;

    const unsigned short *pah[4], *pal[4], *pwh[4], *pwl[4];
    #pragma unroll
    for (int mt = 0; mt < 4; ++mt) {
        pah[mt] = ahi + (size_t)(m0 + mt*16 + fm) * CH + q * 8;
        pal[mt] = alo + (size_t)(m0 + mt*16 + fm) * CH + q * 8;
    }
    #pragma unroll
    for (int nt = 0; nt < 4; ++nt) {
        pwh[nt] = whi + (size_t)(n0 + nt*16 + fm) * CH + q * 8;
        pwl[nt] = wlo + (size_t)(n0 + nt*16 + fm) * CH + q * 8;
    }

    s16x8 ah[2][4], al[2][4], wh[2][4], wl[2][4];
    #pragma unroll
    for (int i = 0; i < 4; ++i) {
        ah[0][i] = *(const s16x8*)(pah[i]);
        al[0][i] = *(const s16x8*)(pal[i]);
        wh[0][i] = *(const s16x8*)(pwh[i]);
        wl[0][i] = *(const s16x8*)(pwl[i]);
    }
    #pragma unroll
    for (int kk = 0; kk < 8; ++kk) {
        const int cur = kk & 1, nxt = cur ^ 1;
        if (kk < 7) {
            const int ko = (kk + 1) * 32;
            #pragma unroll
            for (int i = 0; i < 4; ++i) {
                ah[nxt][i] = *(const s16x8*)(pah[i] + ko);
                al[nxt][i] = *(const s16x8*)(pal[i] + ko);
                wh[nxt][i] = *(const s16x8*)(pwh[i] + ko);
                wl[nxt][i] = *(const s16x8*)(pwl[i] + ko);
            }
        }
        #pragma unroll
        for (int nt = 0; nt < 4; ++nt)
            #pragma unroll
            for (int mt = 0; mt < 4; ++mt) {
                acc[nt][mt] = __builtin_amdgcn_mfma_f32_16x16x32_bf16(wh[cur][nt], ah[cur][mt], acc[nt][mt], 0, 0, 0);
                acc[nt][mt] = __builtin_amdgcn_mfma_f32_16x16x32_bf16(wh[cur][nt], al[cur][mt], acc[nt][mt], 0, 0, 0);
                acc[nt][mt] = __builtin_amdgcn_mfma_f32_16x16x32_bf16(wl[cur][nt], ah[cur][mt], acc[nt][mt], 0, 0, 0);
            }
    }

    #pragma unroll
    for (int nt = 0; nt < 4; ++nt) {
        const float4 b4 = *(const float4*)&bias[n0 + nt*16 + q*4];
        #pragma unroll
        for (int mt = 0; mt < 4; ++mt) {
            f32x4 o = acc[nt][mt];
            o[0] += b4.x; o[1] += b4.y; o[2] += b4.z; o[3] += b4.w;
            *(f32x4*)&out[(size_t)(m0 + mt*16 + fm) * CH + n0 + nt*16 + q*4] = o;
        }
    }
}

// ---------------------------------------------------------------------------
// Same skeleton, BN+SiLU NCHW epilogue (output projection).
// ---------------------------------------------------------------------------
__global__ __launch_bounds__(256)
void gemm64_out(const unsigned short* __restrict__ ahi,
                const unsigned short* __restrict__ alo,
                const unsigned short* __restrict__ whi,
                const unsigned short* __restrict__ wlo,
                const float* __restrict__ bias,
                const float* __restrict__ bn_g,
                const float* __restrict__ bn_b,
                const float* __restrict__ bn_mean,
                const float* __restrict__ bn_var,
                float* __restrict__ y)                  // [B,256,3136]
{
    const int bid = blockIdx.x;
    const int sw  = (bid & 7) * (MTOT / 64 / 8) + (bid >> 3);
    const int m0  = sw * 64;
    const int t = threadIdx.x;
    const int lane = t & 63, wv = t >> 6;
    const int n0 = wv * 64;
    const int fm = lane & 15, q = lane >> 4;

    f32x4 acc[4][4];
    const f32x4 zero = {0.0f, 0.0f, 0.0f, 0.0f};
    #pragma unroll
    for (int i = 0; i < 4; ++i)
        #pragma unroll
        for (int j = 0; j < 4; ++j) acc[i][j] = zero;

    const unsigned short *pah[4], *pal[4], *pwh[4], *pwl[4];
    #pragma unroll
    for (int mt = 0; mt < 4; ++mt) {
        pah[mt] = ahi + (size_t)(m0 + mt*16 + fm) * CH + q * 8;
        pal[mt] = alo + (size_t)(m0 + mt*16 + fm) * CH + q * 8;
    }
    #pragma unroll
    for (int nt = 0; nt < 4; ++nt) {
        pwh[nt] = whi + (size_t)(n0 + nt*16 + fm) * CH + q * 8;
        pwl[nt] = wlo + (size_t)(n0 + nt*16 + fm) * CH + q * 8;
    }

    s16x8 ah[2][4], al[2][4], wh[2][4], wl[2][4];
    #pragma unroll
    for (int i = 0; i < 4; ++i) {
        ah[0][i] = *(const s16x8*)(pah[i]);
        al[0][i] = *(const s16x8*)(pal[i]);
        wh[0][i] = *(const s16x8*)(pwh[i]);
        wl[0][i] = *(const s16x8*)(pwl[i]);
    }
    #pragma unroll
    for (int kk = 0; kk < 8; ++kk) {
        const int cur = kk & 1, nxt = cur ^ 1;
        if (kk < 7) {
            const int ko = (kk + 1) * 32;
            #pragma unroll
            for (int i = 0; i < 4; ++i) {
                ah[nxt][i] = *(const s16x8*)(pah[i] + ko);
                al[nxt][i] = *(const s16x8*)(pal[i] + ko);
                wh[nxt][i] = *(const s16x8*)(pwh[i] + ko);
                wl[nxt][i] = *(const s16x8*)(pwl[i] + ko);
            }
        }
        #pragma unroll
        for (int nt = 0; nt < 4; ++nt)
            #pragma unroll
            for (int mt = 0; mt < 4; ++mt) {
                acc[nt][mt] = __builtin_amdgcn_mfma_f32_16x16x32_bf16(wh[cur][nt], ah[cur][mt], acc[nt][mt], 0, 0, 0);
                acc[nt][mt] = __builtin_amdgcn_mfma_f32_16x16x32_bf16(wh[cur][nt], al[cur][mt], acc[nt][mt], 0, 0, 0);
                acc[nt][mt] = __builtin_amdgcn_mfma_f32_16x16x32_bf16(wl[cur][nt], ah[cur][mt], acc[nt][mt], 0, 0, 0);
            }
    }

    const size_t base = (size_t)(m0 / HW) * CH * HW + (m0 % HW);
    #pragma unroll
    for (int nt = 0; nt < 4; ++nt) {
        #pragma unroll
        for (int r = 0; r < 4; ++r) {
            const int n = n0 + nt*16 + q*4 + r;
            const float sc = bn_g[n] * rsqrtf(bn_var[n] + 1e-5f);
            const float sb = bn_b[n] - bn_mean[n] * sc;
            const float bs = bias[n];
            #pragma unroll
            for (int mt = 0; mt < 4; ++mt) {
                float val = (acc[nt][mt][r] + bs) * sc + sb;
                y[base + (size_t)n * HW + mt*16 + fm] = val / (1.0f + expf(-val));
            }
        }
    }
}

// ---------------------------------------------------------------------------
// Fallback GEMM (proven round-4 structure): 256m x 64n blocks, grid (98,4).
// ---------------------------------------------------------------------------
__global__ __launch_bounds__(256)
void gemm_in_mfma(const unsigned short* __restrict__ xhi, // [m][k]
                  const unsigned short* __restrict__ xlo,
                  const unsigned short* __restrict__ whi, // [n][k]
                  const unsigned short* __restrict__ wlo,
                  const float* __restrict__ bias,
                  float* __restrict__ v)                  // [MTOT,256]
{
    const int m0 = blockIdx.x * 256;
    const int n0 = blockIdx.y * 64;
    const int t = threadIdx.x;
    const int lane = t & 63, wv = t >> 6;
    const int mblk = m0 + wv * 64;
    const int fm = lane & 15;
    const int q  = lane >> 4;

    f32x4 acc[4][4];              // [nt][mt]
    const f32x4 zero = {0.0f, 0.0f, 0.0f, 0.0f};
    #pragma unroll
    for (int i = 0; i < 4; ++i)
        #pragma unroll
        for (int j = 0; j < 4; ++j) acc[i][j] = zero;

    const unsigned short *xrh[4], *xrl[4], *wrh[4], *wrl[4];
    #pragma unroll
    for (int mt = 0; mt < 4; ++mt) {
        xrh[mt] = xhi + (size_t)(mblk + mt*16 + fm) * CH + q * 8;
        xrl[mt] = xlo + (size_t)(mblk + mt*16 + fm) * CH + q * 8;
    }
    #pragma unroll
    for (int nt = 0; nt < 4; ++nt) {
        wrh[nt] = whi + (size_t)(n0 + nt*16 + fm) * CH + q * 8;
        wrl[nt] = wlo + (size_t)(n0 + nt*16 + fm) * CH + q * 8;
    }

    for (int k0 = 0; k0 < CH; k0 += 32) {
        s16x8 wh[4], wl[4], ah[4], al[4];
        #pragma unroll
        for (int nt = 0; nt < 4; ++nt) {
            wh[nt] = *(const s16x8*)(wrh[nt] + k0);
            wl[nt] = *(const s16x8*)(wrl[nt] + k0);
        }
        #pragma unroll
        for (int mt = 0; mt < 4; ++mt) {
            ah[mt] = *(const s16x8*)(xrh[mt] + k0);
            al[mt] = *(const s16x8*)(xrl[mt] + k0);
        }
        #pragma unroll
        for (int nt = 0; nt < 4; ++nt)
            #pragma unroll
            for (int mt = 0; mt < 4; ++mt) {
                acc[nt][mt] = __builtin_amdgcn_mfma_f32_16x16x32_bf16(wh[nt], ah[mt], acc[nt][mt], 0, 0, 0);
                acc[nt][mt] = __builtin_amdgcn_mfma_f32_16x16x32_bf16(wh[nt], al[mt], acc[nt][mt], 0, 0, 0);
                acc[nt][mt] = __builtin_amdgcn_mfma_f32_16x16x32_bf16(wl[nt], ah[mt], acc[nt][mt], 0, 0, 0);
            }
    }

    #pragma unroll
    for (int nt = 0; nt < 4; ++nt) {
        const float4 b4 = *(const float4*)&bias[n0 + nt*16 + q*4];
        #pragma unroll
        for (int mt = 0; mt < 4; ++mt) {
            f32x4 o = acc[nt][mt];
            o[0] += b4.x; o[1] += b4.y; o[2] += b4.z; o[3] += b4.w;
            *(f32x4*)&v[(size_t)(mblk + mt*16 + fm) * CH + n0 + nt*16 + q*4] = o;
        }
    }
}

// ---------------------------------------------------------------------------
// Per-position-wave depthwise 3x3 + bias + LN + GELU from NHWC bf16 hi/lo xt,
// output stored PRE-SPLIT as bf16 hi/lo. One wave per position.
// ---------------------------------------------------------------------------
__global__ __launch_bounds__(256)
void dw_ln_gelu_nhwc_split(const unsigned short* __restrict__ xhi,
                           const unsigned short* __restrict__ xlo,
                           const float* __restrict__ dw_w,   // [256][9]
                           const float* __restrict__ dw_b,
                           const float* __restrict__ ln_g,
                           const float* __restrict__ ln_b,
                           unsigned short* __restrict__ fh,  // [MTOT][256]
                           unsigned short* __restrict__ fl)  // [MTOT][256]
{
    __shared__ float wt[NP][CH];                       // transposed dw weights
    __shared__ float lbias[CH], lgam[CH], lbet[CH];

    const int t = threadIdx.x;
    {
        const float* wp = dw_w + t * NP;
        #pragma unroll
        for (int p = 0; p < NP; ++p) wt[p][t] = wp[p];
        lbias[t] = dw_b[t]; lgam[t] = ln_g[t]; lbet[t] = ln_b[t];
    }
    __syncthreads();

    const int nblk = MTOT / POSB;          // 6272
    const int per  = nblk / 8;             // 784
    const int bid  = blockIdx.x;
    const int sw   = (bid & 7) * per + (bid >> 3);
    const int q    = t >> 6, lane = t & 63;
    const int n    = sw * POSB + q;
    const int b    = n / HW;
    const int hw   = n % HW;
    const int h    = hw / WDIM, w = hw % WDIM;
    const int c4   = lane * 4;
    const size_t base = (size_t)b * HW * CH + c4;

    float ax = 0.0f, ay = 0.0f, az = 0.0f, aw = 0.0f;
    #pragma unroll
    for (int p = 0; p < NP; ++p) {
        const int hh = h + p / 3 - 1;
        const int ww = w + p % 3 - 1;
        if ((unsigned)hh >= (unsigned)HDIM || (unsigned)ww >= (unsigned)WDIM)
            continue;                       // wave-uniform branch (h,w per-wave)
        const size_t idx = base + (size_t)(hh * WDIM + ww) * CH;
        const ushort4 uh = *(const ushort4*)(xhi + idx);
        const ushort4 ul = *(const ushort4*)(xlo + idx);
        const float4 wv = *(const float4*)&wt[p][c4];
        ax = fmaf(__uint_as_float((unsigned)uh.x << 16), wv.x,
             fmaf(__uint_as_float((unsigned)ul.x << 16), wv.x, ax));
        ay = fmaf(__uint_as_float((unsigned)uh.y << 16), wv.y,
             fmaf(__uint_as_float((unsigned)ul.y << 16), wv.y, ay));
        az = fmaf(__uint_as_float((unsigned)uh.z << 16), wv.z,
             fmaf(__uint_as_float((unsigned)ul.z << 16), wv.z, az));
        aw = fmaf(__uint_as_float((unsigned)uh.w << 16), wv.w,
             fmaf(__uint_as_float((unsigned)ul.w << 16), wv.w, aw));
    }
    {
        const float4 b4 = *(const float4*)&lbias[c4];
        ax += b4.x; ay += b4.y; az += b4.z; aw += b4.w;
    }

    // LayerNorm over the wave's 256 channel values: in-wave butterfly.
    float s1 = ax + ay + az + aw;
    float s2 = ax*ax + ay*ay + az*az + aw*aw;
    #pragma unroll
    for (int off = 32; off > 0; off >>= 1) {
        s1 += __shfl_xor(s1, off);
        s2 += __shfl_xor(s2, off);
    }
    const float mean = s1 * (1.0f / 256.0f);
    const float rstd = rsqrtf(s2 * (1.0f / 256.0f) - mean * mean + 1e-5f);

    const float4 g4 = *(const float4*)&lgam[c4];
    const float4 e4 = *(const float4*)&lbet[c4];
    const float x0 = (ax - mean) * rstd * g4.x + e4.x;
    const float x1 = (ay - mean) * rstd * g4.y + e4.y;
    const float x2 = (az - mean) * rstd * g4.z + e4.z;
    const float x3 = (aw - mean) * rstd * g4.w + e4.w;
    const float o0 = 0.5f * x0 * (1.0f + erff(x0 * 0.70710678118654752f));
    const float o1 = 0.5f * x1 * (1.0f + erff(x1 * 0.70710678118654752f));
    const float o2 = 0.5f * x2 * (1.0f + erff(x2 * 0.70710678118654752f));
    const float o3 = 0.5f * x3 * (1.0f + erff(x3 * 0.70710678118654752f));

    unsigned int hp0, lp0, hp1, lp1;
    split2(o0, o1, hp0, lp0);
    split2(o2, o3, hp1, lp1);
    *(uint2*)&fh[(size_t)n * CH + c4] = make_uint2(hp0, hp1);
    *(uint2*)&fl[(size_t)n * CH + c4] = make_uint2(lp0, lp1);
}

// ---------------------------------------------------------------------------
// Transpose + hi/lo bf16 split of a [256k][256n] fp32 weight -> [n][k] bf16.
// ---------------------------------------------------------------------------
__global__ __launch_bounds__(256)
void wt_split_kernel(const float* __restrict__ w,
                     unsigned short* __restrict__ hi,
                     unsigned short* __restrict__ lo)
{
    __shared__ float lds[64][68];
    const int kt = blockIdx.x * 64, nt = blockIdx.y * 64;
    const int t = threadIdx.x;
    #pragma unroll
    for (int p = 0; p < 4; ++p) {
        const int kr = (t >> 4) + p * 16, nc = (t & 15) * 4;
        *(float4*)&lds[kr][nc] = *(const float4*)(w + (size_t)(kt + kr) * CH + nt + nc);
    }
    __syncthreads();
    const int nl = t >> 2, kc = (t & 3) * 16;
    #pragma unroll
    for (int j = 0; j < 16; j += 2) {
        const float f0 = lds[kc + j][nl], f1 = lds[kc + j + 1][nl];
        unsigned int hp, lp;
        split2(f0, f1, hp, lp);
        *(unsigned int*)&hi[(size_t)(nt + nl) * CH + kt + kc + j] = hp;
        *(unsigned int*)&lo[(size_t)(nt + nl) * CH + kt + kc + j] = lp;
    }
}

// ---------------------------------------------------------------------------
// Transpose + split of [w_off | w_mask] -> wt2_hi/lo [256 n_pad][256 k] bf16.
// Also builds bcat[256] = [b_off | b_mask | 0] (block 0 only).
// ---------------------------------------------------------------------------
__global__ __launch_bounds__(256)
void wt2_split_kernel(const float* __restrict__ w_off,   // [256][144]
                      const float* __restrict__ w_mask,  // [256][72]
                      const float* __restrict__ b_off,
                      const float* __restrict__ b_mask,
                      unsigned short* __restrict__ hi,
                      unsigned short* __restrict__ lo,
                      float* __restrict__ bcat)          // [256]
{
    const int n = threadIdx.x;
    if (blockIdx.x == 0) {
        bcat[n] = (n < NOFF) ? b_off[n] : ((n < NTOT) ? b_mask[n - NOFF] : 0.0f);
    }
    const int k0 = blockIdx.x * 16;
    #pragma unroll
    for (int j = 0; j < 16; j += 2) {
        const int k = k0 + j;
        float f0 = 0.0f, f1 = 0.0f;
        if (n < NOFF) {
            f0 = w_off[(size_t)k * NOFF + n];
            f1 = w_off[(size_t)(k + 1) * NOFF + n];
        } else if (n < NTOT) {
            f0 = w_mask[(size_t)k * NMSK + (n - NOFF)];
            f1 = w_mask[(size_t)(k + 1) * NMSK + (n - NOFF)];
        }
        unsigned int hp, lp;
        split2(f0, f1, hp, lp);
        *(unsigned int*)&hi[(size_t)n * CH + k] = hp;
        *(unsigned int*)&lo[(size_t)n * CH + k] = lp;
    }
}

// ---------------------------------------------------------------------------
// Deformable sampling reading the padded omb [MTOT][256] rows
// (cols 0..143 offsets, 144..215 mask logits). Output s PRE-SPLIT bf16 hi/lo.
// ---------------------------------------------------------------------------
__global__ __launch_bounds__(256)
void sample_kernel_omb_split(const float* __restrict__ v,
                             const float* __restrict__ omb,
                             unsigned short* __restrict__ sh,  // [MTOT][256]
                             unsigned short* __restrict__ sl)  // [MTOT][256]
{
    __shared__ alignas(16) float loff[POSB][NOFF];
    __shared__ alignas(16) float lmsk[POSB][NMSK];
    __shared__ alignas(16) float wtab[POSB][GRP*NP][4];
    __shared__ alignas(16) int   itab[POSB][GRP*NP][4];

    const int nblk = MTOT / POSB;            // 6272
    const int per  = nblk / 8;               // 784
    const int bid  = blockIdx.x;
    const int sw   = (bid % 8) * per + (bid / 8);
    const int n0 = sw * POSB;
    const int t = threadIdx.x;

    if (t < POSB * (NOFF/4)) {
        const int q = t / (NOFF/4), r = t % (NOFF/4);
        *(float4*)&loff[q][r*4] = *(const float4*)&omb[(size_t)(n0+q)*CH + r*4];
    } else if (t < POSB * (NOFF/4) + POSB * (NMSK/4)) {
        const int u = t - POSB * (NOFF/4);
        const int q = u / (NMSK/4), r = u % (NMSK/4);
        *(float4*)&lmsk[q][r*4] = *(const float4*)&omb[(size_t)(n0+q)*CH + NOFF + r*4];
    }
    __syncthreads();

    if (t < POSB * GRP) {
        const int q = t >> 3, g = t & 7;
        float* mm = &lmsk[q][g * NP];
        float mx = -1e30f;
        #pragma unroll
        for (int p = 0; p < NP; ++p) mx = fmaxf(mx, mm[p]);
        float sum = 0.0f;
        #pragma unroll
        for (int p = 0; p < NP; ++p) { const float e = __expf(mm[p] - mx); mm[p] = e; sum += e; }
        const float inv = 1.0f / sum;
        #pragma unroll
        for (int p = 0; p < NP; ++p) mm[p] *= inv;
    }
    __syncthreads();

    for (int u = t; u < POSB * GRP * NP; u += 256) {
        const int q = u / (GRP*NP), j = u % (GRP*NP);
        const int g = j / NP, p = j % NP;
        const int n = n0 + q;
        const int hw = n % HW;
        const int h = hw / WDIM, w = hw % WDIM;
        const float ox = loff[q][g*18 + p*2 + 0];
        const float oy = loff[q][g*18 + p*2 + 1];
        const float m  = lmsk[q][g*NP + p];
        const float px = (float)(w + p/3) + ox;
        const float py = (float)(h + p%3) + oy;
        const float fx = floorf(px), fy = floorf(py);
        const float wx = px - fx, wy = py - fy;
        const int x0 = (int)fx, y0 = (int)fy;
        const int x1 = x0 + 1, y1 = y0 + 1;
        const float vx0 = (x0 >= 1 && x0 < 57) ? 1.0f : 0.0f;
        const float vx1 = (x1 >= 1 && x1 < 57) ? 1.0f : 0.0f;
        const float vy0 = (y0 >= 1 && y0 < 57) ? 1.0f : 0.0f;
        const float vy1 = (y1 >= 1 && y1 < 57) ? 1.0f : 0.0f;
        const int x0c = min(max(x0, 1), 56), x1c = min(max(x1, 1), 56);
        const int y0c = min(max(y0, 1), 56), y1c = min(max(y1, 1), 56);
        wtab[q][j][0] = m * (1.0f-wx) * (1.0f-wy) * vx0 * vy0;
        wtab[q][j][1] = m * wx        * (1.0f-wy) * vx1 * vy0;
        wtab[q][j][2] = m * (1.0f-wx) * wy        * vx0 * vy1;
        wtab[q][j][3] = m * wx        * wy        * vx1 * vy1;
        itab[q][j][0] = ((y0c-1)*WDIM + (x0c-1)) * CH;
        itab[q][j][1] = ((y0c-1)*WDIM + (x1c-1)) * CH;
        itab[q][j][2] = ((y1c-1)*WDIM + (x0c-1)) * CH;
        itab[q][j][3] = ((y1c-1)*WDIM + (x1c-1)) * CH;
    }
    __syncthreads();

    const int q = t >> 6, lane = t & 63;
    const int n = n0 + q;
    const int b = n / HW;
    const int g = lane >> 3;
    const float* vb = v + (size_t)b*HW*CH + lane*4;
    float4 acc = {0.0f, 0.0f, 0.0f, 0.0f};
    #pragma unroll
    for (int p = 0; p < NP; ++p) {
        const int j = g*NP + p;
        const float4 wv = *(const float4*)&wtab[q][j][0];
        const int4  iv = *(const int4*)&itab[q][j][0];
        const float4 c0 = *(const float4*)(vb + iv.x);
        const float4 c1 = *(const float4*)(vb + iv.y);
        const float4 c2 = *(const float4*)(vb + iv.z);
        const float4 c3 = *(const float4*)(vb + iv.w);
        acc.x += wv.x*c0.x + wv.y*c1.x + wv.z*c2.x + wv.w*c3.x;
        acc.y += wv.x*c0.y + wv.y*c1.y + wv.z*c2.y + wv.w*c3.y;
        acc.z += wv.x*c0.z + wv.y*c1.z + wv.z*c2.z + wv.w*c3.z;
        acc.w += wv.x*c0.w + wv.y*c1.w + wv.z*c2.w + wv.w*c3.w;
    }
    unsigned int hp0, lp0, hp1, lp1;
    split2(acc.x, acc.y, hp0, lp0);
    split2(acc.z, acc.w, hp1, lp1);
    *(uint2*)&sh[(size_t)n*CH + lane*4] = make_uint2(hp0, hp1);
    *(uint2*)&sl[(size_t)n*CH + lane*4] = make_uint2(lp0, lp1);
}

// ---------------------------------------------------------------------------
// Fallback GEMM out from PRE-SPLIT bf16 A (round-5 structure, grid (98,4)).
// ---------------------------------------------------------------------------
__global__ __launch_bounds__(256)
void gemm_out_bf16(const unsigned short* __restrict__ shp, // [m][k] bf16 hi
                   const unsigned short* __restrict__ slp, // [m][k] bf16 lo
                   const unsigned short* __restrict__ whi, // [256 n][256 k]
                   const unsigned short* __restrict__ wlo,
                   const float* __restrict__ bias,
                   const float* __restrict__ bn_g,
                   const float* __restrict__ bn_b,
                   const float* __restrict__ bn_mean,
                   const float* __restrict__ bn_var,
                   float* __restrict__ y)                  // [B,256,3136]
{
    const int m0 = blockIdx.x * 256;
    const int n0 = blockIdx.y * 64;
    const int t = threadIdx.x;
    const int lane = t & 63, wv = t >> 6;
    const int mblk = m0 + wv * 64;
    const int fm = lane & 15;
    const int q  = lane >> 4;

    f32x4 acc[4][4];
    const f32x4 zero = {0.0f, 0.0f, 0.0f, 0.0f};
    #pragma unroll
    for (int i = 0; i < 4; ++i)
        #pragma unroll
        for (int j = 0; j < 4; ++j) acc[i][j] = zero;

    const unsigned short *xrh[4], *xrl[4], *wrh[4], *wrl[4];
    #pragma unroll
    for (int mt = 0; mt < 4; ++mt) {
        xrh[mt] = shp + (size_t)(mblk + mt*16 + fm) * CH + q * 8;
        xrl[mt] = slp + (size_t)(mblk + mt*16 + fm) * CH + q * 8;
    }
    #pragma unroll
    for (int nt = 0; nt < 4; ++nt) {
        wrh[nt] = whi + (size_t)(n0 + nt*16 + fm) * CH + q * 8;
        wrl[nt] = wlo + (size_t)(n0 + nt*16 + fm) * CH + q * 8;
    }

    for (int k0 = 0; k0 < CH; k0 += 32) {
        s16x8 wh[4], wl[4], ah[4], al[4];
        #pragma unroll
        for (int nt = 0; nt < 4; ++nt) {
            wh[nt] = *(const s16x8*)(wrh[nt] + k0);
            wl[nt] = *(const s16x8*)(wrl[nt] + k0);
        }
        #pragma unroll
        for (int mt = 0; mt < 4; ++mt) {
            ah[mt] = *(const s16x8*)(xrh[mt] + k0);
            al[mt] = *(const s16x8*)(xrl[mt] + k0);
        }
        #pragma unroll
        for (int nt = 0; nt < 4; ++nt)
            #pragma unroll
            for (int mt = 0; mt < 4; ++mt) {
                acc[nt][mt] = __builtin_amdgcn_mfma_f32_16x16x32_bf16(wh[nt], ah[mt], acc[nt][mt], 0, 0, 0);
                acc[nt][mt] = __builtin_amdgcn_mfma_f32_16x16x32_bf16(wh[nt], al[mt], acc[nt][mt], 0, 0, 0);
                acc[nt][mt] = __builtin_amdgcn_mfma_f32_16x16x32_bf16(wl[nt], ah[mt], acc[nt][mt], 0, 0, 0);
            }
    }

    #pragma unroll
    for (int nt = 0; nt < 4; ++nt) {
        #pragma unroll
        for (int r = 0; r < 4; ++r) {
            const int n = n0 + nt*16 + q*4 + r;
            const float sc = bn_g[n] * rsqrtf(bn_var[n] + 1e-5f);
            const float sb = bn_b[n] - bn_mean[n] * sc;
            const float bs = bias[n];
            #pragma unroll
            for (int mt = 0; mt < 4; ++mt) {
                const int mm = mblk + mt*16;
                const size_t base = (size_t)(mm / HW) * CH * HW + (mm % HW);
                float val = (acc[nt][mt][r] + bs) * sc + sb;
                y[base + (size_t)n * HW + fm] = val / (1.0f + expf(-val));
            }
        }
    }
}

extern "C" void kernel_launch(void* const* d_in, const int* in_sizes, int n_in,
                              void* d_out, int out_size, void* d_ws, size_t ws_size,
                              hipStream_t stream) {
    const float* x      = (const float*)d_in[0];
    const float* w_in   = (const float*)d_in[1];
    const float* b_in   = (const float*)d_in[2];
    const float* dw_w   = (const float*)d_in[3];
    const float* dw_b   = (const float*)d_in[4];
    const float* ln_g   = (const float*)d_in[5];
    const float* ln_b   = (const float*)d_in[6];
    const float* w_off  = (const float*)d_in[7];
    const float* b_off  = (const float*)d_in[8];
    const float* w_mask = (const float*)d_in[9];
    const float* b_mask = (const float*)d_in[10];
    const float* w_out  = (const float*)d_in[11];
    const float* b_out  = (const float*)d_in[12];
    const float* bn_g   = (const float*)d_in[13];
    const float* bn_b   = (const float*)d_in[14];
    const float* bn_mean= (const float*)d_in[15];
    const float* bn_var = (const float*)d_in[16];
    float* out = (float*)d_out;

    const size_t SZ = (size_t)MTOT * CH;                 // elements
    // Layout: v | xt_hi,xt_lo | fh,fl | omb | weights | bcat
    const size_t need_new =
        4 * SZ * sizeof(float)
        + 6 * (size_t)CH * CH * sizeof(unsigned short)
        + CH * sizeof(float);

    if (ws_size >= need_new) {
        // -------- main path --------
        float* ws = (float*)d_ws;
        float* v    = ws;                                          // SZ f32
        unsigned short* xt_hi = (unsigned short*)(v + SZ);         // SZ us
        unsigned short* xt_lo = xt_hi + SZ;                        // SZ us
        unsigned short* fh    = xt_lo + SZ;                        // SZ us
        unsigned short* fl    = fh + SZ;                           // SZ us
        float* omb  = (float*)(fl + SZ);                           // SZ f32
        unsigned short* wt_hi  = (unsigned short*)(omb + SZ);
        unsigned short* wt_lo  = wt_hi + CH * CH;
        unsigned short* wt2_hi = wt_lo + CH * CH;
        unsigned short* wt2_lo = wt2_hi + CH * CH;
        unsigned short* wt3_hi = wt2_lo + CH * CH;
        unsigned short* wt3_lo = wt3_hi + CH * CH;
        float* bcat = (float*)(wt3_lo + CH * CH);                  // 256 f32
        // sh/sl overlay xt region (xt consumed by gemm_in + dw before sample).
        unsigned short* sh = xt_hi;
        unsigned short* sl = xt_lo;

        wt_split_kernel<<<dim3(4, 4), dim3(256), 0, stream>>>(w_out, wt_hi, wt_lo);
        wt_split_kernel<<<dim3(4, 4), dim3(256), 0, stream>>>(w_in, wt3_hi, wt3_lo);
        wt2_split_kernel<<<dim3(16), dim3(256), 0, stream>>>(
            w_off, w_mask, b_off, b_mask, wt2_hi, wt2_lo, bcat);
        xt_split_kernel<<<dim3(HW/64, CH/64, BATCH), dim3(256), 0, stream>>>(x, xt_hi, xt_lo);
        gemm64_f32<<<dim3(MTOT/64), dim3(256), 0, stream>>>(
            xt_hi, xt_lo, wt3_hi, wt3_lo, b_in, v);
        dw_ln_gelu_nhwc_split<<<dim3(MTOT/POSB), dim3(256), 0, stream>>>(
            xt_hi, xt_lo, dw_w, dw_b, ln_g, ln_b, fh, fl);
        gemm64_f32<<<dim3(MTOT/64), dim3(256), 0, stream>>>(
            fh, fl, wt2_hi, wt2_lo, bcat, omb);
        sample_kernel_omb_split<<<dim3(MTOT/POSB), dim3(256), 0, stream>>>(v, omb, sh, sl);
        gemm64_out<<<dim3(MTOT/64), dim3(256), 0, stream>>>(
            sh, sl, wt_hi, wt_lo, b_out, bn_g, bn_b, bn_mean, bn_var, out);
    } else {
        // -------- fallback: round-5 verified path --------
        float* ws = (float*)d_ws;
        float* v    = ws;
        unsigned short* xt_hi = (unsigned short*)(v + SZ);
        unsigned short* xt_lo = xt_hi + SZ;
        unsigned short* fh    = xt_lo + SZ;
        unsigned short* fl    = fh + SZ;
        float* omb  = (float*)(fl + SZ);
        unsigned short* wt_hi  = (unsigned short*)(omb + SZ);
        unsigned short* wt_lo  = wt_hi + CH * CH;
        unsigned short* wt2_hi = wt_lo + CH * CH;
        unsigned short* wt2_lo = wt2_hi + CH * CH;
        unsigned short* wt3_hi = wt2_lo + CH * CH;
        unsigned short* wt3_lo = wt3_hi + CH * CH;
        float* bcat = (float*)(wt3_lo + CH * CH);
        unsigned short* sh = xt_hi;
        unsigned short* sl = xt_lo;

        wt_split_kernel<<<dim3(4, 4), dim3(256), 0, stream>>>(w_out, wt_hi, wt_lo);
        wt_split_kernel<<<dim3(4, 4), dim3(256), 0, stream>>>(w_in, wt3_hi, wt3_lo);
        wt2_split_kernel<<<dim3(16), dim3(256), 0, stream>>>(
            w_off, w_mask, b_off, b_mask, wt2_hi, wt2_lo, bcat);
        xt_split_kernel<<<dim3(HW/64, CH/64, BATCH), dim3(256), 0, stream>>>(x, xt_hi, xt_lo);
        gemm_in_mfma<<<dim3(MTOT/256, CH/64), dim3(256), 0, stream>>>(
            xt_hi, xt_lo, wt3_hi, wt3_lo, b_in, v);
        dw_ln_gelu_nhwc_split<<<dim3(MTOT/POSB), dim3(256), 0, stream>>>(
            xt_hi, xt_lo, dw_w, dw_b, ln_g, ln_b, fh, fl);
        gemm_in_mfma<<<dim3(MTOT/256, CH/64), dim3(256), 0, stream>>>(
            fh, fl, wt2_hi, wt2_lo, bcat, omb);
        sample_kernel_omb_split<<<dim3(MTOT/POSB), dim3(256), 0, stream>>>(v, omb, sh, sl);
        gemm_out_bf16<<<dim3(MTOT/256, CH/64), dim3(256), 0, stream>>>(
            sh, sl, wt_hi, wt_lo, b_out, bn_g, bn_b, bn_mean, bn_var, out);
    }
}

// Round 7
// 285.105 us; speedup vs baseline: 1.1566x; 1.0156x over previous
//
#include <hip/hip_runtime.h>
#include <math.h>

// Problem constants
#define BATCH 8
#define CH    256
#define HDIM  56
#define WDIM  56
#define HW    (HDIM*WDIM)          // 3136
#define MTOT  (BATCH*HW)           // 25088
#define GRP   8
#define GC    32
#define NP    9                    // K*K
#define NOFF  (GRP*NP*2)           // 144
#define NMSK  (GRP*NP)             // 72
#define NTOT  (NOFF+NMSK)          // 216
#define POSB  4                    // positions per sample block
#define NMT   (MTOT/64)            // 392 m-tiles

typedef float f32x4 __attribute__((ext_vector_type(4)));
typedef short s16x8 __attribute__((ext_vector_type(8)));

// split a,b into packed bf16 hi (truncation) and bf16 lo (exact remainder, truncated)
__device__ inline void split2(float a, float b, unsigned int& hp, unsigned int& lp)
{
    const unsigned int ua = __float_as_uint(a), ub = __float_as_uint(b);
    hp = (ub & 0xffff0000u) | (ua >> 16);
    const float ha = __uint_as_float(ua & 0xffff0000u);
    const float hb = __uint_as_float(ub & 0xffff0000u);
    const unsigned int la = __float_as_uint(a - ha), lb = __float_as_uint(b - hb);
    lp = (lb & 0xffff0000u) | (la >> 16);
}

// ---------------------------------------------------------------------------
// Transpose + split x (NCHW) -> xt_hi/xt_lo [m][k] bf16. 64x64 LDS tiles.
// ---------------------------------------------------------------------------
__global__ __launch_bounds__(256)
void xt_split_kernel(const float* __restrict__ x,
                     unsigned short* __restrict__ hi,
                     unsigned short* __restrict__ lo)
{
    __shared__ float lds[64][68];
    const int hw0 = blockIdx.x * 64;       // 49 tiles (3136/64)
    const int k0  = blockIdx.y * 64;       // 4 tiles
    const int b   = blockIdx.z;            // 8
    const int t = threadIdx.x;
    #pragma unroll
    for (int p = 0; p < 4; ++p) {
        const int kr = (t >> 4) + p * 16;
        const int hc = (t & 15) * 4;
        *(float4*)&lds[kr][hc] =
            *(const float4*)(x + ((size_t)b * CH + k0 + kr) * HW + hw0 + hc);
    }
    __syncthreads();
    const int ml = t >> 2;             // m-row 0..63
    const int kc = (t & 3) * 16;       // k base 0,16,32,48
    unsigned int hbuf[8], lbuf[8];
    #pragma unroll
    for (int j = 0; j < 16; j += 2)
        split2(lds[kc + j][ml], lds[kc + j + 1][ml], hbuf[j >> 1], lbuf[j >> 1]);
    const size_t row = (size_t)(b * HW + hw0 + ml) * CH + k0 + kc;
    *(uint4*)&hi[row]     = *(uint4*)&hbuf[0];
    *(uint4*)&hi[row + 8] = *(uint4*)&hbuf[4];
    *(uint4*)&lo[row]     = *(uint4*)&lbuf[0];
    *(uint4*)&lo[row + 8] = *(uint4*)&lbuf[4];
}

// ---------------------------------------------------------------------------
// Shared GEMM block body: 64-row m-tile, 4 waves = 4 n-panels of 64.
// Register double-buffered 8-step k-loop (launch_bounds(256,1) frees enough
// VGPRs for both buffers to actually materialize).
// ---------------------------------------------------------------------------
__device__ __forceinline__ void gemm64_body(
    const unsigned short* __restrict__ ahi,
    const unsigned short* __restrict__ alo,
    const unsigned short* __restrict__ whi,
    const unsigned short* __restrict__ wlo,
    int m0, int n0, int fm, int q, f32x4 (&acc)[4][4])
{
    const unsigned short *pah[4], *pal[4], *pwh[4], *pwl[4];
    #pragma unroll
    for (int mt = 0; mt < 4; ++mt) {
        pah[mt] = ahi + (size_t)(m0 + mt*16 + fm) * CH + q * 8;
        pal[mt] = alo + (size_t)(m0 + mt*16 + fm) * CH + q * 8;
    }
    #pragma unroll
    for (int nt = 0; nt < 4; ++nt) {
        pwh[nt] = whi + (size_t)(n0 + nt*16 + fm) * CH + q * 8;
        pwl[nt] = wlo + (size_t)(n0 + nt*16 + fm) * CH + q * 8;
    }

    s16x8 ah[2][4], al[2][4], wh[2][4], wl[2][4];
    #pragma unroll
    for (int i = 0; i < 4; ++i) {
        ah[0][i] = *(const s16x8*)(pah[i]);
        al[0][i] = *(const s16x8*)(pal[i]);
        wh[0][i] = *(const s16x8*)(pwh[i]);
        wl[0][i] = *(const s16x8*)(pwl[i]);
    }
    #pragma unroll
    for (int kk = 0; kk < 8; ++kk) {
        const int cur = kk & 1, nxt = cur ^ 1;
        if (kk < 7) {
            const int ko = (kk + 1) * 32;
            #pragma unroll
            for (int i = 0; i < 4; ++i) {
                ah[nxt][i] = *(const s16x8*)(pah[i] + ko);
                al[nxt][i] = *(const s16x8*)(pal[i] + ko);
                wh[nxt][i] = *(const s16x8*)(pwh[i] + ko);
                wl[nxt][i] = *(const s16x8*)(pwl[i] + ko);
            }
        }
        #pragma unroll
        for (int nt = 0; nt < 4; ++nt)
            #pragma unroll
            for (int mt = 0; mt < 4; ++mt) {
                acc[nt][mt] = __builtin_amdgcn_mfma_f32_16x16x32_bf16(wh[cur][nt], ah[cur][mt], acc[nt][mt], 0, 0, 0);
                acc[nt][mt] = __builtin_amdgcn_mfma_f32_16x16x32_bf16(wh[cur][nt], al[cur][mt], acc[nt][mt], 0, 0, 0);
                acc[nt][mt] = __builtin_amdgcn_mfma_f32_16x16x32_bf16(wl[cur][nt], ah[cur][mt], acc[nt][mt], 0, 0, 0);
            }
    }
}

// ---------------------------------------------------------------------------
// DUAL GEMM: one dispatch runs BOTH independent middle projections.
// bid<NMT: v = xt @ w_in; bid>=NMT: omb = f @ wt2. Doubles blocks/CU for
// the latency-bound phase. 784%8==0 keeps the per-half XCD swizzle intact.
// ---------------------------------------------------------------------------
__global__ __launch_bounds__(256, 1)
void gemm64_dual(const unsigned short* __restrict__ ahi1,
                 const unsigned short* __restrict__ alo1,
                 const unsigned short* __restrict__ whi1,
                 const unsigned short* __restrict__ wlo1,
                 const float* __restrict__ bias1,
                 float* __restrict__ out1,
                 const unsigned short* __restrict__ ahi2,
                 const unsigned short* __restrict__ alo2,
                 const unsigned short* __restrict__ whi2,
                 const unsigned short* __restrict__ wlo2,
                 const float* __restrict__ bias2,
                 float* __restrict__ out2)
{
    const int half = blockIdx.x >= NMT;
    const int lbid = blockIdx.x - (half ? NMT : 0);
    const unsigned short* ahi = half ? ahi2 : ahi1;
    const unsigned short* alo = half ? alo2 : alo1;
    const unsigned short* whi = half ? whi2 : whi1;
    const unsigned short* wlo = half ? wlo2 : wlo1;
    const float* bias = half ? bias2 : bias1;
    float* out = half ? out2 : out1;

    const int sw  = (lbid & 7) * (NMT / 8) + (lbid >> 3);
    const int m0  = sw * 64;
    const int t = threadIdx.x;
    const int lane = t & 63, wv = t >> 6;
    const int n0 = wv * 64;
    const int fm = lane & 15, q = lane >> 4;

    f32x4 acc[4][4];
    const f32x4 zero = {0.0f, 0.0f, 0.0f, 0.0f};
    #pragma unroll
    for (int i = 0; i < 4; ++i)
        #pragma unroll
        for (int j = 0; j < 4; ++j) acc[i][j] = zero;

    gemm64_body(ahi, alo, whi, wlo, m0, n0, fm, q, acc);

    #pragma unroll
    for (int nt = 0; nt < 4; ++nt) {
        const float4 b4 = *(const float4*)&bias[n0 + nt*16 + q*4];
        #pragma unroll
        for (int mt = 0; mt < 4; ++mt) {
            f32x4 o = acc[nt][mt];
            o[0] += b4.x; o[1] += b4.y; o[2] += b4.z; o[3] += b4.w;
            *(f32x4*)&out[(size_t)(m0 + mt*16 + fm) * CH + n0 + nt*16 + q*4] = o;
        }
    }
}

// ---------------------------------------------------------------------------
// Output GEMM: same skeleton, BN+SiLU NCHW epilogue.
// ---------------------------------------------------------------------------
__global__ __launch_bounds__(256, 1)
void gemm64_out(const unsigned short* __restrict__ ahi,
                const unsigned short* __restrict__ alo,
                const unsigned short* __restrict__ whi,
                const unsigned short* __restrict__ wlo,
                const float* __restrict__ bias,
                const float* __restrict__ bn_g,
                const float* __restrict__ bn_b,
                const float* __restrict__ bn_mean,
                const float* __restrict__ bn_var,
                float* __restrict__ y)                  // [B,256,3136]
{
    const int bid = blockIdx.x;
    const int sw  = (bid & 7) * (NMT / 8) + (bid >> 3);
    const int m0  = sw * 64;
    const int t = threadIdx.x;
    const int lane = t & 63, wv = t >> 6;
    const int n0 = wv * 64;
    const int fm = lane & 15, q = lane >> 4;

    f32x4 acc[4][4];
    const f32x4 zero = {0.0f, 0.0f, 0.0f, 0.0f};
    #pragma unroll
    for (int i = 0; i < 4; ++i)
        #pragma unroll
        for (int j = 0; j < 4; ++j) acc[i][j] = zero;

    gemm64_body(ahi, alo, whi, wlo, m0, n0, fm, q, acc);

    const size_t base = (size_t)(m0 / HW) * CH * HW + (m0 % HW);
    #pragma unroll
    for (int nt = 0; nt < 4; ++nt) {
        #pragma unroll
        for (int r = 0; r < 4; ++r) {
            const int n = n0 + nt*16 + q*4 + r;
            const float sc = bn_g[n] * rsqrtf(bn_var[n] + 1e-5f);
            const float sb = bn_b[n] - bn_mean[n] * sc;
            const float bs = bias[n];
            #pragma unroll
            for (int mt = 0; mt < 4; ++mt) {
                float val = (acc[nt][mt][r] + bs) * sc + sb;
                y[base + (size_t)n * HW + mt*16 + fm] = val / (1.0f + expf(-val));
            }
        }
    }
}

// ---------------------------------------------------------------------------
// Fallback GEMM (proven round-4 structure): 256m x 64n blocks, grid (98,4).
// ---------------------------------------------------------------------------
__global__ __launch_bounds__(256)
void gemm_in_mfma(const unsigned short* __restrict__ xhi, // [m][k]
                  const unsigned short* __restrict__ xlo,
                  const unsigned short* __restrict__ whi, // [n][k]
                  const unsigned short* __restrict__ wlo,
                  const float* __restrict__ bias,
                  float* __restrict__ v)                  // [MTOT,256]
{
    const int m0 = blockIdx.x * 256;
    const int n0 = blockIdx.y * 64;
    const int t = threadIdx.x;
    const int lane = t & 63, wv = t >> 6;
    const int mblk = m0 + wv * 64;
    const int fm = lane & 15;
    const int q  = lane >> 4;

    f32x4 acc[4][4];              // [nt][mt]
    const f32x4 zero = {0.0f, 0.0f, 0.0f, 0.0f};
    #pragma unroll
    for (int i = 0; i < 4; ++i)
        #pragma unroll
        for (int j = 0; j < 4; ++j) acc[i][j] = zero;

    const unsigned short *xrh[4], *xrl[4], *wrh[4], *wrl[4];
    #pragma unroll
    for (int mt = 0; mt < 4; ++mt) {
        xrh[mt] = xhi + (size_t)(mblk + mt*16 + fm) * CH + q * 8;
        xrl[mt] = xlo + (size_t)(mblk + mt*16 + fm) * CH + q * 8;
    }
    #pragma unroll
    for (int nt = 0; nt < 4; ++nt) {
        wrh[nt] = whi + (size_t)(n0 + nt*16 + fm) * CH + q * 8;
        wrl[nt] = wlo + (size_t)(n0 + nt*16 + fm) * CH + q * 8;
    }

    for (int k0 = 0; k0 < CH; k0 += 32) {
        s16x8 wh[4], wl[4], ah[4], al[4];
        #pragma unroll
        for (int nt = 0; nt < 4; ++nt) {
            wh[nt] = *(const s16x8*)(wrh[nt] + k0);
            wl[nt] = *(const s16x8*)(wrl[nt] + k0);
        }
        #pragma unroll
        for (int mt = 0; mt < 4; ++mt) {
            ah[mt] = *(const s16x8*)(xrh[mt] + k0);
            al[mt] = *(const s16x8*)(xrl[mt] + k0);
        }
        #pragma unroll
        for (int nt = 0; nt < 4; ++nt)
            #pragma unroll
            for (int mt = 0; mt < 4; ++mt) {
                acc[nt][mt] = __builtin_amdgcn_mfma_f32_16x16x32_bf16(wh[nt], ah[mt], acc[nt][mt], 0, 0, 0);
                acc[nt][mt] = __builtin_amdgcn_mfma_f32_16x16x32_bf16(wh[nt], al[mt], acc[nt][mt], 0, 0, 0);
                acc[nt][mt] = __builtin_amdgcn_mfma_f32_16x16x32_bf16(wl[nt], ah[mt], acc[nt][mt], 0, 0, 0);
            }
    }

    #pragma unroll
    for (int nt = 0; nt < 4; ++nt) {
        const float4 b4 = *(const float4*)&bias[n0 + nt*16 + q*4];
        #pragma unroll
        for (int mt = 0; mt < 4; ++mt) {
            f32x4 o = acc[nt][mt];
            o[0] += b4.x; o[1] += b4.y; o[2] += b4.z; o[3] += b4.w;
            *(f32x4*)&v[(size_t)(mblk + mt*16 + fm) * CH + n0 + nt*16 + q*4] = o;
        }
    }
}

// ---------------------------------------------------------------------------
// Per-position-wave depthwise 3x3 + bias + LN + GELU from NHWC bf16 hi/lo xt,
// output stored PRE-SPLIT as bf16 hi/lo. One wave per position.
// ---------------------------------------------------------------------------
__global__ __launch_bounds__(256)
void dw_ln_gelu_nhwc_split(const unsigned short* __restrict__ xhi,
                           const unsigned short* __restrict__ xlo,
                           const float* __restrict__ dw_w,   // [256][9]
                           const float* __restrict__ dw_b,
                           const float* __restrict__ ln_g,
                           const float* __restrict__ ln_b,
                           unsigned short* __restrict__ fh,  // [MTOT][256]
                           unsigned short* __restrict__ fl)  // [MTOT][256]
{
    __shared__ float wt[NP][CH];                       // transposed dw weights
    __shared__ float lbias[CH], lgam[CH], lbet[CH];

    const int t = threadIdx.x;
    {
        const float* wp = dw_w + t * NP;
        #pragma unroll
        for (int p = 0; p < NP; ++p) wt[p][t] = wp[p];
        lbias[t] = dw_b[t]; lgam[t] = ln_g[t]; lbet[t] = ln_b[t];
    }
    __syncthreads();

    const int nblk = MTOT / POSB;          // 6272
    const int per  = nblk / 8;             // 784
    const int bid  = blockIdx.x;
    const int sw   = (bid & 7) * per + (bid >> 3);
    const int q    = t >> 6, lane = t & 63;
    const int n    = sw * POSB + q;
    const int b    = n / HW;
    const int hw   = n % HW;
    const int h    = hw / WDIM, w = hw % WDIM;
    const int c4   = lane * 4;
    const size_t base = (size_t)b * HW * CH + c4;

    float ax = 0.0f, ay = 0.0f, az = 0.0f, aw = 0.0f;
    #pragma unroll
    for (int p = 0; p < NP; ++p) {
        const int hh = h + p / 3 - 1;
        const int ww = w + p % 3 - 1;
        if ((unsigned)hh >= (unsigned)HDIM || (unsigned)ww >= (unsigned)WDIM)
            continue;                       // wave-uniform branch (h,w per-wave)
        const size_t idx = base + (size_t)(hh * WDIM + ww) * CH;
        const ushort4 uh = *(const ushort4*)(xhi + idx);
        const ushort4 ul = *(const ushort4*)(xlo + idx);
        const float4 wv = *(const float4*)&wt[p][c4];
        ax = fmaf(__uint_as_float((unsigned)uh.x << 16), wv.x,
             fmaf(__uint_as_float((unsigned)ul.x << 16), wv.x, ax));
        ay = fmaf(__uint_as_float((unsigned)uh.y << 16), wv.y,
             fmaf(__uint_as_float((unsigned)ul.y << 16), wv.y, ay));
        az = fmaf(__uint_as_float((unsigned)uh.z << 16), wv.z,
             fmaf(__uint_as_float((unsigned)ul.z << 16), wv.z, az));
        aw = fmaf(__uint_as_float((unsigned)uh.w << 16), wv.w,
             fmaf(__uint_as_float((unsigned)ul.w << 16), wv.w, aw));
    }
    {
        const float4 b4 = *(const float4*)&lbias[c4];
        ax += b4.x; ay += b4.y; az += b4.z; aw += b4.w;
    }

    // LayerNorm over the wave's 256 channel values: in-wave butterfly.
    float s1 = ax + ay + az + aw;
    float s2 = ax*ax + ay*ay + az*az + aw*aw;
    #pragma unroll
    for (int off = 32; off > 0; off >>= 1) {
        s1 += __shfl_xor(s1, off);
        s2 += __shfl_xor(s2, off);
    }
    const float mean = s1 * (1.0f / 256.0f);
    const float rstd = rsqrtf(s2 * (1.0f / 256.0f) - mean * mean + 1e-5f);

    const float4 g4 = *(const float4*)&lgam[c4];
    const float4 e4 = *(const float4*)&lbet[c4];
    const float x0 = (ax - mean) * rstd * g4.x + e4.x;
    const float x1 = (ay - mean) * rstd * g4.y + e4.y;
    const float x2 = (az - mean) * rstd * g4.z + e4.z;
    const float x3 = (aw - mean) * rstd * g4.w + e4.w;
    const float o0 = 0.5f * x0 * (1.0f + erff(x0 * 0.70710678118654752f));
    const float o1 = 0.5f * x1 * (1.0f + erff(x1 * 0.70710678118654752f));
    const float o2 = 0.5f * x2 * (1.0f + erff(x2 * 0.70710678118654752f));
    const float o3 = 0.5f * x3 * (1.0f + erff(x3 * 0.70710678118654752f));

    unsigned int hp0, lp0, hp1, lp1;
    split2(o0, o1, hp0, lp0);
    split2(o2, o3, hp1, lp1);
    *(uint2*)&fh[(size_t)n * CH + c4] = make_uint2(hp0, hp1);
    *(uint2*)&fl[(size_t)n * CH + c4] = make_uint2(lp0, lp1);
}

// ---------------------------------------------------------------------------
// Transpose + hi/lo bf16 split of a [256k][256n] fp32 weight -> [n][k] bf16.
// ---------------------------------------------------------------------------
__global__ __launch_bounds__(256)
void wt_split_kernel(const float* __restrict__ w,
                     unsigned short* __restrict__ hi,
                     unsigned short* __restrict__ lo)
{
    __shared__ float lds[64][68];
    const int kt = blockIdx.x * 64, nt = blockIdx.y * 64;
    const int t = threadIdx.x;
    #pragma unroll
    for (int p = 0; p < 4; ++p) {
        const int kr = (t >> 4) + p * 16, nc = (t & 15) * 4;
        *(float4*)&lds[kr][nc] = *(const float4*)(w + (size_t)(kt + kr) * CH + nt + nc);
    }
    __syncthreads();
    const int nl = t >> 2, kc = (t & 3) * 16;
    #pragma unroll
    for (int j = 0; j < 16; j += 2) {
        const float f0 = lds[kc + j][nl], f1 = lds[kc + j + 1][nl];
        unsigned int hp, lp;
        split2(f0, f1, hp, lp);
        *(unsigned int*)&hi[(size_t)(nt + nl) * CH + kt + kc + j] = hp;
        *(unsigned int*)&lo[(size_t)(nt + nl) * CH + kt + kc + j] = lp;
    }
}

// ---------------------------------------------------------------------------
// Transpose + split of [w_off | w_mask] -> wt2_hi/lo [256 n_pad][256 k] bf16.
// Also builds bcat[256] = [b_off | b_mask | 0] (block 0 only).
// ---------------------------------------------------------------------------
__global__ __launch_bounds__(256)
void wt2_split_kernel(const float* __restrict__ w_off,   // [256][144]
                      const float* __restrict__ w_mask,  // [256][72]
                      const float* __restrict__ b_off,
                      const float* __restrict__ b_mask,
                      unsigned short* __restrict__ hi,
                      unsigned short* __restrict__ lo,
                      float* __restrict__ bcat)          // [256]
{
    const int n = threadIdx.x;
    if (blockIdx.x == 0) {
        bcat[n] = (n < NOFF) ? b_off[n] : ((n < NTOT) ? b_mask[n - NOFF] : 0.0f);
    }
    const int k0 = blockIdx.x * 16;
    #pragma unroll
    for (int j = 0; j < 16; j += 2) {
        const int k = k0 + j;
        float f0 = 0.0f, f1 = 0.0f;
        if (n < NOFF) {
            f0 = w_off[(size_t)k * NOFF + n];
            f1 = w_off[(size_t)(k + 1) * NOFF + n];
        } else if (n < NTOT) {
            f0 = w_mask[(size_t)k * NMSK + (n - NOFF)];
            f1 = w_mask[(size_t)(k + 1) * NMSK + (n - NOFF)];
        }
        unsigned int hp, lp;
        split2(f0, f1, hp, lp);
        *(unsigned int*)&hi[(size_t)n * CH + k] = hp;
        *(unsigned int*)&lo[(size_t)n * CH + k] = lp;
    }
}

// ---------------------------------------------------------------------------
// Deformable sampling reading the padded omb [MTOT][256] rows
// (cols 0..143 offsets, 144..215 mask logits). Output s PRE-SPLIT bf16 hi/lo.
// ---------------------------------------------------------------------------
__global__ __launch_bounds__(256)
void sample_kernel_omb_split(const float* __restrict__ v,
                             const float* __restrict__ omb,
                             unsigned short* __restrict__ sh,  // [MTOT][256]
                             unsigned short* __restrict__ sl)  // [MTOT][256]
{
    __shared__ alignas(16) float loff[POSB][NOFF];
    __shared__ alignas(16) float lmsk[POSB][NMSK];
    __shared__ alignas(16) float wtab[POSB][GRP*NP][4];
    __shared__ alignas(16) int   itab[POSB][GRP*NP][4];

    const int nblk = MTOT / POSB;            // 6272
    const int per  = nblk / 8;               // 784
    const int bid  = blockIdx.x;
    const int sw   = (bid % 8) * per + (bid / 8);
    const int n0 = sw * POSB;
    const int t = threadIdx.x;

    if (t < POSB * (NOFF/4)) {
        const int q = t / (NOFF/4), r = t % (NOFF/4);
        *(float4*)&loff[q][r*4] = *(const float4*)&omb[(size_t)(n0+q)*CH + r*4];
    } else if (t < POSB * (NOFF/4) + POSB * (NMSK/4)) {
        const int u = t - POSB * (NOFF/4);
        const int q = u / (NMSK/4), r = u % (NMSK/4);
        *(float4*)&lmsk[q][r*4] = *(const float4*)&omb[(size_t)(n0+q)*CH + NOFF + r*4];
    }
    __syncthreads();

    if (t < POSB * GRP) {
        const int q = t >> 3, g = t & 7;
        float* mm = &lmsk[q][g * NP];
        float mx = -1e30f;
        #pragma unroll
        for (int p = 0; p < NP; ++p) mx = fmaxf(mx, mm[p]);
        float sum = 0.0f;
        #pragma unroll
        for (int p = 0; p < NP; ++p) { const float e = __expf(mm[p] - mx); mm[p] = e; sum += e; }
        const float inv = 1.0f / sum;
        #pragma unroll
        for (int p = 0; p < NP; ++p) mm[p] *= inv;
    }
    __syncthreads();

    for (int u = t; u < POSB * GRP * NP; u += 256) {
        const int q = u / (GRP*NP), j = u % (GRP*NP);
        const int g = j / NP, p = j % NP;
        const int n = n0 + q;
        const int hw = n % HW;
        const int h = hw / WDIM, w = hw % WDIM;
        const float ox = loff[q][g*18 + p*2 + 0];
        const float oy = loff[q][g*18 + p*2 + 1];
        const float m  = lmsk[q][g*NP + p];
        const float px = (float)(w + p/3) + ox;
        const float py = (float)(h + p%3) + oy;
        const float fx = floorf(px), fy = floorf(py);
        const float wx = px - fx, wy = py - fy;
        const int x0 = (int)fx, y0 = (int)fy;
        const int x1 = x0 + 1, y1 = y0 + 1;
        const float vx0 = (x0 >= 1 && x0 < 57) ? 1.0f : 0.0f;
        const float vx1 = (x1 >= 1 && x1 < 57) ? 1.0f : 0.0f;
        const float vy0 = (y0 >= 1 && y0 < 57) ? 1.0f : 0.0f;
        const float vy1 = (y1 >= 1 && y1 < 57) ? 1.0f : 0.0f;
        const int x0c = min(max(x0, 1), 56), x1c = min(max(x1, 1), 56);
        const int y0c = min(max(y0, 1), 56), y1c = min(max(y1, 1), 56);
        wtab[q][j][0] = m * (1.0f-wx) * (1.0f-wy) * vx0 * vy0;
        wtab[q][j][1] = m * wx        * (1.0f-wy) * vx1 * vy0;
        wtab[q][j][2] = m * (1.0f-wx) * wy        * vx0 * vy1;
        wtab[q][j][3] = m * wx        * wy        * vx1 * vy1;
        itab[q][j][0] = ((y0c-1)*WDIM + (x0c-1)) * CH;
        itab[q][j][1] = ((y0c-1)*WDIM + (x1c-1)) * CH;
        itab[q][j][2] = ((y1c-1)*WDIM + (x0c-1)) * CH;
        itab[q][j][3] = ((y1c-1)*WDIM + (x1c-1)) * CH;
    }
    __syncthreads();

    const int q = t >> 6, lane = t & 63;
    const int n = n0 + q;
    const int b = n / HW;
    const int g = lane >> 3;
    const float* vb = v + (size_t)b*HW*CH + lane*4;
    float4 acc = {0.0f, 0.0f, 0.0f, 0.0f};
    #pragma unroll
    for (int p = 0; p < NP; ++p) {
        const int j = g*NP + p;
        const float4 wv = *(const float4*)&wtab[q][j][0];
        const int4  iv = *(const int4*)&itab[q][j][0];
        const float4 c0 = *(const float4*)(vb + iv.x);
        const float4 c1 = *(const float4*)(vb + iv.y);
        const float4 c2 = *(const float4*)(vb + iv.z);
        const float4 c3 = *(const float4*)(vb + iv.w);
        acc.x += wv.x*c0.x + wv.y*c1.x + wv.z*c2.x + wv.w*c3.x;
        acc.y += wv.x*c0.y + wv.y*c1.y + wv.z*c2.y + wv.w*c3.y;
        acc.z += wv.x*c0.z + wv.y*c1.z + wv.z*c2.z + wv.w*c3.z;
        acc.w += wv.x*c0.w + wv.y*c1.w + wv.z*c2.w + wv.w*c3.w;
    }
    unsigned int hp0, lp0, hp1, lp1;
    split2(acc.x, acc.y, hp0, lp0);
    split2(acc.z, acc.w, hp1, lp1);
    *(uint2*)&sh[(size_t)n*CH + lane*4] = make_uint2(hp0, hp1);
    *(uint2*)&sl[(size_t)n*CH + lane*4] = make_uint2(lp0, lp1);
}

// ---------------------------------------------------------------------------
// Fallback GEMM out from PRE-SPLIT bf16 A (round-5 structure, grid (98,4)).
// ---------------------------------------------------------------------------
__global__ __launch_bounds__(256)
void gemm_out_bf16(const unsigned short* __restrict__ shp, // [m][k] bf16 hi
                   const unsigned short* __restrict__ slp, // [m][k] bf16 lo
                   const unsigned short* __restrict__ whi, // [256 n][256 k]
                   const unsigned short* __restrict__ wlo,
                   const float* __restrict__ bias,
                   const float* __restrict__ bn_g,
                   const float* __restrict__ bn_b,
                   const float* __restrict__ bn_mean,
                   const float* __restrict__ bn_var,
                   float* __restrict__ y)                  // [B,256,3136]
{
    const int m0 = blockIdx.x * 256;
    const int n0 = blockIdx.y * 64;
    const int t = threadIdx.x;
    const int lane = t & 63, wv = t >> 6;
    const int mblk = m0 + wv * 64;
    const int fm = lane & 15;
    const int q  = lane >> 4;

    f32x4 acc[4][4];
    const f32x4 zero = {0.0f, 0.0f, 0.0f, 0.0f};
    #pragma unroll
    for (int i = 0; i < 4; ++i)
        #pragma unroll
        for (int j = 0; j < 4; ++j) acc[i][j] = zero;

    const unsigned short *xrh[4], *xrl[4], *wrh[4], *wrl[4];
    #pragma unroll
    for (int mt = 0; mt < 4; ++mt) {
        xrh[mt] = shp + (size_t)(mblk + mt*16 + fm) * CH + q * 8;
        xrl[mt] = slp + (size_t)(mblk + mt*16 + fm) * CH + q * 8;
    }
    #pragma unroll
    for (int nt = 0; nt < 4; ++nt) {
        wrh[nt] = whi + (size_t)(n0 + nt*16 + fm) * CH + q * 8;
        wrl[nt] = wlo + (size_t)(n0 + nt*16 + fm) * CH + q * 8;
    }

    for (int k0 = 0; k0 < CH; k0 += 32) {
        s16x8 wh[4], wl[4], ah[4], al[4];
        #pragma unroll
        for (int nt = 0; nt < 4; ++nt) {
            wh[nt] = *(const s16x8*)(wrh[nt] + k0);
            wl[nt] = *(const s16x8*)(wrl[nt] + k0);
        }
        #pragma unroll
        for (int mt = 0; mt < 4; ++mt) {
            ah[mt] = *(const s16x8*)(xrh[mt] + k0);
            al[mt] = *(const s16x8*)(xrl[mt] + k0);
        }
        #pragma unroll
        for (int nt = 0; nt < 4; ++nt)
            #pragma unroll
            for (int mt = 0; mt < 4; ++mt) {
                acc[nt][mt] = __builtin_amdgcn_mfma_f32_16x16x32_bf16(wh[nt], ah[mt], acc[nt][mt], 0, 0, 0);
                acc[nt][mt] = __builtin_amdgcn_mfma_f32_16x16x32_bf16(wh[nt], al[mt], acc[nt][mt], 0, 0, 0);
                acc[nt][mt] = __builtin_amdgcn_mfma_f32_16x16x32_bf16(wl[nt], ah[mt], acc[nt][mt], 0, 0, 0);
            }
    }

    #pragma unroll
    for (int nt = 0; nt < 4; ++nt) {
        #pragma unroll
        for (int r = 0; r < 4; ++r) {
            const int n = n0 + nt*16 + q*4 + r;
            const float sc = bn_g[n] * rsqrtf(bn_var[n] + 1e-5f);
            const float sb = bn_b[n] - bn_mean[n] * sc;
            const float bs = bias[n];
            #pragma unroll
            for (int mt = 0; mt < 4; ++mt) {
                const int mm = mblk + mt*16;
                const size_t base = (size_t)(mm / HW) * CH * HW + (mm % HW);
                float val = (acc[nt][mt][r] + bs) * sc + sb;
                y[base + (size_t)n * HW + fm] = val / (1.0f + expf(-val));
            }
        }
    }
}

extern "C" void kernel_launch(void* const* d_in, const int* in_sizes, int n_in,
                              void* d_out, int out_size, void* d_ws, size_t ws_size,
                              hipStream_t stream) {
    const float* x      = (const float*)d_in[0];
    const float* w_in   = (const float*)d_in[1];
    const float* b_in   = (const float*)d_in[2];
    const float* dw_w   = (const float*)d_in[3];
    const float* dw_b   = (const float*)d_in[4];
    const float* ln_g   = (const float*)d_in[5];
    const float* ln_b   = (const float*)d_in[6];
    const float* w_off  = (const float*)d_in[7];
    const float* b_off  = (const float*)d_in[8];
    const float* w_mask = (const float*)d_in[9];
    const float* b_mask = (const float*)d_in[10];
    const float* w_out  = (const float*)d_in[11];
    const float* b_out  = (const float*)d_in[12];
    const float* bn_g   = (const float*)d_in[13];
    const float* bn_b   = (const float*)d_in[14];
    const float* bn_mean= (const float*)d_in[15];
    const float* bn_var = (const float*)d_in[16];
    float* out = (float*)d_out;

    const size_t SZ = (size_t)MTOT * CH;                 // elements
    // Layout: v | xt_hi,xt_lo | fh,fl | omb | weights | bcat
    const size_t need_new =
        4 * SZ * sizeof(float)
        + 6 * (size_t)CH * CH * sizeof(unsigned short)
        + CH * sizeof(float);

    if (ws_size >= need_new) {
        // -------- main path --------
        float* ws = (float*)d_ws;
        float* v    = ws;                                          // SZ f32
        unsigned short* xt_hi = (unsigned short*)(v + SZ);         // SZ us
        unsigned short* xt_lo = xt_hi + SZ;                        // SZ us
        unsigned short* fh    = xt_lo + SZ;                        // SZ us
        unsigned short* fl    = fh + SZ;                           // SZ us
        float* omb  = (float*)(fl + SZ);                           // SZ f32
        unsigned short* wt_hi  = (unsigned short*)(omb + SZ);
        unsigned short* wt_lo  = wt_hi + CH * CH;
        unsigned short* wt2_hi = wt_lo + CH * CH;
        unsigned short* wt2_lo = wt2_hi + CH * CH;
        unsigned short* wt3_hi = wt2_lo + CH * CH;
        unsigned short* wt3_lo = wt3_hi + CH * CH;
        float* bcat = (float*)(wt3_lo + CH * CH);                  // 256 f32
        // sh/sl overlay xt region (xt consumed by dual GEMM + dw beforehand).
        unsigned short* sh = xt_hi;
        unsigned short* sl = xt_lo;

        wt_split_kernel<<<dim3(4, 4), dim3(256), 0, stream>>>(w_out, wt_hi, wt_lo);
        wt_split_kernel<<<dim3(4, 4), dim3(256), 0, stream>>>(w_in, wt3_hi, wt3_lo);
        wt2_split_kernel<<<dim3(16), dim3(256), 0, stream>>>(
            w_off, w_mask, b_off, b_mask, wt2_hi, wt2_lo, bcat);
        xt_split_kernel<<<dim3(HW/64, CH/64, BATCH), dim3(256), 0, stream>>>(x, xt_hi, xt_lo);
        dw_ln_gelu_nhwc_split<<<dim3(MTOT/POSB), dim3(256), 0, stream>>>(
            xt_hi, xt_lo, dw_w, dw_b, ln_g, ln_b, fh, fl);
        // Both middle projections in ONE dispatch (independent of each other):
        gemm64_dual<<<dim3(2 * NMT), dim3(256), 0, stream>>>(
            xt_hi, xt_lo, wt3_hi, wt3_lo, b_in, v,
            fh, fl, wt2_hi, wt2_lo, bcat, omb);
        sample_kernel_omb_split<<<dim3(MTOT/POSB), dim3(256), 0, stream>>>(v, omb, sh, sl);
        gemm64_out<<<dim3(NMT), dim3(256), 0, stream>>>(
            sh, sl, wt_hi, wt_lo, b_out, bn_g, bn_b, bn_mean, bn_var, out);
    } else {
        // -------- fallback: round-5 verified path --------
        float* ws = (float*)d_ws;
        float* v    = ws;
        unsigned short* xt_hi = (unsigned short*)(v + SZ);
        unsigned short* xt_lo = xt_hi + SZ;
        unsigned short* fh    = xt_lo + SZ;
        unsigned short* fl    = fh + SZ;
        float* omb  = (float*)(fl + SZ);
        unsigned short* wt_hi  = (unsigned short*)(omb + SZ);
        unsigned short* wt_lo  = wt_hi + CH * CH;
        unsigned short* wt2_hi = wt_lo + CH * CH;
        unsigned short* wt2_lo = wt2_hi + CH * CH;
        unsigned short* wt3_hi = wt2_lo + CH * CH;
        unsigned short* wt3_lo = wt3_hi + CH * CH;
        float* bcat = (float*)(wt3_lo + CH * CH);
        unsigned short* sh = xt_hi;
        unsigned short* sl = xt_lo;

        wt_split_kernel<<<dim3(4, 4), dim3(256), 0, stream>>>(w_out, wt_hi, wt_lo);
        wt_split_kernel<<<dim3(4, 4), dim3(256), 0, stream>>>(w_in, wt3_hi, wt3_lo);
        wt2_split_kernel<<<dim3(16), dim3(256), 0, stream>>>(
            w_off, w_mask, b_off, b_mask, wt2_hi, wt2_lo, bcat);
        xt_split_kernel<<<dim3(HW/64, CH/64, BATCH), dim3(256), 0, stream>>>(x, xt_hi, xt_lo);
        gemm_in_mfma<<<dim3(MTOT/256, CH/64), dim3(256), 0, stream>>>(
            xt_hi, xt_lo, wt3_hi, wt3_lo, b_in, v);
        dw_ln_gelu_nhwc_split<<<dim3(MTOT/POSB), dim3(256), 0, stream>>>(
            xt_hi, xt_lo, dw_w, dw_b, ln_g, ln_b, fh, fl);
        gemm_in_mfma<<<dim3(MTOT/256, CH/64), dim3(256), 0, stream>>>(
            fh, fl, wt2_hi, wt2_lo, bcat, omb);
        sample_kernel_omb_split<<<dim3(MTOT/POSB), dim3(256), 0, stream>>>(v, omb, sh, sl);
        gemm_out_bf16<<<dim3(MTOT/256, CH/64), dim3(256), 0, stream>>>(
            sh, sl, wt_hi, wt_lo, b_out, bn_g, bn_b, bn_mean, bn_var, out);
    }
}

// Round 8
// 232.474 us; speedup vs baseline: 1.4184x; 1.2264x over previous
//
#include <hip/hip_runtime.h>
#include <math.h>

// Problem constants
#define BATCH 8
#define CH    256
#define HDIM  56
#define WDIM  56
#define HW    (HDIM*WDIM)          // 3136
#define MTOT  (BATCH*HW)           // 25088
#define GRP   8
#define GC    32
#define NP    9                    // K*K
#define NOFF  (GRP*NP*2)           // 144
#define NMSK  (GRP*NP)             // 72
#define NTOT  (NOFF+NMSK)          // 216
#define POSB  4                    // positions per sample block
#define NBLK128 ((MTOT/128)*2)     // 392: 196 m-tiles x 2 n-tiles

typedef float f32x4 __attribute__((ext_vector_type(4)));
typedef short s16x8 __attribute__((ext_vector_type(8)));

// split a,b into packed bf16 hi (truncation) and bf16 lo (exact remainder, truncated)
__device__ inline void split2(float a, float b, unsigned int& hp, unsigned int& lp)
{
    const unsigned int ua = __float_as_uint(a), ub = __float_as_uint(b);
    hp = (ub & 0xffff0000u) | (ua >> 16);
    const float ha = __uint_as_float(ua & 0xffff0000u);
    const float hb = __uint_as_float(ub & 0xffff0000u);
    const unsigned int la = __float_as_uint(a - ha), lb = __float_as_uint(b - hb);
    lp = (lb & 0xffff0000u) | (la >> 16);
}

// async global(16B/lane) -> LDS (wave-uniform base + lane*16)
__device__ __forceinline__ void gld_lds16(const unsigned short* g, unsigned short* l)
{
    __builtin_amdgcn_global_load_lds(
        (const __attribute__((address_space(1))) unsigned int*)g,
        (__attribute__((address_space(3))) unsigned int*)l, 16, 0, 0);
}

// ---------------------------------------------------------------------------
// Transpose + split x (NCHW) -> xt_hi/xt_lo [m][k] bf16. 64x64 LDS tiles.
// ---------------------------------------------------------------------------
__global__ __launch_bounds__(256)
void xt_split_kernel(const float* __restrict__ x,
                     unsigned short* __restrict__ hi,
                     unsigned short* __restrict__ lo)
{
    __shared__ float lds[64][68];
    const int hw0 = blockIdx.x * 64;       // 49 tiles (3136/64)
    const int k0  = blockIdx.y * 64;       // 4 tiles
    const int b   = blockIdx.z;            // 8
    const int t = threadIdx.x;
    #pragma unroll
    for (int p = 0; p < 4; ++p) {
        const int kr = (t >> 4) + p * 16;
        const int hc = (t & 15) * 4;
        *(float4*)&lds[kr][hc] =
            *(const float4*)(x + ((size_t)b * CH + k0 + kr) * HW + hw0 + hc);
    }
    __syncthreads();
    const int ml = t >> 2;             // m-row 0..63
    const int kc = (t & 3) * 16;       // k base 0,16,32,48
    unsigned int hbuf[8], lbuf[8];
    #pragma unroll
    for (int j = 0; j < 16; j += 2)
        split2(lds[kc + j][ml], lds[kc + j + 1][ml], hbuf[j >> 1], lbuf[j >> 1]);
    const size_t row = (size_t)(b * HW + hw0 + ml) * CH + k0 + kc;
    *(uint4*)&hi[row]     = *(uint4*)&hbuf[0];
    *(uint4*)&hi[row + 8] = *(uint4*)&hbuf[4];
    *(uint4*)&lo[row]     = *(uint4*)&lbuf[0];
    *(uint4*)&lo[row + 8] = *(uint4*)&lbuf[4];
}

// ---------------------------------------------------------------------------
// m97-style GEMM body: 128x128 tile, 4 waves (2m x 2n quadrants), BK=32,
// single-buffered LDS, 2-barrier k-loop, global_load_lds width-16 staging.
// Slot swizzle (slot ^= (row>>1)&3) applied on BOTH sides: pre-swizzled
// global source (gload_lds writes linearly) + swizzled ds_read -> 2-way
// banks (free). MFMA order identical to the register version (bit-identical).
// ---------------------------------------------------------------------------
__device__ __forceinline__ void gemm128_body(
    const unsigned short* __restrict__ ahi,
    const unsigned short* __restrict__ alo,
    const unsigned short* __restrict__ whi,
    const unsigned short* __restrict__ wlo,
    unsigned short* sAh, unsigned short* sAl,
    unsigned short* sBh, unsigned short* sBl,
    int m0, int n0g, int t, f32x4 (&acc)[4][4])
{
    const int lane = t & 63, wv4 = t >> 6;
    const int wm = wv4 & 1, wn = wv4 >> 1;
    const int fm = lane & 15, q = lane >> 4;

    // staging decomposition (per issue i: 256 thr x 16B = 64 rows)
    int srow[2], sgs[2], slb[2];
    #pragma unroll
    for (int i = 0; i < 2; ++i) {
        const int u = i * 256 + t;
        srow[i] = u >> 2;
        const int ss = u & 3;
        sgs[i] = ss ^ ((srow[i] >> 1) & 3);      // pre-swizzled source slot
        slb[i] = i * 2048 + wv4 * 512;           // wave-uniform LDS base (shorts)
    }

    for (int kk = 0; kk < 8; ++kk) {
        const int k0 = kk * 32;
        #pragma unroll
        for (int i = 0; i < 2; ++i) {
            const size_t ga = (size_t)(m0 + srow[i]) * CH + k0 + sgs[i] * 8;
            const size_t gb = (size_t)(n0g + srow[i]) * CH + k0 + sgs[i] * 8;
            gld_lds16(ahi + ga, sAh + slb[i]);
            gld_lds16(alo + ga, sAl + slb[i]);
            gld_lds16(whi + gb, sBh + slb[i]);
            gld_lds16(wlo + gb, sBl + slb[i]);
        }
        __syncthreads();                          // vmcnt(0) drain + barrier

        s16x8 ah[4], al[4], wh[4], wl[4];
        #pragma unroll
        for (int i = 0; i < 4; ++i) {
            const int ar = wm * 64 + i * 16 + fm;
            const int as = (q ^ ((ar >> 1) & 3)) * 8;
            ah[i] = *(const s16x8*)&sAh[ar * 32 + as];
            al[i] = *(const s16x8*)&sAl[ar * 32 + as];
            const int br = wn * 64 + i * 16 + fm;
            const int bs = (q ^ ((br >> 1) & 3)) * 8;
            wh[i] = *(const s16x8*)&sBh[br * 32 + bs];
            wl[i] = *(const s16x8*)&sBl[br * 32 + bs];
        }
        #pragma unroll
        for (int nt = 0; nt < 4; ++nt)
            #pragma unroll
            for (int mt = 0; mt < 4; ++mt) {
                acc[nt][mt] = __builtin_amdgcn_mfma_f32_16x16x32_bf16(wh[nt], ah[mt], acc[nt][mt], 0, 0, 0);
                acc[nt][mt] = __builtin_amdgcn_mfma_f32_16x16x32_bf16(wh[nt], al[mt], acc[nt][mt], 0, 0, 0);
                acc[nt][mt] = __builtin_amdgcn_mfma_f32_16x16x32_bf16(wl[nt], ah[mt], acc[nt][mt], 0, 0, 0);
            }
        __syncthreads();                          // before next-stage overwrite
    }
}

// ---------------------------------------------------------------------------
// DUAL GEMM (both middle projections), 128x128 tiles, LDS-staged.
// bid<NBLK128: v = xt @ w_in; else: omb = f @ wt2.
// ---------------------------------------------------------------------------
__global__ __launch_bounds__(256)
void gemm128_dual(const unsigned short* __restrict__ ahi1,
                  const unsigned short* __restrict__ alo1,
                  const unsigned short* __restrict__ whi1,
                  const unsigned short* __restrict__ wlo1,
                  const float* __restrict__ bias1,
                  float* __restrict__ out1,
                  const unsigned short* __restrict__ ahi2,
                  const unsigned short* __restrict__ alo2,
                  const unsigned short* __restrict__ whi2,
                  const unsigned short* __restrict__ wlo2,
                  const float* __restrict__ bias2,
                  float* __restrict__ out2)
{
    __shared__ unsigned short sAh[128*32], sAl[128*32], sBh[128*32], sBl[128*32];

    const int half = blockIdx.x >= NBLK128;
    const int lbid = blockIdx.x - (half ? NBLK128 : 0);
    const unsigned short* ahi = half ? ahi2 : ahi1;
    const unsigned short* alo = half ? alo2 : alo1;
    const unsigned short* whi = half ? whi2 : whi1;
    const unsigned short* wlo = half ? wlo2 : wlo1;
    const float* bias = half ? bias2 : bias1;
    float* out = half ? out2 : out1;

    const int sw = (lbid & 7) * (NBLK128 / 8) + (lbid >> 3);   // bijective, 392=8*49
    const int m0 = (sw >> 1) * 128;
    const int n0g = (sw & 1) * 128;
    const int t = threadIdx.x;
    const int lane = t & 63, wv4 = t >> 6;
    const int wm = wv4 & 1, wn = wv4 >> 1;
    const int fm = lane & 15, q = lane >> 4;

    f32x4 acc[4][4];
    const f32x4 zero = {0.0f, 0.0f, 0.0f, 0.0f};
    #pragma unroll
    for (int i = 0; i < 4; ++i)
        #pragma unroll
        for (int j = 0; j < 4; ++j) acc[i][j] = zero;

    gemm128_body(ahi, alo, whi, wlo, sAh, sAl, sBh, sBl, m0, n0g, t, acc);

    #pragma unroll
    for (int nt = 0; nt < 4; ++nt) {
        const int n = n0g + wn*64 + nt*16 + q*4;
        const float4 b4 = *(const float4*)&bias[n];
        #pragma unroll
        for (int mt = 0; mt < 4; ++mt) {
            const int mm = m0 + wm*64 + mt*16 + fm;
            f32x4 o = acc[nt][mt];
            o[0] += b4.x; o[1] += b4.y; o[2] += b4.z; o[3] += b4.w;
            *(f32x4*)&out[(size_t)mm * CH + n] = o;
        }
    }
}

// ---------------------------------------------------------------------------
// Output GEMM, 128x128 tiles, LDS-staged; BN+SiLU NCHW epilogue.
// 128-row tiles straddle batch images (3136 = 24.5*128): b/hw per row.
// ---------------------------------------------------------------------------
__global__ __launch_bounds__(256)
void gemm128_out(const unsigned short* __restrict__ ahi,
                 const unsigned short* __restrict__ alo,
                 const unsigned short* __restrict__ whi,
                 const unsigned short* __restrict__ wlo,
                 const float* __restrict__ bias,
                 const float* __restrict__ bn_g,
                 const float* __restrict__ bn_b,
                 const float* __restrict__ bn_mean,
                 const float* __restrict__ bn_var,
                 float* __restrict__ y)                  // [B,256,3136]
{
    __shared__ unsigned short sAh[128*32], sAl[128*32], sBh[128*32], sBl[128*32];

    const int sw = (blockIdx.x & 7) * (NBLK128 / 8) + (blockIdx.x >> 3);
    const int m0 = (sw >> 1) * 128;
    const int n0g = (sw & 1) * 128;
    const int t = threadIdx.x;
    const int lane = t & 63, wv4 = t >> 6;
    const int wm = wv4 & 1, wn = wv4 >> 1;
    const int fm = lane & 15, q = lane >> 4;

    f32x4 acc[4][4];
    const f32x4 zero = {0.0f, 0.0f, 0.0f, 0.0f};
    #pragma unroll
    for (int i = 0; i < 4; ++i)
        #pragma unroll
        for (int j = 0; j < 4; ++j) acc[i][j] = zero;

    gemm128_body(ahi, alo, whi, wlo, sAh, sAl, sBh, sBl, m0, n0g, t, acc);

    #pragma unroll
    for (int nt = 0; nt < 4; ++nt) {
        #pragma unroll
        for (int r = 0; r < 4; ++r) {
            const int n = n0g + wn*64 + nt*16 + q*4 + r;
            const float sc = bn_g[n] * rsqrtf(bn_var[n] + 1e-5f);
            const float sb = bn_b[n] - bn_mean[n] * sc;
            const float bs = bias[n];
            #pragma unroll
            for (int mt = 0; mt < 4; ++mt) {
                const int mm = m0 + wm*64 + mt*16 + fm;
                const int bimg = mm / HW, hw = mm % HW;
                float val = (acc[nt][mt][r] + bs) * sc + sb;
                y[(size_t)bimg * CH * HW + (size_t)n * HW + hw] = val / (1.0f + expf(-val));
            }
        }
    }
}

// ---------------------------------------------------------------------------
// Fallback GEMM (proven round-4 structure): 256m x 64n blocks, grid (98,4).
// ---------------------------------------------------------------------------
__global__ __launch_bounds__(256)
void gemm_in_mfma(const unsigned short* __restrict__ xhi, // [m][k]
                  const unsigned short* __restrict__ xlo,
                  const unsigned short* __restrict__ whi, // [n][k]
                  const unsigned short* __restrict__ wlo,
                  const float* __restrict__ bias,
                  float* __restrict__ v)                  // [MTOT,256]
{
    const int m0 = blockIdx.x * 256;
    const int n0 = blockIdx.y * 64;
    const int t = threadIdx.x;
    const int lane = t & 63, wv = t >> 6;
    const int mblk = m0 + wv * 64;
    const int fm = lane & 15;
    const int q  = lane >> 4;

    f32x4 acc[4][4];              // [nt][mt]
    const f32x4 zero = {0.0f, 0.0f, 0.0f, 0.0f};
    #pragma unroll
    for (int i = 0; i < 4; ++i)
        #pragma unroll
        for (int j = 0; j < 4; ++j) acc[i][j] = zero;

    const unsigned short *xrh[4], *xrl[4], *wrh[4], *wrl[4];
    #pragma unroll
    for (int mt = 0; mt < 4; ++mt) {
        xrh[mt] = xhi + (size_t)(mblk + mt*16 + fm) * CH + q * 8;
        xrl[mt] = xlo + (size_t)(mblk + mt*16 + fm) * CH + q * 8;
    }
    #pragma unroll
    for (int nt = 0; nt < 4; ++nt) {
        wrh[nt] = whi + (size_t)(n0 + nt*16 + fm) * CH + q * 8;
        wrl[nt] = wlo + (size_t)(n0 + nt*16 + fm) * CH + q * 8;
    }

    for (int k0 = 0; k0 < CH; k0 += 32) {
        s16x8 wh[4], wl[4], ah[4], al[4];
        #pragma unroll
        for (int nt = 0; nt < 4; ++nt) {
            wh[nt] = *(const s16x8*)(wrh[nt] + k0);
            wl[nt] = *(const s16x8*)(wrl[nt] + k0);
        }
        #pragma unroll
        for (int mt = 0; mt < 4; ++mt) {
            ah[mt] = *(const s16x8*)(xrh[mt] + k0);
            al[mt] = *(const s16x8*)(xrl[mt] + k0);
        }
        #pragma unroll
        for (int nt = 0; nt < 4; ++nt)
            #pragma unroll
            for (int mt = 0; mt < 4; ++mt) {
                acc[nt][mt] = __builtin_amdgcn_mfma_f32_16x16x32_bf16(wh[nt], ah[mt], acc[nt][mt], 0, 0, 0);
                acc[nt][mt] = __builtin_amdgcn_mfma_f32_16x16x32_bf16(wh[nt], al[mt], acc[nt][mt], 0, 0, 0);
                acc[nt][mt] = __builtin_amdgcn_mfma_f32_16x16x32_bf16(wl[nt], ah[mt], acc[nt][mt], 0, 0, 0);
            }
    }

    #pragma unroll
    for (int nt = 0; nt < 4; ++nt) {
        const float4 b4 = *(const float4*)&bias[n0 + nt*16 + q*4];
        #pragma unroll
        for (int mt = 0; mt < 4; ++mt) {
            f32x4 o = acc[nt][mt];
            o[0] += b4.x; o[1] += b4.y; o[2] += b4.z; o[3] += b4.w;
            *(f32x4*)&v[(size_t)(mblk + mt*16 + fm) * CH + n0 + nt*16 + q*4] = o;
        }
    }
}

// ---------------------------------------------------------------------------
// Per-position-wave depthwise 3x3 + bias + LN + GELU from NHWC bf16 hi/lo xt,
// output stored PRE-SPLIT as bf16 hi/lo. One wave per position.
// ---------------------------------------------------------------------------
__global__ __launch_bounds__(256)
void dw_ln_gelu_nhwc_split(const unsigned short* __restrict__ xhi,
                           const unsigned short* __restrict__ xlo,
                           const float* __restrict__ dw_w,   // [256][9]
                           const float* __restrict__ dw_b,
                           const float* __restrict__ ln_g,
                           const float* __restrict__ ln_b,
                           unsigned short* __restrict__ fh,  // [MTOT][256]
                           unsigned short* __restrict__ fl)  // [MTOT][256]
{
    __shared__ float wt[NP][CH];                       // transposed dw weights
    __shared__ float lbias[CH], lgam[CH], lbet[CH];

    const int t = threadIdx.x;
    {
        const float* wp = dw_w + t * NP;
        #pragma unroll
        for (int p = 0; p < NP; ++p) wt[p][t] = wp[p];
        lbias[t] = dw_b[t]; lgam[t] = ln_g[t]; lbet[t] = ln_b[t];
    }
    __syncthreads();

    const int nblk = MTOT / POSB;          // 6272
    const int per  = nblk / 8;             // 784
    const int bid  = blockIdx.x;
    const int sw   = (bid & 7) * per + (bid >> 3);
    const int q    = t >> 6, lane = t & 63;
    const int n    = sw * POSB + q;
    const int b    = n / HW;
    const int hw   = n % HW;
    const int h    = hw / WDIM, w = hw % WDIM;
    const int c4   = lane * 4;
    const size_t base = (size_t)b * HW * CH + c4;

    float ax = 0.0f, ay = 0.0f, az = 0.0f, aw = 0.0f;
    #pragma unroll
    for (int p = 0; p < NP; ++p) {
        const int hh = h + p / 3 - 1;
        const int ww = w + p % 3 - 1;
        if ((unsigned)hh >= (unsigned)HDIM || (unsigned)ww >= (unsigned)WDIM)
            continue;                       // wave-uniform branch (h,w per-wave)
        const size_t idx = base + (size_t)(hh * WDIM + ww) * CH;
        const ushort4 uh = *(const ushort4*)(xhi + idx);
        const ushort4 ul = *(const ushort4*)(xlo + idx);
        const float4 wv = *(const float4*)&wt[p][c4];
        ax = fmaf(__uint_as_float((unsigned)uh.x << 16), wv.x,
             fmaf(__uint_as_float((unsigned)ul.x << 16), wv.x, ax));
        ay = fmaf(__uint_as_float((unsigned)uh.y << 16), wv.y,
             fmaf(__uint_as_float((unsigned)ul.y << 16), wv.y, ay));
        az = fmaf(__uint_as_float((unsigned)uh.z << 16), wv.z,
             fmaf(__uint_as_float((unsigned)ul.z << 16), wv.z, az));
        aw = fmaf(__uint_as_float((unsigned)uh.w << 16), wv.w,
             fmaf(__uint_as_float((unsigned)ul.w << 16), wv.w, aw));
    }
    {
        const float4 b4 = *(const float4*)&lbias[c4];
        ax += b4.x; ay += b4.y; az += b4.z; aw += b4.w;
    }

    // LayerNorm over the wave's 256 channel values: in-wave butterfly.
    float s1 = ax + ay + az + aw;
    float s2 = ax*ax + ay*ay + az*az + aw*aw;
    #pragma unroll
    for (int off = 32; off > 0; off >>= 1) {
        s1 += __shfl_xor(s1, off);
        s2 += __shfl_xor(s2, off);
    }
    const float mean = s1 * (1.0f / 256.0f);
    const float rstd = rsqrtf(s2 * (1.0f / 256.0f) - mean * mean + 1e-5f);

    const float4 g4 = *(const float4*)&lgam[c4];
    const float4 e4 = *(const float4*)&lbet[c4];
    const float x0 = (ax - mean) * rstd * g4.x + e4.x;
    const float x1 = (ay - mean) * rstd * g4.y + e4.y;
    const float x2 = (az - mean) * rstd * g4.z + e4.z;
    const float x3 = (aw - mean) * rstd * g4.w + e4.w;
    const float o0 = 0.5f * x0 * (1.0f + erff(x0 * 0.70710678118654752f));
    const float o1 = 0.5f * x1 * (1.0f + erff(x1 * 0.70710678118654752f));
    const float o2 = 0.5f * x2 * (1.0f + erff(x2 * 0.70710678118654752f));
    const float o3 = 0.5f * x3 * (1.0f + erff(x3 * 0.70710678118654752f));

    unsigned int hp0, lp0, hp1, lp1;
    split2(o0, o1, hp0, lp0);
    split2(o2, o3, hp1, lp1);
    *(uint2*)&fh[(size_t)n * CH + c4] = make_uint2(hp0, hp1);
    *(uint2*)&fl[(size_t)n * CH + c4] = make_uint2(lp0, lp1);
}

// ---------------------------------------------------------------------------
// Transpose + hi/lo bf16 split of a [256k][256n] fp32 weight -> [n][k] bf16.
// ---------------------------------------------------------------------------
__global__ __launch_bounds__(256)
void wt_split_kernel(const float* __restrict__ w,
                     unsigned short* __restrict__ hi,
                     unsigned short* __restrict__ lo)
{
    __shared__ float lds[64][68];
    const int kt = blockIdx.x * 64, nt = blockIdx.y * 64;
    const int t = threadIdx.x;
    #pragma unroll
    for (int p = 0; p < 4; ++p) {
        const int kr = (t >> 4) + p * 16, nc = (t & 15) * 4;
        *(float4*)&lds[kr][nc] = *(const float4*)(w + (size_t)(kt + kr) * CH + nt + nc);
    }
    __syncthreads();
    const int nl = t >> 2, kc = (t & 3) * 16;
    #pragma unroll
    for (int j = 0; j < 16; j += 2) {
        const float f0 = lds[kc + j][nl], f1 = lds[kc + j + 1][nl];
        unsigned int hp, lp;
        split2(f0, f1, hp, lp);
        *(unsigned int*)&hi[(size_t)(nt + nl) * CH + kt + kc + j] = hp;
        *(unsigned int*)&lo[(size_t)(nt + nl) * CH + kt + kc + j] = lp;
    }
}

// ---------------------------------------------------------------------------
// Transpose + split of [w_off | w_mask] -> wt2_hi/lo [256 n_pad][256 k] bf16.
// Also builds bcat[256] = [b_off | b_mask | 0] (block 0 only).
// ---------------------------------------------------------------------------
__global__ __launch_bounds__(256)
void wt2_split_kernel(const float* __restrict__ w_off,   // [256][144]
                      const float* __restrict__ w_mask,  // [256][72]
                      const float* __restrict__ b_off,
                      const float* __restrict__ b_mask,
                      unsigned short* __restrict__ hi,
                      unsigned short* __restrict__ lo,
                      float* __restrict__ bcat)          // [256]
{
    const int n = threadIdx.x;
    if (blockIdx.x == 0) {
        bcat[n] = (n < NOFF) ? b_off[n] : ((n < NTOT) ? b_mask[n - NOFF] : 0.0f);
    }
    const int k0 = blockIdx.x * 16;
    #pragma unroll
    for (int j = 0; j < 16; j += 2) {
        const int k = k0 + j;
        float f0 = 0.0f, f1 = 0.0f;
        if (n < NOFF) {
            f0 = w_off[(size_t)k * NOFF + n];
            f1 = w_off[(size_t)(k + 1) * NOFF + n];
        } else if (n < NTOT) {
            f0 = w_mask[(size_t)k * NMSK + (n - NOFF)];
            f1 = w_mask[(size_t)(k + 1) * NMSK + (n - NOFF)];
        }
        unsigned int hp, lp;
        split2(f0, f1, hp, lp);
        *(unsigned int*)&hi[(size_t)n * CH + k] = hp;
        *(unsigned int*)&lo[(size_t)n * CH + k] = lp;
    }
}

// ---------------------------------------------------------------------------
// Deformable sampling reading the padded omb [MTOT][256] rows
// (cols 0..143 offsets, 144..215 mask logits). Output s PRE-SPLIT bf16 hi/lo.
// ---------------------------------------------------------------------------
__global__ __launch_bounds__(256)
void sample_kernel_omb_split(const float* __restrict__ v,
                             const float* __restrict__ omb,
                             unsigned short* __restrict__ sh,  // [MTOT][256]
                             unsigned short* __restrict__ sl)  // [MTOT][256]
{
    __shared__ alignas(16) float loff[POSB][NOFF];
    __shared__ alignas(16) float lmsk[POSB][NMSK];
    __shared__ alignas(16) float wtab[POSB][GRP*NP][4];
    __shared__ alignas(16) int   itab[POSB][GRP*NP][4];

    const int nblk = MTOT / POSB;            // 6272
    const int per  = nblk / 8;               // 784
    const int bid  = blockIdx.x;
    const int sw   = (bid % 8) * per + (bid / 8);
    const int n0 = sw * POSB;
    const int t = threadIdx.x;

    if (t < POSB * (NOFF/4)) {
        const int q = t / (NOFF/4), r = t % (NOFF/4);
        *(float4*)&loff[q][r*4] = *(const float4*)&omb[(size_t)(n0+q)*CH + r*4];
    } else if (t < POSB * (NOFF/4) + POSB * (NMSK/4)) {
        const int u = t - POSB * (NOFF/4);
        const int q = u / (NMSK/4), r = u % (NMSK/4);
        *(float4*)&lmsk[q][r*4] = *(const float4*)&omb[(size_t)(n0+q)*CH + NOFF + r*4];
    }
    __syncthreads();

    if (t < POSB * GRP) {
        const int q = t >> 3, g = t & 7;
        float* mm = &lmsk[q][g * NP];
        float mx = -1e30f;
        #pragma unroll
        for (int p = 0; p < NP; ++p) mx = fmaxf(mx, mm[p]);
        float sum = 0.0f;
        #pragma unroll
        for (int p = 0; p < NP; ++p) { const float e = __expf(mm[p] - mx); mm[p] = e; sum += e; }
        const float inv = 1.0f / sum;
        #pragma unroll
        for (int p = 0; p < NP; ++p) mm[p] *= inv;
    }
    __syncthreads();

    for (int u = t; u < POSB * GRP * NP; u += 256) {
        const int q = u / (GRP*NP), j = u % (GRP*NP);
        const int g = j / NP, p = j % NP;
        const int n = n0 + q;
        const int hw = n % HW;
        const int h = hw / WDIM, w = hw % WDIM;
        const float ox = loff[q][g*18 + p*2 + 0];
        const float oy = loff[q][g*18 + p*2 + 1];
        const float m  = lmsk[q][g*NP + p];
        const float px = (float)(w + p/3) + ox;
        const float py = (float)(h + p%3) + oy;
        const float fx = floorf(px), fy = floorf(py);
        const float wx = px - fx, wy = py - fy;
        const int x0 = (int)fx, y0 = (int)fy;
        const int x1 = x0 + 1, y1 = y0 + 1;
        const float vx0 = (x0 >= 1 && x0 < 57) ? 1.0f : 0.0f;
        const float vx1 = (x1 >= 1 && x1 < 57) ? 1.0f : 0.0f;
        const float vy0 = (y0 >= 1 && y0 < 57) ? 1.0f : 0.0f;
        const float vy1 = (y1 >= 1 && y1 < 57) ? 1.0f : 0.0f;
        const int x0c = min(max(x0, 1), 56), x1c = min(max(x1, 1), 56);
        const int y0c = min(max(y0, 1), 56), y1c = min(max(y1, 1), 56);
        wtab[q][j][0] = m * (1.0f-wx) * (1.0f-wy) * vx0 * vy0;
        wtab[q][j][1] = m * wx        * (1.0f-wy) * vx1 * vy0;
        wtab[q][j][2] = m * (1.0f-wx) * wy        * vx0 * vy1;
        wtab[q][j][3] = m * wx        * wy        * vx1 * vy1;
        itab[q][j][0] = ((y0c-1)*WDIM + (x0c-1)) * CH;
        itab[q][j][1] = ((y0c-1)*WDIM + (x1c-1)) * CH;
        itab[q][j][2] = ((y1c-1)*WDIM + (x0c-1)) * CH;
        itab[q][j][3] = ((y1c-1)*WDIM + (x1c-1)) * CH;
    }
    __syncthreads();

    const int q = t >> 6, lane = t & 63;
    const int n = n0 + q;
    const int b = n / HW;
    const int g = lane >> 3;
    const float* vb = v + (size_t)b*HW*CH + lane*4;
    float4 acc = {0.0f, 0.0f, 0.0f, 0.0f};
    #pragma unroll
    for (int p = 0; p < NP; ++p) {
        const int j = g*NP + p;
        const float4 wv = *(const float4*)&wtab[q][j][0];
        const int4  iv = *(const int4*)&itab[q][j][0];
        const float4 c0 = *(const float4*)(vb + iv.x);
        const float4 c1 = *(const float4*)(vb + iv.y);
        const float4 c2 = *(const float4*)(vb + iv.z);
        const float4 c3 = *(const float4*)(vb + iv.w);
        acc.x += wv.x*c0.x + wv.y*c1.x + wv.z*c2.x + wv.w*c3.x;
        acc.y += wv.x*c0.y + wv.y*c1.y + wv.z*c2.y + wv.w*c3.y;
        acc.z += wv.x*c0.z + wv.y*c1.z + wv.z*c2.z + wv.w*c3.z;
        acc.w += wv.x*c0.w + wv.y*c1.w + wv.z*c2.w + wv.w*c3.w;
    }
    unsigned int hp0, lp0, hp1, lp1;
    split2(acc.x, acc.y, hp0, lp0);
    split2(acc.z, acc.w, hp1, lp1);
    *(uint2*)&sh[(size_t)n*CH + lane*4] = make_uint2(hp0, hp1);
    *(uint2*)&sl[(size_t)n*CH + lane*4] = make_uint2(lp0, lp1);
}

// ---------------------------------------------------------------------------
// Fallback GEMM out from PRE-SPLIT bf16 A (round-5 structure, grid (98,4)).
// ---------------------------------------------------------------------------
__global__ __launch_bounds__(256)
void gemm_out_bf16(const unsigned short* __restrict__ shp, // [m][k] bf16 hi
                   const unsigned short* __restrict__ slp, // [m][k] bf16 lo
                   const unsigned short* __restrict__ whi, // [256 n][256 k]
                   const unsigned short* __restrict__ wlo,
                   const float* __restrict__ bias,
                   const float* __restrict__ bn_g,
                   const float* __restrict__ bn_b,
                   const float* __restrict__ bn_mean,
                   const float* __restrict__ bn_var,
                   float* __restrict__ y)                  // [B,256,3136]
{
    const int m0 = blockIdx.x * 256;
    const int n0 = blockIdx.y * 64;
    const int t = threadIdx.x;
    const int lane = t & 63, wv = t >> 6;
    const int mblk = m0 + wv * 64;
    const int fm = lane & 15;
    const int q  = lane >> 4;

    f32x4 acc[4][4];
    const f32x4 zero = {0.0f, 0.0f, 0.0f, 0.0f};
    #pragma unroll
    for (int i = 0; i < 4; ++i)
        #pragma unroll
        for (int j = 0; j < 4; ++j) acc[i][j] = zero;

    const unsigned short *xrh[4], *xrl[4], *wrh[4], *wrl[4];
    #pragma unroll
    for (int mt = 0; mt < 4; ++mt) {
        xrh[mt] = shp + (size_t)(mblk + mt*16 + fm) * CH + q * 8;
        xrl[mt] = slp + (size_t)(mblk + mt*16 + fm) * CH + q * 8;
    }
    #pragma unroll
    for (int nt = 0; nt < 4; ++nt) {
        wrh[nt] = whi + (size_t)(n0 + nt*16 + fm) * CH + q * 8;
        wrl[nt] = wlo + (size_t)(n0 + nt*16 + fm) * CH + q * 8;
    }

    for (int k0 = 0; k0 < CH; k0 += 32) {
        s16x8 wh[4], wl[4], ah[4], al[4];
        #pragma unroll
        for (int nt = 0; nt < 4; ++nt) {
            wh[nt] = *(const s16x8*)(wrh[nt] + k0);
            wl[nt] = *(const s16x8*)(wrl[nt] + k0);
        }
        #pragma unroll
        for (int mt = 0; mt < 4; ++mt) {
            ah[mt] = *(const s16x8*)(xrh[mt] + k0);
            al[mt] = *(const s16x8*)(xrl[mt] + k0);
        }
        #pragma unroll
        for (int nt = 0; nt < 4; ++nt)
            #pragma unroll
            for (int mt = 0; mt < 4; ++mt) {
                acc[nt][mt] = __builtin_amdgcn_mfma_f32_16x16x32_bf16(wh[nt], ah[mt], acc[nt][mt], 0, 0, 0);
                acc[nt][mt] = __builtin_amdgcn_mfma_f32_16x16x32_bf16(wh[nt], al[mt], acc[nt][mt], 0, 0, 0);
                acc[nt][mt] = __builtin_amdgcn_mfma_f32_16x16x32_bf16(wl[nt], ah[mt], acc[nt][mt], 0, 0, 0);
            }
    }

    #pragma unroll
    for (int nt = 0; nt < 4; ++nt) {
        #pragma unroll
        for (int r = 0; r < 4; ++r) {
            const int n = n0 + nt*16 + q*4 + r;
            const float sc = bn_g[n] * rsqrtf(bn_var[n] + 1e-5f);
            const float sb = bn_b[n] - bn_mean[n] * sc;
            const float bs = bias[n];
            #pragma unroll
            for (int mt = 0; mt < 4; ++mt) {
                const int mm = mblk + mt*16;
                const size_t base = (size_t)(mm / HW) * CH * HW + (mm % HW);
                float val = (acc[nt][mt][r] + bs) * sc + sb;
                y[base + (size_t)n * HW + fm] = val / (1.0f + expf(-val));
            }
        }
    }
}

extern "C" void kernel_launch(void* const* d_in, const int* in_sizes, int n_in,
                              void* d_out, int out_size, void* d_ws, size_t ws_size,
                              hipStream_t stream) {
    const float* x      = (const float*)d_in[0];
    const float* w_in   = (const float*)d_in[1];
    const float* b_in   = (const float*)d_in[2];
    const float* dw_w   = (const float*)d_in[3];
    const float* dw_b   = (const float*)d_in[4];
    const float* ln_g   = (const float*)d_in[5];
    const float* ln_b   = (const float*)d_in[6];
    const float* w_off  = (const float*)d_in[7];
    const float* b_off  = (const float*)d_in[8];
    const float* w_mask = (const float*)d_in[9];
    const float* b_mask = (const float*)d_in[10];
    const float* w_out  = (const float*)d_in[11];
    const float* b_out  = (const float*)d_in[12];
    const float* bn_g   = (const float*)d_in[13];
    const float* bn_b   = (const float*)d_in[14];
    const float* bn_mean= (const float*)d_in[15];
    const float* bn_var = (const float*)d_in[16];
    float* out = (float*)d_out;

    const size_t SZ = (size_t)MTOT * CH;                 // elements
    // Layout: v | xt_hi,xt_lo | fh,fl | omb | weights | bcat
    const size_t need_new =
        4 * SZ * sizeof(float)
        + 6 * (size_t)CH * CH * sizeof(unsigned short)
        + CH * sizeof(float);

    if (ws_size >= need_new) {
        // -------- main path --------
        float* ws = (float*)d_ws;
        float* v    = ws;                                          // SZ f32
        unsigned short* xt_hi = (unsigned short*)(v + SZ);         // SZ us
        unsigned short* xt_lo = xt_hi + SZ;                        // SZ us
        unsigned short* fh    = xt_lo + SZ;                        // SZ us
        unsigned short* fl    = fh + SZ;                           // SZ us
        float* omb  = (float*)(fl + SZ);                           // SZ f32
        unsigned short* wt_hi  = (unsigned short*)(omb + SZ);
        unsigned short* wt_lo  = wt_hi + CH * CH;
        unsigned short* wt2_hi = wt_lo + CH * CH;
        unsigned short* wt2_lo = wt2_hi + CH * CH;
        unsigned short* wt3_hi = wt2_lo + CH * CH;
        unsigned short* wt3_lo = wt3_hi + CH * CH;
        float* bcat = (float*)(wt3_lo + CH * CH);                  // 256 f32
        // sh/sl overlay xt region (xt consumed by dual GEMM + dw beforehand).
        unsigned short* sh = xt_hi;
        unsigned short* sl = xt_lo;

        wt_split_kernel<<<dim3(4, 4), dim3(256), 0, stream>>>(w_out, wt_hi, wt_lo);
        wt_split_kernel<<<dim3(4, 4), dim3(256), 0, stream>>>(w_in, wt3_hi, wt3_lo);
        wt2_split_kernel<<<dim3(16), dim3(256), 0, stream>>>(
            w_off, w_mask, b_off, b_mask, wt2_hi, wt2_lo, bcat);
        xt_split_kernel<<<dim3(HW/64, CH/64, BATCH), dim3(256), 0, stream>>>(x, xt_hi, xt_lo);
        dw_ln_gelu_nhwc_split<<<dim3(MTOT/POSB), dim3(256), 0, stream>>>(
            xt_hi, xt_lo, dw_w, dw_b, ln_g, ln_b, fh, fl);
        // Both middle projections in ONE dispatch, LDS-staged 128x128 tiles:
        gemm128_dual<<<dim3(2 * NBLK128), dim3(256), 0, stream>>>(
            xt_hi, xt_lo, wt3_hi, wt3_lo, b_in, v,
            fh, fl, wt2_hi, wt2_lo, bcat, omb);
        sample_kernel_omb_split<<<dim3(MTOT/POSB), dim3(256), 0, stream>>>(v, omb, sh, sl);
        gemm128_out<<<dim3(NBLK128), dim3(256), 0, stream>>>(
            sh, sl, wt_hi, wt_lo, b_out, bn_g, bn_b, bn_mean, bn_var, out);
    } else {
        // -------- fallback: round-5 verified path --------
        float* ws = (float*)d_ws;
        float* v    = ws;
        unsigned short* xt_hi = (unsigned short*)(v + SZ);
        unsigned short* xt_lo = xt_hi + SZ;
        unsigned short* fh    = xt_lo + SZ;
        unsigned short* fl    = fh + SZ;
        float* omb  = (float*)(fl + SZ);
        unsigned short* wt_hi  = (unsigned short*)(omb + SZ);
        unsigned short* wt_lo  = wt_hi + CH * CH;
        unsigned short* wt2_hi = wt_lo + CH * CH;
        unsigned short* wt2_lo = wt2_hi + CH * CH;
        unsigned short* wt3_hi = wt2_lo + CH * CH;
        unsigned short* wt3_lo = wt3_hi + CH * CH;
        float* bcat = (float*)(wt3_lo + CH * CH);
        unsigned short* sh = xt_hi;
        unsigned short* sl = xt_lo;

        wt_split_kernel<<<dim3(4, 4), dim3(256), 0, stream>>>(w_out, wt_hi, wt_lo);
        wt_split_kernel<<<dim3(4, 4), dim3(256), 0, stream>>>(w_in, wt3_hi, wt3_lo);
        wt2_split_kernel<<<dim3(16), dim3(256), 0, stream>>>(
            w_off, w_mask, b_off, b_mask, wt2_hi, wt2_lo, bcat);
        xt_split_kernel<<<dim3(HW/64, CH/64, BATCH), dim3(256), 0, stream>>>(x, xt_hi, xt_lo);
        gemm_in_mfma<<<dim3(MTOT/256, CH/64), dim3(256), 0, stream>>>(
            xt_hi, xt_lo, wt3_hi, wt3_lo, b_in, v);
        dw_ln_gelu_nhwc_split<<<dim3(MTOT/POSB), dim3(256), 0, stream>>>(
            xt_hi, xt_lo, dw_w, dw_b, ln_g, ln_b, fh, fl);
        gemm_in_mfma<<<dim3(MTOT/256, CH/64), dim3(256), 0, stream>>>(
            fh, fl, wt2_hi, wt2_lo, bcat, omb);
        sample_kernel_omb_split<<<dim3(MTOT/POSB), dim3(256), 0, stream>>>(v, omb, sh, sl);
        gemm_out_bf16<<<dim3(MTOT/256, CH/64), dim3(256), 0, stream>>>(
            sh, sl, wt_hi, wt_lo, b_out, bn_g, bn_b, bn_mean, bn_var, out);
    }
}